// Round 1
// baseline (1873.955 us; speedup 1.0000x reference)
//
#include <hip/hip_runtime.h>
#include <math.h>

// ---------------- problem constants ----------------
#define N_ENTS   50000
#define E_EDGES  800000
#define HD       128      // embedding dim
#define BSZ      1024
#define C_CH     96
#define FLATD    9600     // 96*10*10
#define TOPK_K   15
#define HIDD     200
#define SPLITK   16
#define OUT_SCORE ((size_t)BSZ * N_ENTS)   // 51,200,000

// ---------------- workspace layout (float element offsets) ----------------
// total = 36,283,136 floats = 145,132,544 bytes (~138.4 MiB)
#define F_COMMON   ((size_t)0)          // 50000*128        -> later c1
#define F_PRIVATE  ((size_t)6400000)    // 50000*128        -> later c2
#define F_NEIGH1   ((size_t)12800000)   // 50000*128   (reused: g1/g2 halves, convout)
#define F_NEIGH2   ((size_t)19200000)   // 50000*128
#define F_ENTOUT   ((size_t)25600000)   // 50000*128
#define F_SCORE1   ((size_t)32000000)   // 800000  (scores -> norms; later fc partials)
#define F_SCORE2   ((size_t)32800000)   // 800000
#define F_W1       ((size_t)33600000)   // 800000
#define F_W2       ((size_t)34400000)   // 800000  (later x1/x2 live here)
#define I_EORDER   ((size_t)35200000)   // 800000 int
#define I_DEG      ((size_t)36000000)   // 50000 int
#define I_START    ((size_t)36050000)   // 50000 int
#define I_CURSOR   ((size_t)36100000)   // 50000 int
#define I_BSUM     ((size_t)36150000)   // 1024 int
#define F_RED      ((size_t)36152000)   // 16
#define F_XFC      ((size_t)36152064)   // 1024*128
// reuses (phase-ordered, non-overlapping within a phase):
#define F_G1       F_NEIGH1                       // 25000*200 = 5,000,000
#define F_G2       (F_NEIGH1 + 5000000)           // 25000*200
#define F_CONVOUT  F_NEIGH1                       // 1024*9600 = 9,830,400
#define F_FCPART   F_SCORE1                       // 16*1024*128 = 2,097,152
#define F_X1       F_W2                           // 50000
#define F_X2       (F_W2 + 50000)                 // 50000

// ================= CSR build =================
__global__ void k_deg(const int* __restrict__ dst, int* __restrict__ deg) {
    int e = blockIdx.x * 256 + threadIdx.x;
    if (e < E_EDGES) atomicAdd(&deg[dst[e]], 1);
}

__global__ void k_scan1(const int* __restrict__ in, int* __restrict__ out,
                        int* __restrict__ bsum, int n) {
    __shared__ int sh[256];
    int i = blockIdx.x * 256 + threadIdx.x;
    int v = (i < n) ? in[i] : 0;
    sh[threadIdx.x] = v; __syncthreads();
    for (int off = 1; off < 256; off <<= 1) {
        int t = (threadIdx.x >= off) ? sh[threadIdx.x - off] : 0;
        __syncthreads();
        sh[threadIdx.x] += t;
        __syncthreads();
    }
    if (i < n) out[i] = sh[threadIdx.x] - v;          // exclusive
    if (threadIdx.x == 255) bsum[blockIdx.x] = sh[255];
}

__global__ void k_scan2(int* __restrict__ bsum, int nb) {
    __shared__ int sh[1024];
    int t = threadIdx.x;
    int v = (t < nb) ? bsum[t] : 0;
    sh[t] = v; __syncthreads();
    for (int off = 1; off < 1024; off <<= 1) {
        int u = (t >= off) ? sh[t - off] : 0;
        __syncthreads();
        sh[t] += u;
        __syncthreads();
    }
    if (t < nb) bsum[t] = sh[t] - v;                  // exclusive
}

__global__ void k_scan3(int* __restrict__ out, const int* __restrict__ bsum, int n) {
    int i = blockIdx.x * 256 + threadIdx.x;
    if (i < n) out[i] += bsum[blockIdx.x];
}

__global__ void k_scatter(const int* __restrict__ dst, const int* __restrict__ start,
                          int* __restrict__ cursor, int* __restrict__ eorder) {
    int e = blockIdx.x * 256 + threadIdx.x;
    if (e < E_EDGES) {
        int n = dst[e];
        int p = start[n] + atomicAdd(&cursor[n], 1);
        eorder[p] = e;
    }
}

// deterministic order: sort each node's slot segment by edge id ascending
__global__ void k_sortseg(const int* __restrict__ start, const int* __restrict__ deg,
                          int* __restrict__ eorder) {
    int n = blockIdx.x * 256 + threadIdx.x;
    if (n >= N_ENTS) return;
    int b = start[n], d = deg[n];
    for (int i = 1; i < d; i++) {
        int key = eorder[b + i];
        int j = i - 1;
        while (j >= 0 && eorder[b + j] > key) { eorder[b + j + 1] = eorder[b + j]; j--; }
        eorder[b + j + 1] = key;
    }
}

// ================= edge scores (wave per slot, both layers fused) =================
__global__ void k_scores(const int* __restrict__ eorder, const int* __restrict__ src,
                         const int* __restrict__ dst, const int* __restrict__ rel_id,
                         const float* __restrict__ common, const float* __restrict__ priv,
                         const float* __restrict__ rel,
                         float* __restrict__ s1, float* __restrict__ s2) {
    int slot = blockIdx.x * 4 + (threadIdx.x >> 6);
    int lane = threadIdx.x & 63;
    if (slot >= E_EDGES) return;
    int e = eorder[slot];
    size_t sB = (size_t)src[e] * HD, dB = (size_t)dst[e] * HD, rB = (size_t)rel_id[e] * HD;
    float2 rr = *(const float2*)(rel   + rB + 2 * lane);
    float2 cs = *(const float2*)(common+ sB + 2 * lane);
    float2 cd = *(const float2*)(common+ dB + 2 * lane);
    float2 ps = *(const float2*)(priv  + sB + 2 * lane);
    float2 pd = *(const float2*)(priv  + dB + 2 * lane);
    float a = cs.x * rr.x * cd.x + cs.y * rr.y * cd.y;
    float b = ps.x * rr.x * pd.x + ps.y * rr.y * pd.y;
    for (int m = 32; m; m >>= 1) { a += __shfl_xor(a, m, 64); b += __shfl_xor(b, m, 64); }
    if (lane == 0) { s1[slot] = a; s2[slot] = b; }
}

// ================= per-node softmax: scores -> norms in place =================
__global__ void k_softmax(const int* __restrict__ start, const int* __restrict__ deg,
                          float* __restrict__ s1, float* __restrict__ s2) {
    int n = blockIdx.x * 4 + (threadIdx.x >> 6);
    int lane = threadIdx.x & 63;
    if (n >= N_ENTS) return;
    int b = start[n], d = deg[n];
    if (d == 0) return;
    float m1 = -INFINITY, m2 = -INFINITY;
    for (int i = lane; i < d; i += 64) { m1 = fmaxf(m1, s1[b + i]); m2 = fmaxf(m2, s2[b + i]); }
    for (int o = 32; o; o >>= 1) { m1 = fmaxf(m1, __shfl_xor(m1, o, 64)); m2 = fmaxf(m2, __shfl_xor(m2, o, 64)); }
    float z1 = 0.f, z2 = 0.f;
    for (int i = lane; i < d; i += 64) { z1 += expf(s1[b + i] - m1); z2 += expf(s2[b + i] - m2); }
    for (int o = 32; o; o >>= 1) { z1 += __shfl_xor(z1, o, 64); z2 += __shfl_xor(z2, o, 64); }
    for (int i = lane; i < d; i += 64) {
        s1[b + i] = expf(s1[b + i] - m1) / z1;
        s2[b + i] = expf(s2[b + i] - m2) / z2;
    }
}

// ================= top-15 per node (count-based rank; exact lexsort tie semantics) =====
__global__ void k_topk(const int* __restrict__ eorder, const int* __restrict__ dst,
                       const int* __restrict__ start, const int* __restrict__ deg,
                       const float* __restrict__ n1, const float* __restrict__ n2,
                       float* __restrict__ w1, float* __restrict__ w2) {
    int slot = blockIdx.x * 256 + threadIdx.x;
    if (slot >= E_EDGES) return;
    int e = eorder[slot];
    int nd = dst[e];
    int b = start[nd], d = deg[nd];
    float my1 = n1[slot], my2 = n2[slot];
    int r1 = 0, r2 = 0;
    for (int j = b; j < b + d; j++) {
        float v1 = n1[j], v2 = n2[j];
        int id = eorder[j];
        r1 += (v1 > my1) || (v1 == my1 && id < e);
        r2 += (v2 > my2) || (v2 == my2 && id < e);
    }
    w1[slot] = (r1 < TOPK_K) ? my1 : 0.f;
    w2[slot] = (r2 < TOPK_K) ? my2 : 0.f;
}

// ================= weighted aggregation (wave per node, both layers) =================
__global__ void k_agg(const int* __restrict__ eorder, const int* __restrict__ src,
                      const int* __restrict__ rel_id,
                      const int* __restrict__ start, const int* __restrict__ deg,
                      const float* __restrict__ w1, const float* __restrict__ w2,
                      const float* __restrict__ common, const float* __restrict__ priv,
                      const float* __restrict__ rel,
                      float* __restrict__ neigh1, float* __restrict__ neigh2) {
    int n = blockIdx.x * 4 + (threadIdx.x >> 6);
    int lane = threadIdx.x & 63;
    if (n >= N_ENTS) return;
    int b = start[n], d = deg[n];
    float2 a1 = make_float2(0.f, 0.f), a2 = make_float2(0.f, 0.f);
    for (int s = b; s < b + d; s++) {
        float x1 = w1[s], x2 = w2[s];
        if (x1 == 0.f && x2 == 0.f) continue;
        int e = eorder[s];
        size_t sB = (size_t)src[e] * HD + 2 * lane;
        size_t rB = (size_t)rel_id[e] * HD + 2 * lane;
        float2 rr = *(const float2*)(rel + rB);
        float2 cs = *(const float2*)(common + sB);
        float2 ps = *(const float2*)(priv + sB);
        a1.x += x1 * cs.x * rr.x; a1.y += x1 * cs.y * rr.y;
        a2.x += x2 * ps.x * rr.x; a2.y += x2 * ps.y * rr.y;
    }
    *(float2*)(neigh1 + (size_t)n * HD + 2 * lane) = a1;
    *(float2*)(neigh2 + (size_t)n * HD + 2 * lane) = a2;
}

// ================= generic f32 GEMM =================
// C[M,N] = epi(A[M,K] @ B + bias), B normal [K,N] (BT=0) or transposed [N,K] (BT=1).
// grid.z>1 => split-K partial write (no bias/epi): out + z*M*N, k range [z*kChunk, ...).
// epi: 0 none, 1 relu, 2 tanh, 3 sigmoid
#define LP 68
template <int BT>
__global__ __launch_bounds__(256) void k_gemm(
    const float* __restrict__ A, const float* __restrict__ B,
    const float* __restrict__ bias, float* __restrict__ Cout,
    int M, int N, int K, int kChunk, int epi) {
    __shared__ __align__(16) float As[16 * LP];
    __shared__ __align__(16) float Bs[16 * LP];
    const int tid = threadIdx.x;
    const int tx = tid & 15, ty = tid >> 4;
    const int row0 = blockIdx.x * 64, col0 = blockIdx.y * 64;
    const int kb = blockIdx.z * kChunk;
    const int ke = min(K, kb + kChunk);
    const int alk = tid & 15;      // k for A/BT staging
    const int alm = tid >> 4;      // base row/col
    const int bln = tid & 63;      // col for B staging
    const int blk = tid >> 6;      // base k for B staging

    float acc[4][4];
#pragma unroll
    for (int i = 0; i < 4; i++)
#pragma unroll
        for (int j = 0; j < 4; j++) acc[i][j] = 0.f;

    for (int kk = kb; kk < ke; kk += 16) {
#pragma unroll
        for (int i = 0; i < 4; i++) {
            int m = alm + 16 * i;
            int gr = row0 + m, gk = kk + alk;
            float v = 0.f;
            if (gr < M && gk < ke) v = A[(size_t)gr * K + gk];
            As[alk * LP + m] = v;
        }
        if (BT == 0) {
#pragma unroll
            for (int i = 0; i < 4; i++) {
                int k = blk + 4 * i;
                int gk = kk + k, gc = col0 + bln;
                float v = 0.f;
                if (gk < ke && gc < N) v = B[(size_t)gk * N + gc];
                Bs[k * LP + bln] = v;
            }
        } else {
#pragma unroll
            for (int i = 0; i < 4; i++) {
                int nn = alm + 16 * i;
                int gc = col0 + nn, gk = kk + alk;
                float v = 0.f;
                if (gc < N && gk < ke) v = B[(size_t)gc * K + gk];
                Bs[alk * LP + nn] = v;
            }
        }
        __syncthreads();
#pragma unroll
        for (int k = 0; k < 16; k++) {
            float4 a4 = *(const float4*)&As[k * LP + ty * 4];
            float4 b4 = *(const float4*)&Bs[k * LP + tx * 4];
            float av[4] = {a4.x, a4.y, a4.z, a4.w};
            float bv[4] = {b4.x, b4.y, b4.z, b4.w};
#pragma unroll
            for (int i = 0; i < 4; i++)
#pragma unroll
                for (int j = 0; j < 4; j++) acc[i][j] += av[i] * bv[j];
        }
        __syncthreads();
    }

    if (gridDim.z > 1) {
        float* P = Cout + (size_t)blockIdx.z * M * N;
#pragma unroll
        for (int i = 0; i < 4; i++) {
            int gr = row0 + ty * 4 + i;
            if (gr >= M) continue;
#pragma unroll
            for (int j = 0; j < 4; j++) {
                int gc = col0 + tx * 4 + j;
                if (gc < N) P[(size_t)gr * N + gc] = acc[i][j];
            }
        }
    } else {
#pragma unroll
        for (int i = 0; i < 4; i++) {
            int gr = row0 + ty * 4 + i;
            if (gr >= M) continue;
#pragma unroll
            for (int j = 0; j < 4; j++) {
                int gc = col0 + tx * 4 + j;
                if (gc >= N) continue;
                float v = acc[i][j];
                if (bias) v += bias[gc];
                if (epi == 1) v = fmaxf(v, 0.f);
                else if (epi == 2) v = tanhf(v);
                else if (epi == 3) v = 1.f / (1.f + expf(-v));
                Cout[(size_t)gr * N + gc] = v;
            }
        }
    }
}

// ================= split-K reduce for fc =================
__global__ void k_fcreduce(const float* __restrict__ part, const float* __restrict__ bias,
                           float* __restrict__ out) {
    int i = blockIdx.x * 256 + threadIdx.x;
    if (i >= BSZ * HD) return;
    float s = 0.f;
    for (int z = 0; z < SPLITK; z++) s += part[(size_t)z * BSZ * HD + i];
    s += bias[i & (HD - 1)];
    out[i] = fmaxf(s, 0.f);
}

// ================= ent_out = ent + c1 + c2 =================
__global__ void k_entout(const float* __restrict__ ent, const float* __restrict__ c1,
                         const float* __restrict__ c2, float* __restrict__ out) {
    int i = blockIdx.x * 256 + threadIdx.x;
    if (i < N_ENTS * HD) out[i] = ent[i] + c1[i] + c2[i];
}

// ================= matvec over K=200: out[r] = A[r,:] . w + b =================
__global__ void k_matvec200(const float* __restrict__ A, const float* __restrict__ w,
                            const float* __restrict__ b, float* __restrict__ out, int M) {
    int r = blockIdx.x * 4 + (threadIdx.x >> 6);
    int lane = threadIdx.x & 63;
    if (r >= M) return;
    float s = 0.f;
    for (int k = lane; k < HIDD; k += 64) s += A[(size_t)r * HIDD + k] * w[k];
    for (int o = 32; o; o >>= 1) s += __shfl_xor(s, o, 64);
    if (lane == 0) out[r] = s + b[0];
}

// ================= corr =================
__global__ void k_corr1(const float* __restrict__ x1, const float* __restrict__ x2,
                        float* __restrict__ red) {
    __shared__ float sa[1024], sb[1024];
    int t = threadIdx.x;
    float s1 = 0.f, s2 = 0.f;
    for (int i = t; i < N_ENTS; i += 1024) { s1 += x1[i]; s2 += x2[i]; }
    sa[t] = s1; sb[t] = s2; __syncthreads();
    for (int o = 512; o > 0; o >>= 1) {
        if (t < o) { sa[t] += sa[t + o]; sb[t] += sb[t + o]; }
        __syncthreads();
    }
    if (t == 0) { red[0] = sa[0] / (float)N_ENTS; red[1] = sb[0] / (float)N_ENTS; }
}

__global__ void k_corr2(const float* __restrict__ x1, const float* __restrict__ x2,
                        const float* __restrict__ red, float* __restrict__ out) {
    __shared__ float s11[1024], s22[1024], s12[1024];
    int t = threadIdx.x;
    float m1 = red[0], m2 = red[1];
    float a11 = 0.f, a22 = 0.f, a12 = 0.f;
    for (int i = t; i < N_ENTS; i += 1024) {
        float a = x1[i] - m1, b = x2[i] - m2;
        a11 += a * a; a22 += b * b; a12 += a * b;
    }
    s11[t] = a11; s22[t] = a22; s12[t] = a12; __syncthreads();
    for (int o = 512; o > 0; o >>= 1) {
        if (t < o) { s11[t] += s11[t + o]; s22[t] += s22[t + o]; s12[t] += s12[t + o]; }
        __syncthreads();
    }
    if (t == 0) {
        float v11 = s11[0] / (float)N_ENTS, v22 = s22[0] / (float)N_ENTS, v12 = s12[0] / (float)N_ENTS;
        out[0] = fabsf(v12) / (sqrtf(v11) * sqrtf(v22));
    }
}

// ================= ConvE conv (block per batch elem) =================
__global__ void k_conv(const int* __restrict__ h_id, const int* __restrict__ r_id,
                       const float* __restrict__ entout, const float* __restrict__ prel,
                       const float* __restrict__ cw, const float* __restrict__ cb,
                       float* __restrict__ out) {
    __shared__ float img[256];
    __shared__ float filt[C_CH * 49];
    int b = blockIdx.x, tid = threadIdx.x;
    if (tid < 128) img[tid] = entout[(size_t)h_id[b] * HD + tid];
    else           img[tid] = prel[(size_t)r_id[b] * HD + (tid - 128)];
    for (int i = tid; i < C_CH * 49; i += 256) filt[i] = cw[i];
    __syncthreads();
    for (int idx = tid; idx < FLATD; idx += 256) {
        int o = idx / 100, rem = idx % 100, i = rem / 10, j = rem % 10;
        float acc = cb[o];
        const float* f = &filt[o * 49];
#pragma unroll
        for (int ki = 0; ki < 7; ki++)
#pragma unroll
            for (int kj = 0; kj < 7; kj++)
                acc += img[(i + ki) * 16 + (j + kj)] * f[ki * 7 + kj];
        out[(size_t)b * FLATD + idx] = fmaxf(acc, 0.f);
    }
}

// ================= host launcher =================
extern "C" void kernel_launch(void* const* d_in, const int* in_sizes, int n_in,
                              void* d_out, int out_size, void* d_ws, size_t ws_size,
                              hipStream_t stream) {
    const int* h_id    = (const int*)d_in[0];
    const int* r_id    = (const int*)d_in[1];
    const int* src     = (const int*)d_in[2];
    const int* dst     = (const int*)d_in[3];
    const int* rel_id  = (const int*)d_in[4];
    const float* ent_emb  = (const float*)d_in[5];
    const float* rel_emb0 = (const float*)d_in[6];
    const float* neigh_w  = (const float*)d_in[7];
    const float* S_w = (const float*)d_in[8];
    const float* S_b = (const float*)d_in[9];
    const float* L_w = (const float*)d_in[10];
    const float* L_b = (const float*)d_in[11];
    const float* pred_rel = (const float*)d_in[12];
    const float* phi_w0 = (const float*)d_in[13]; const float* phi_b0 = (const float*)d_in[14];
    const float* phi_w1 = (const float*)d_in[15]; const float* phi_b1 = (const float*)d_in[16];
    const float* phi_w2 = (const float*)d_in[17]; const float* phi_b2 = (const float*)d_in[18];
    const float* psi_w0 = (const float*)d_in[19]; const float* psi_b0 = (const float*)d_in[20];
    const float* psi_w1 = (const float*)d_in[21]; const float* psi_b1 = (const float*)d_in[22];
    const float* psi_w2 = (const float*)d_in[23]; const float* psi_b2 = (const float*)d_in[24];
    const float* conv_w = (const float*)d_in[25]; const float* conv_b = (const float*)d_in[26];
    const float* fc_w   = (const float*)d_in[27]; const float* fc_b   = (const float*)d_in[28];
    const float* score_b= (const float*)d_in[29];

    float* W  = (float*)d_ws;
    int*   Wi = (int*)d_ws;
    float* common  = W + F_COMMON;
    float* privb   = W + F_PRIVATE;
    float* neigh1  = W + F_NEIGH1;
    float* neigh2  = W + F_NEIGH2;
    float* entout  = W + F_ENTOUT;
    float* score1  = W + F_SCORE1;
    float* score2  = W + F_SCORE2;
    float* w1      = W + F_W1;
    float* w2      = W + F_W2;
    int*   eorder  = Wi + I_EORDER;
    int*   deg     = Wi + I_DEG;
    int*   startp  = Wi + I_START;
    int*   cursor  = Wi + I_CURSOR;
    int*   bsum    = Wi + I_BSUM;
    float* red     = W + F_RED;
    float* xfc     = W + F_XFC;
    float* g1      = W + F_G1;
    float* g2      = W + F_G2;
    float* convout = W + F_CONVOUT;
    float* fcpart  = W + F_FCPART;
    float* x1      = W + F_X1;
    float* x2      = W + F_X2;
    float* outf    = (float*)d_out;

    // ---- projections: common/private ----
    k_gemm<0><<<dim3(782, 2, 1), 256, 0, stream>>>(ent_emb, S_w, S_b, common, N_ENTS, HD, HD, HD, 0);
    k_gemm<0><<<dim3(782, 2, 1), 256, 0, stream>>>(ent_emb, L_w, L_b, privb,  N_ENTS, HD, HD, HD, 0);

    // ---- CSR build ----
    hipMemsetAsync(deg, 0, N_ENTS * sizeof(int), stream);
    hipMemsetAsync(cursor, 0, N_ENTS * sizeof(int), stream);
    k_deg<<<dim3((E_EDGES + 255) / 256), 256, 0, stream>>>(dst, deg);
    int nscan = (N_ENTS + 255) / 256;   // 196
    k_scan1<<<dim3(nscan), 256, 0, stream>>>(deg, startp, bsum, N_ENTS);
    k_scan2<<<dim3(1), 1024, 0, stream>>>(bsum, nscan);
    k_scan3<<<dim3(nscan), 256, 0, stream>>>(startp, bsum, N_ENTS);
    k_scatter<<<dim3((E_EDGES + 255) / 256), 256, 0, stream>>>(dst, startp, cursor, eorder);
    k_sortseg<<<dim3(nscan), 256, 0, stream>>>(startp, deg, eorder);

    // ---- edge scores, softmax, topk, aggregate (both layers fused) ----
    k_scores<<<dim3(E_EDGES / 4), 256, 0, stream>>>(eorder, src, dst, rel_id, common, privb,
                                                    rel_emb0, score1, score2);
    k_softmax<<<dim3((N_ENTS + 3) / 4), 256, 0, stream>>>(startp, deg, score1, score2);
    k_topk<<<dim3((E_EDGES + 255) / 256), 256, 0, stream>>>(eorder, dst, startp, deg,
                                                            score1, score2, w1, w2);
    k_agg<<<dim3((N_ENTS + 3) / 4), 256, 0, stream>>>(eorder, src, rel_id, startp, deg,
                                                      w1, w2, common, privb, rel_emb0,
                                                      neigh1, neigh2);

    // ---- c1/c2 = tanh(neigh @ neigh_w); overwrite common/private buffers ----
    k_gemm<0><<<dim3(782, 2, 1), 256, 0, stream>>>(neigh1, neigh_w, nullptr, common, N_ENTS, HD, HD, HD, 2);
    k_gemm<0><<<dim3(782, 2, 1), 256, 0, stream>>>(neigh2, neigh_w, nullptr, privb,  N_ENTS, HD, HD, HD, 2);
    float* c1 = common;
    float* c2 = privb;

    // ---- ent_out ----
    k_entout<<<dim3((N_ENTS * HD + 255) / 256), 256, 0, stream>>>(ent_emb, c1, c2, entout);

    // ---- MLPs (phi on c1 -> x1, psi on c2 -> x2), processed in 2 row-halves ----
    for (int half = 0; half < 2; half++) {
        int M = 25000, roff = half * 25000;
        k_gemm<0><<<dim3(391, 4, 1), 256, 0, stream>>>(c1 + (size_t)roff * HD, phi_w0, phi_b0, g1, M, HIDD, HD, HD, 1);
        k_gemm<0><<<dim3(391, 4, 1), 256, 0, stream>>>(g1, phi_w1, phi_b1, g2, M, HIDD, HIDD, HIDD, 1);
        k_matvec200<<<dim3((M + 3) / 4), 256, 0, stream>>>(g2, phi_w2, phi_b2, x1 + roff, M);
    }
    for (int half = 0; half < 2; half++) {
        int M = 25000, roff = half * 25000;
        k_gemm<0><<<dim3(391, 4, 1), 256, 0, stream>>>(c2 + (size_t)roff * HD, psi_w0, psi_b0, g1, M, HIDD, HD, HD, 1);
        k_gemm<0><<<dim3(391, 4, 1), 256, 0, stream>>>(g1, psi_w1, psi_b1, g2, M, HIDD, HIDD, HIDD, 1);
        k_matvec200<<<dim3((M + 3) / 4), 256, 0, stream>>>(g2, psi_w2, psi_b2, x2 + roff, M);
    }

    // ---- corr -> d_out[51200000] ----
    k_corr1<<<dim3(1), 1024, 0, stream>>>(x1, x2, red);
    k_corr2<<<dim3(1), 1024, 0, stream>>>(x1, x2, red, outf + OUT_SCORE);

    // ---- ConvE: conv -> fc(split-K) -> score GEMM (sigmoid) ----
    k_conv<<<dim3(BSZ), 256, 0, stream>>>(h_id, r_id, entout, pred_rel, conv_w, conv_b, convout);
    k_gemm<0><<<dim3(16, 2, SPLITK), 256, 0, stream>>>(convout, fc_w, nullptr, fcpart,
                                                       BSZ, HD, FLATD, FLATD / SPLITK, 0);
    k_fcreduce<<<dim3((BSZ * HD + 255) / 256), 256, 0, stream>>>(fcpart, fc_b, xfc);
    k_gemm<1><<<dim3(16, 782, 1), 256, 0, stream>>>(xfc, entout, score_b, outf,
                                                    BSZ, N_ENTS, HD, HD, 3);
}

// Round 2
// 1190.860 us; speedup vs baseline: 1.5736x; 1.5736x over previous
//
#include <hip/hip_runtime.h>
#include <math.h>

typedef unsigned short ushort;
typedef unsigned int   uint;
typedef short bf16x8 __attribute__((ext_vector_type(8)));
typedef float f32x4  __attribute__((ext_vector_type(4)));

// ---------------- problem constants ----------------
#define N_ENTS   50000
#define E_EDGES  800000
#define HD       128
#define BSZ      1024
#define C_CH     96
#define FLATD    9600
#define TOPK_K   15
#define HIDD     200
#define SPLITK   10
#define OUT_SCORE ((size_t)BSZ * N_ENTS)

#define MPAD     50048            // 391*128
#define NPAD_ENT 50176            // 196*256  (score GEMM B rows)
#define KPAD200  224              // 200 -> 7*32
#define NPAD200  256

// ---------------- workspace layout (byte offsets) ----------------
#define OFF_ENT      ((size_t)0)            // ushort [50048][128]
#define OFF_COMMON   ((size_t)12812288)     // ushort [50048][128]  -> c1
#define OFF_PRIV     ((size_t)25624576)     // ushort [50048][128]  -> c2
#define OFF_ENTOUT   ((size_t)38436864)     // ushort [50176][128]
#define OFF_RELBF    ((size_t)51281920)     // ushort [1000][128]
#define OFF_PRELBF   ((size_t)51537920)     // ushort [1000][128]
#define OFF_SWT      ((size_t)51793920)     // ushort [128][128]
#define OFF_LWT      ((size_t)51826688)
#define OFF_NWT      ((size_t)51859456)
#define OFF_P0T      ((size_t)51892224)     // ushort [256][128]
#define OFF_Q0T      ((size_t)51957760)
#define OFF_P1T      ((size_t)52023296)     // ushort [256][224]
#define OFF_Q1T      ((size_t)52137984)
#define OFF_FCT      ((size_t)52252672)     // ushort [128][9600]
#define OFF_S1       ((size_t)54710272)     // float [800000]
#define OFF_S2       ((size_t)57910272)
#define OFF_W1       ((size_t)61110272)
#define OFF_W2       ((size_t)64310272)
#define OFF_EORD     ((size_t)67510272)     // int [800000]
#define OFF_DEG      ((size_t)70710272)     // int [50000]
#define OFF_START    ((size_t)70910272)
#define OFF_CUR      ((size_t)71110272)
#define OFF_BSUM     ((size_t)71310272)     // int [1024]
#define OFF_X1       ((size_t)71314368)     // float [50000]
#define OFF_X2       ((size_t)71514368)
#define OFF_RED      ((size_t)71714368)     // float [64]
#define OFF_XFC      ((size_t)71714624)     // ushort [1024][128]
#define OFF_ARENA    ((size_t)71976768)     // 44,843,008 bytes
#define ARENA_BYTES  ((size_t)44843008)
// arena sub-layout (phase-ordered):
//   neigh1_bf = ARENA+0 (ushort[50048][128]), neigh2_bf = ARENA+12812288
//   g1 = ARENA+0 (ushort[50048][224]), g2 = ARENA+22421504
//   convout = ARENA+0 (ushort[1024][9600]), fcpart = ARENA+22421504 (float[10][1024][128])

// ---------------- bf16 helpers ----------------
__device__ inline ushort f2b(float f) {
    uint u = __float_as_uint(f);
    return (ushort)((u + 0x7fffu + ((u >> 16) & 1u)) >> 16);  // RNE
}
__device__ inline float b2f(ushort u) { return __uint_as_float((uint)u << 16); }
__device__ inline float2 up2(uint u) {
    return make_float2(__uint_as_float(u << 16), __uint_as_float(u & 0xffff0000u));
}

// ---------------- conversion kernels ----------------
// f32 [M][K] -> bf16 [Mpad][K] (pad rows zero)
__global__ void k_cvt(const float* __restrict__ in, ushort* __restrict__ out,
                      int M, int Mpad, int K) {
    int i = blockIdx.x * 256 + threadIdx.x;
    if (i >= Mpad * K) return;
    int r = i / K;
    out[i] = (r < M) ? f2b(in[i]) : (ushort)0;
}

// f32 [K][N] -> bf16 [Npad][Kpad], out[n][k]=in[k][n], pads zero
__global__ void k_tcvt(const float* __restrict__ in, ushort* __restrict__ out,
                       int K, int N, int Kpad, int Npad) {
    int i = blockIdx.x * 256 + threadIdx.x;
    if (i >= Npad * Kpad) return;
    int n = i / Kpad, k = i % Kpad;
    out[i] = (n < N && k < K) ? f2b(in[(size_t)k * N + n]) : (ushort)0;
}

// ================= MFMA bf16 GEMM =================
// C[M,N] = epi(A[M,*lda] @ Bt[N,*ldb]^T + bias)
// A bf16 row-major (row clamp to M-1), Bt bf16 row-major N x K, rows padded so
// unmasked fragment loads stay in-bounds. K multiple of 32.
// gridDim.z>1: split-K f32 partials at Cout + z*M*ldc (no bias/epi).
// epi: 0 none, 1 relu, 2 tanh, 3 sigmoid. OUTBF: 1 -> bf16 out, 0 -> f32 out.
template <int WM, int WN, int OUTBF>
__global__ __launch_bounds__(256) void k_mgemm(
    const ushort* __restrict__ A, int lda,
    const ushort* __restrict__ Bt, int ldb,
    const float* __restrict__ bias, void* __restrict__ Cout, int ldc,
    int M, int N, int K, int kChunk, int epi) {
    const int w = threadIdx.x >> 6, lane = threadIdx.x & 63;
    const int wr = w / WN, wc = w % WN;
    const int row0 = blockIdx.x * (WM * 64) + wr * 64;
    const int col0 = blockIdx.y * (WN * 64) + wc * 64;
    const int lr = lane & 15;
    const int kg = (lane >> 4) * 8;
    const int kb = blockIdx.z * kChunk;
    const int ke = kb + kChunk;

    f32x4 acc[4][4];
#pragma unroll
    for (int i = 0; i < 4; i++)
#pragma unroll
        for (int j = 0; j < 4; j++) acc[i][j] = (f32x4){0.f, 0.f, 0.f, 0.f};

    for (int kk = kb; kk < ke; kk += 32) {
        bf16x8 af[4], bfr[4];
#pragma unroll
        for (int i = 0; i < 4; i++) {
            int r = row0 + i * 16 + lr;
            r = min(r, M - 1);
            af[i] = *(const bf16x8*)(A + (size_t)r * lda + kk + kg);
        }
#pragma unroll
        for (int j = 0; j < 4; j++) {
            int c = col0 + j * 16 + lr;   // Bt rows padded: no clamp
            bfr[j] = *(const bf16x8*)(Bt + (size_t)c * ldb + kk + kg);
        }
#pragma unroll
        for (int i = 0; i < 4; i++)
#pragma unroll
            for (int j = 0; j < 4; j++)
                acc[i][j] = __builtin_amdgcn_mfma_f32_16x16x32_bf16(af[i], bfr[j], acc[i][j], 0, 0, 0);
    }

    const int cr = (lane >> 4) * 4, cc = lane & 15;
    if (gridDim.z > 1) {
        float* P = (float*)Cout + (size_t)blockIdx.z * M * ldc;
#pragma unroll
        for (int i = 0; i < 4; i++)
#pragma unroll
            for (int j = 0; j < 4; j++) {
                int col = col0 + j * 16 + cc;
                if (col >= N) continue;
#pragma unroll
                for (int t = 0; t < 4; t++) {
                    int row = row0 + i * 16 + cr + t;
                    if (row < M) P[(size_t)row * ldc + col] = acc[i][j][t];
                }
            }
    } else {
#pragma unroll
        for (int i = 0; i < 4; i++)
#pragma unroll
            for (int j = 0; j < 4; j++) {
                int col = col0 + j * 16 + cc;
                if (col >= N) continue;
                float bi = bias ? bias[col] : 0.f;
#pragma unroll
                for (int t = 0; t < 4; t++) {
                    int row = row0 + i * 16 + cr + t;
                    if (row >= M) continue;
                    float v = acc[i][j][t] + bi;
                    if (epi == 1) v = fmaxf(v, 0.f);
                    else if (epi == 2) v = tanhf(v);
                    else if (epi == 3) v = 1.f / (1.f + expf(-v));
                    if (OUTBF) ((ushort*)Cout)[(size_t)row * ldc + col] = f2b(v);
                    else       ((float*)Cout)[(size_t)row * ldc + col] = v;
                }
            }
    }
}

// ================= CSR build =================
__global__ void k_deg(const int* __restrict__ dst, int* __restrict__ deg) {
    int e = blockIdx.x * 256 + threadIdx.x;
    if (e < E_EDGES) atomicAdd(&deg[dst[e]], 1);
}

__global__ void k_scan1(const int* __restrict__ in, int* __restrict__ out,
                        int* __restrict__ bsum, int n) {
    __shared__ int sh[256];
    int i = blockIdx.x * 256 + threadIdx.x;
    int v = (i < n) ? in[i] : 0;
    sh[threadIdx.x] = v; __syncthreads();
    for (int off = 1; off < 256; off <<= 1) {
        int t = (threadIdx.x >= off) ? sh[threadIdx.x - off] : 0;
        __syncthreads();
        sh[threadIdx.x] += t;
        __syncthreads();
    }
    if (i < n) out[i] = sh[threadIdx.x] - v;
    if (threadIdx.x == 255) bsum[blockIdx.x] = sh[255];
}

__global__ void k_scan2(int* __restrict__ bsum, int nb) {
    __shared__ int sh[1024];
    int t = threadIdx.x;
    int v = (t < nb) ? bsum[t] : 0;
    sh[t] = v; __syncthreads();
    for (int off = 1; off < 1024; off <<= 1) {
        int u = (t >= off) ? sh[t - off] : 0;
        __syncthreads();
        sh[t] += u;
        __syncthreads();
    }
    if (t < nb) bsum[t] = sh[t] - v;
}

__global__ void k_scan3(int* __restrict__ out, const int* __restrict__ bsum, int n) {
    int i = blockIdx.x * 256 + threadIdx.x;
    if (i < n) out[i] += bsum[blockIdx.x];
}

__global__ void k_scatter(const int* __restrict__ dst, const int* __restrict__ start,
                          int* __restrict__ cursor, int* __restrict__ eorder) {
    int e = blockIdx.x * 256 + threadIdx.x;
    if (e < E_EDGES) {
        int n = dst[e];
        int p = start[n] + atomicAdd(&cursor[n], 1);
        eorder[p] = e;
    }
}

__global__ void k_sortseg(const int* __restrict__ start, const int* __restrict__ deg,
                          int* __restrict__ eorder) {
    int n = blockIdx.x * 256 + threadIdx.x;
    if (n >= N_ENTS) return;
    int b = start[n], d = deg[n];
    for (int i = 1; i < d; i++) {
        int key = eorder[b + i];
        int j = i - 1;
        while (j >= 0 && eorder[b + j] > key) { eorder[b + j + 1] = eorder[b + j]; j--; }
        eorder[b + j + 1] = key;
    }
}

// ================= edge scores (bf16 gathers) =================
__global__ void k_scores(const int* __restrict__ eorder, const int* __restrict__ src,
                         const int* __restrict__ dst, const int* __restrict__ rel_id,
                         const ushort* __restrict__ common, const ushort* __restrict__ priv,
                         const ushort* __restrict__ rel,
                         float* __restrict__ s1, float* __restrict__ s2) {
    int slot = blockIdx.x * 4 + (threadIdx.x >> 6);
    int lane = threadIdx.x & 63;
    if (slot >= E_EDGES) return;
    int e = eorder[slot];
    const uint* cs = (const uint*)common + (size_t)src[e] * 64;
    const uint* cd = (const uint*)common + (size_t)dst[e] * 64;
    const uint* ps = (const uint*)priv   + (size_t)src[e] * 64;
    const uint* pd = (const uint*)priv   + (size_t)dst[e] * 64;
    const uint* rr = (const uint*)rel    + (size_t)rel_id[e] * 64;
    float2 r2 = up2(rr[lane]);
    float2 c1 = up2(cs[lane]), c2 = up2(cd[lane]);
    float2 p1 = up2(ps[lane]), p2 = up2(pd[lane]);
    float a = c1.x * r2.x * c2.x + c1.y * r2.y * c2.y;
    float b = p1.x * r2.x * p2.x + p1.y * r2.y * p2.y;
    for (int m = 32; m; m >>= 1) { a += __shfl_xor(a, m, 64); b += __shfl_xor(b, m, 64); }
    if (lane == 0) { s1[slot] = a; s2[slot] = b; }
}

// ================= fused softmax + top-15 -> pruned weights =================
__global__ void k_softtop(const int* __restrict__ start, const int* __restrict__ deg,
                          const float* __restrict__ s1, const float* __restrict__ s2,
                          float* __restrict__ w1, float* __restrict__ w2) {
    int n = blockIdx.x * 4 + (threadIdx.x >> 6);
    int lane = threadIdx.x & 63;
    if (n >= N_ENTS) return;
    int b = start[n], d = deg[n];
    if (d == 0) return;
    float m1 = -INFINITY, m2 = -INFINITY;
    for (int i = lane; i < d; i += 64) { m1 = fmaxf(m1, s1[b + i]); m2 = fmaxf(m2, s2[b + i]); }
    for (int o = 32; o; o >>= 1) { m1 = fmaxf(m1, __shfl_xor(m1, o, 64)); m2 = fmaxf(m2, __shfl_xor(m2, o, 64)); }
    float z1 = 0.f, z2 = 0.f;
    for (int i = lane; i < d; i += 64) { z1 += expf(s1[b + i] - m1); z2 += expf(s2[b + i] - m2); }
    for (int o = 32; o; o >>= 1) { z1 += __shfl_xor(z1, o, 64); z2 += __shfl_xor(z2, o, 64); }
    for (int i = lane; i < d; i += 64) {
        float my1 = expf(s1[b + i] - m1) / z1;
        float my2 = expf(s2[b + i] - m2) / z2;
        int r1 = 0, r2 = 0;
        for (int j = 0; j < d; j++) {
            float v1 = expf(s1[b + j] - m1) / z1;
            float v2 = expf(s2[b + j] - m2) / z2;
            r1 += (v1 > my1) || (v1 == my1 && j < i);   // segment sorted by edge id
            r2 += (v2 > my2) || (v2 == my2 && j < i);
        }
        w1[b + i] = (r1 < TOPK_K) ? my1 : 0.f;
        w2[b + i] = (r2 < TOPK_K) ? my2 : 0.f;
    }
}

// ================= weighted aggregation (bf16 gathers, bf16 out) =================
__global__ void k_agg(const int* __restrict__ eorder, const int* __restrict__ src,
                      const int* __restrict__ rel_id,
                      const int* __restrict__ start, const int* __restrict__ deg,
                      const float* __restrict__ w1, const float* __restrict__ w2,
                      const ushort* __restrict__ common, const ushort* __restrict__ priv,
                      const ushort* __restrict__ rel,
                      ushort* __restrict__ neigh1, ushort* __restrict__ neigh2) {
    int n = blockIdx.x * 4 + (threadIdx.x >> 6);
    int lane = threadIdx.x & 63;
    if (n >= N_ENTS) return;
    int b = start[n], d = deg[n];
    float2 a1 = make_float2(0.f, 0.f), a2 = make_float2(0.f, 0.f);
    for (int s = b; s < b + d; s++) {
        float x1 = w1[s], x2 = w2[s];
        if (x1 == 0.f && x2 == 0.f) continue;
        int e = eorder[s];
        const uint* cs = (const uint*)common + (size_t)src[e] * 64;
        const uint* ps = (const uint*)priv   + (size_t)src[e] * 64;
        const uint* rr = (const uint*)rel    + (size_t)rel_id[e] * 64;
        float2 r2 = up2(rr[lane]);
        float2 c1 = up2(cs[lane]);
        float2 p1 = up2(ps[lane]);
        a1.x += x1 * c1.x * r2.x; a1.y += x1 * c1.y * r2.y;
        a2.x += x2 * p1.x * r2.x; a2.y += x2 * p1.y * r2.y;
    }
    uint o1 = (uint)f2b(a1.x) | ((uint)f2b(a1.y) << 16);
    uint o2 = (uint)f2b(a2.x) | ((uint)f2b(a2.y) << 16);
    ((uint*)(neigh1 + (size_t)n * HD))[lane] = o1;
    ((uint*)(neigh2 + (size_t)n * HD))[lane] = o2;
}

// ================= ent_out (bf16, padded rows zero) =================
__global__ void k_entout(const float* __restrict__ ent, const ushort* __restrict__ c1,
                         const ushort* __restrict__ c2, ushort* __restrict__ out) {
    int i = blockIdx.x * 256 + threadIdx.x;
    if (i >= NPAD_ENT * HD) return;
    int r = i >> 7;
    float v = 0.f;
    if (r < N_ENTS) v = ent[i] + b2f(c1[i]) + b2f(c2[i]);
    out[i] = (r < N_ENTS) ? f2b(v) : (ushort)0;
}

// ================= matvec over K=200 (bf16 A) =================
__global__ void k_matvec(const ushort* __restrict__ A, int lda, const float* __restrict__ w,
                         const float* __restrict__ b, float* __restrict__ out, int M) {
    int r = blockIdx.x * 4 + (threadIdx.x >> 6);
    int lane = threadIdx.x & 63;
    if (r >= M) return;
    float s = 0.f;
    for (int k = lane; k < HIDD; k += 64) s += b2f(A[(size_t)r * lda + k]) * w[k];
    for (int o = 32; o; o >>= 1) s += __shfl_xor(s, o, 64);
    if (lane == 0) out[r] = s + b[0];
}

// ================= corr =================
__global__ void k_corr1(const float* __restrict__ x1, const float* __restrict__ x2,
                        float* __restrict__ red) {
    __shared__ float sa[1024], sb[1024];
    int t = threadIdx.x;
    float s1 = 0.f, s2 = 0.f;
    for (int i = t; i < N_ENTS; i += 1024) { s1 += x1[i]; s2 += x2[i]; }
    sa[t] = s1; sb[t] = s2; __syncthreads();
    for (int o = 512; o > 0; o >>= 1) {
        if (t < o) { sa[t] += sa[t + o]; sb[t] += sb[t + o]; }
        __syncthreads();
    }
    if (t == 0) { red[0] = sa[0] / (float)N_ENTS; red[1] = sb[0] / (float)N_ENTS; }
}

__global__ void k_corr2(const float* __restrict__ x1, const float* __restrict__ x2,
                        const float* __restrict__ red, float* __restrict__ out) {
    __shared__ float s11[1024], s22[1024], s12[1024];
    int t = threadIdx.x;
    float m1 = red[0], m2 = red[1];
    float a11 = 0.f, a22 = 0.f, a12 = 0.f;
    for (int i = t; i < N_ENTS; i += 1024) {
        float a = x1[i] - m1, b = x2[i] - m2;
        a11 += a * a; a22 += b * b; a12 += a * b;
    }
    s11[t] = a11; s22[t] = a22; s12[t] = a12; __syncthreads();
    for (int o = 512; o > 0; o >>= 1) {
        if (t < o) { s11[t] += s11[t + o]; s22[t] += s22[t + o]; s12[t] += s12[t + o]; }
        __syncthreads();
    }
    if (t == 0) {
        float v11 = s11[0] / (float)N_ENTS, v22 = s22[0] / (float)N_ENTS, v12 = s12[0] / (float)N_ENTS;
        out[0] = fabsf(v12) / (sqrtf(v11) * sqrtf(v22));
    }
}

// ================= ConvE conv (bf16 img inputs, bf16 out) =================
__global__ void k_conv(const int* __restrict__ h_id, const int* __restrict__ r_id,
                       const ushort* __restrict__ entout, const ushort* __restrict__ prel,
                       const float* __restrict__ cw, const float* __restrict__ cb,
                       ushort* __restrict__ out) {
    __shared__ float img[256];
    __shared__ float filt[C_CH * 49];
    int b = blockIdx.x, tid = threadIdx.x;
    if (tid < 128) img[tid] = b2f(entout[(size_t)h_id[b] * HD + tid]);
    else           img[tid] = b2f(prel[(size_t)r_id[b] * HD + (tid - 128)]);
    for (int i = tid; i < C_CH * 49; i += 256) filt[i] = cw[i];
    __syncthreads();
    for (int idx = tid; idx < FLATD; idx += 256) {
        int o = idx / 100, rem = idx % 100, i = rem / 10, j = rem % 10;
        float acc = cb[o];
        const float* f = &filt[o * 49];
#pragma unroll
        for (int ki = 0; ki < 7; ki++)
#pragma unroll
            for (int kj = 0; kj < 7; kj++)
                acc += img[(i + ki) * 16 + (j + kj)] * f[ki * 7 + kj];
        out[(size_t)b * FLATD + idx] = f2b(fmaxf(acc, 0.f));
    }
}

// ================= split-K reduce for fc -> bf16 xfc =================
__global__ void k_fcreduce(const float* __restrict__ part, const float* __restrict__ bias,
                           ushort* __restrict__ out) {
    int i = blockIdx.x * 256 + threadIdx.x;
    if (i >= BSZ * HD) return;
    float s = 0.f;
    for (int z = 0; z < SPLITK; z++) s += part[(size_t)z * BSZ * HD + i];
    s += bias[i & (HD - 1)];
    out[i] = f2b(fmaxf(s, 0.f));
}

// ================= host launcher =================
extern "C" void kernel_launch(void* const* d_in, const int* in_sizes, int n_in,
                              void* d_out, int out_size, void* d_ws, size_t ws_size,
                              hipStream_t stream) {
    const int* h_id    = (const int*)d_in[0];
    const int* r_id    = (const int*)d_in[1];
    const int* src     = (const int*)d_in[2];
    const int* dst     = (const int*)d_in[3];
    const int* rel_id  = (const int*)d_in[4];
    const float* ent_emb  = (const float*)d_in[5];
    const float* rel_emb0 = (const float*)d_in[6];
    const float* neigh_w  = (const float*)d_in[7];
    const float* S_w = (const float*)d_in[8];
    const float* S_b = (const float*)d_in[9];
    const float* L_w = (const float*)d_in[10];
    const float* L_b = (const float*)d_in[11];
    const float* pred_rel = (const float*)d_in[12];
    const float* phi_w0 = (const float*)d_in[13]; const float* phi_b0 = (const float*)d_in[14];
    const float* phi_w1 = (const float*)d_in[15]; const float* phi_b1 = (const float*)d_in[16];
    const float* phi_w2 = (const float*)d_in[17]; const float* phi_b2 = (const float*)d_in[18];
    const float* psi_w0 = (const float*)d_in[19]; const float* psi_b0 = (const float*)d_in[20];
    const float* psi_w1 = (const float*)d_in[21]; const float* psi_b1 = (const float*)d_in[22];
    const float* psi_w2 = (const float*)d_in[23]; const float* psi_b2 = (const float*)d_in[24];
    const float* conv_w = (const float*)d_in[25]; const float* conv_b = (const float*)d_in[26];
    const float* fc_w   = (const float*)d_in[27]; const float* fc_b   = (const float*)d_in[28];
    const float* score_b= (const float*)d_in[29];

    char* base = (char*)d_ws;
    ushort* ent_bf   = (ushort*)(base + OFF_ENT);
    ushort* common_bf= (ushort*)(base + OFF_COMMON);
    ushort* priv_bf  = (ushort*)(base + OFF_PRIV);
    ushort* entout_bf= (ushort*)(base + OFF_ENTOUT);
    ushort* rel_bf   = (ushort*)(base + OFF_RELBF);
    ushort* prel_bf  = (ushort*)(base + OFF_PRELBF);
    ushort* Swt      = (ushort*)(base + OFF_SWT);
    ushort* Lwt      = (ushort*)(base + OFF_LWT);
    ushort* nWt      = (ushort*)(base + OFF_NWT);
    ushort* p0t      = (ushort*)(base + OFF_P0T);
    ushort* q0t      = (ushort*)(base + OFF_Q0T);
    ushort* p1t      = (ushort*)(base + OFF_P1T);
    ushort* q1t      = (ushort*)(base + OFF_Q1T);
    ushort* fct      = (ushort*)(base + OFF_FCT);
    float*  s1       = (float*)(base + OFF_S1);
    float*  s2       = (float*)(base + OFF_S2);
    float*  w1       = (float*)(base + OFF_W1);
    float*  w2       = (float*)(base + OFF_W2);
    int*    eorder   = (int*)(base + OFF_EORD);
    int*    deg      = (int*)(base + OFF_DEG);
    int*    startp   = (int*)(base + OFF_START);
    int*    cursor   = (int*)(base + OFF_CUR);
    int*    bsum     = (int*)(base + OFF_BSUM);
    float*  x1       = (float*)(base + OFF_X1);
    float*  x2       = (float*)(base + OFF_X2);
    float*  red      = (float*)(base + OFF_RED);
    ushort* xfc_bf   = (ushort*)(base + OFF_XFC);
    ushort* neigh1_bf= (ushort*)(base + OFF_ARENA);
    ushort* neigh2_bf= (ushort*)(base + OFF_ARENA + 12812288);
    ushort* g1       = (ushort*)(base + OFF_ARENA);
    ushort* g2       = (ushort*)(base + OFF_ARENA + 22421504);
    ushort* convout  = (ushort*)(base + OFF_ARENA);
    float*  fcpart   = (float*)(base + OFF_ARENA + 22421504);
    float*  outf     = (float*)d_out;

    // ---- phase 0: conversions & weight transposes ----
    k_cvt<<<dim3((MPAD * HD + 255) / 256), 256, 0, stream>>>(ent_emb, ent_bf, N_ENTS, MPAD, HD);
    k_cvt<<<dim3((1000 * HD + 255) / 256), 256, 0, stream>>>(rel_emb0, rel_bf, 1000, 1000, HD);
    k_cvt<<<dim3((1000 * HD + 255) / 256), 256, 0, stream>>>(pred_rel, prel_bf, 1000, 1000, HD);
    k_tcvt<<<dim3((128 * 128 + 255) / 256), 256, 0, stream>>>(S_w, Swt, 128, 128, 128, 128);
    k_tcvt<<<dim3((128 * 128 + 255) / 256), 256, 0, stream>>>(L_w, Lwt, 128, 128, 128, 128);
    k_tcvt<<<dim3((128 * 128 + 255) / 256), 256, 0, stream>>>(neigh_w, nWt, 128, 128, 128, 128);
    k_tcvt<<<dim3((NPAD200 * 128 + 255) / 256), 256, 0, stream>>>(phi_w0, p0t, 128, HIDD, 128, NPAD200);
    k_tcvt<<<dim3((NPAD200 * 128 + 255) / 256), 256, 0, stream>>>(psi_w0, q0t, 128, HIDD, 128, NPAD200);
    k_tcvt<<<dim3((NPAD200 * KPAD200 + 255) / 256), 256, 0, stream>>>(phi_w1, p1t, HIDD, HIDD, KPAD200, NPAD200);
    k_tcvt<<<dim3((NPAD200 * KPAD200 + 255) / 256), 256, 0, stream>>>(psi_w1, q1t, HIDD, HIDD, KPAD200, NPAD200);
    k_tcvt<<<dim3((128 * FLATD + 255) / 256), 256, 0, stream>>>(fc_w, fct, FLATD, 128, FLATD, 128);

    // ---- phase 1: projections (bf16 MFMA) ----
    k_mgemm<2,2,1><<<dim3(391, 1, 1), 256, 0, stream>>>(ent_bf, HD, Swt, HD, S_b, common_bf, HD, N_ENTS, HD, HD, HD, 0);
    k_mgemm<2,2,1><<<dim3(391, 1, 1), 256, 0, stream>>>(ent_bf, HD, Lwt, HD, L_b, priv_bf,   HD, N_ENTS, HD, HD, HD, 0);

    // ---- phase 2: CSR build ----
    hipMemsetAsync(deg, 0, N_ENTS * sizeof(int), stream);
    hipMemsetAsync(cursor, 0, N_ENTS * sizeof(int), stream);
    k_deg<<<dim3((E_EDGES + 255) / 256), 256, 0, stream>>>(dst, deg);
    int nscan = (N_ENTS + 255) / 256;
    k_scan1<<<dim3(nscan), 256, 0, stream>>>(deg, startp, bsum, N_ENTS);
    k_scan2<<<dim3(1), 1024, 0, stream>>>(bsum, nscan);
    k_scan3<<<dim3(nscan), 256, 0, stream>>>(startp, bsum, N_ENTS);
    k_scatter<<<dim3((E_EDGES + 255) / 256), 256, 0, stream>>>(dst, startp, cursor, eorder);
    k_sortseg<<<dim3(nscan), 256, 0, stream>>>(startp, deg, eorder);

    // ---- phase 3-5: edge pipeline ----
    k_scores<<<dim3(E_EDGES / 4), 256, 0, stream>>>(eorder, src, dst, rel_id, common_bf, priv_bf, rel_bf, s1, s2);
    k_softtop<<<dim3((N_ENTS + 3) / 4), 256, 0, stream>>>(startp, deg, s1, s2, w1, w2);
    k_agg<<<dim3((N_ENTS + 3) / 4), 256, 0, stream>>>(eorder, src, rel_id, startp, deg, w1, w2,
                                                      common_bf, priv_bf, rel_bf, neigh1_bf, neigh2_bf);

    // ---- phase 6: c1/c2 = tanh(neigh @ W)  (overwrite common/priv slots) ----
    k_mgemm<2,2,1><<<dim3(391, 1, 1), 256, 0, stream>>>(neigh1_bf, HD, nWt, HD, nullptr, common_bf, HD, N_ENTS, HD, HD, HD, 2);
    k_mgemm<2,2,1><<<dim3(391, 1, 1), 256, 0, stream>>>(neigh2_bf, HD, nWt, HD, nullptr, priv_bf,   HD, N_ENTS, HD, HD, HD, 2);
    ushort* c1_bf = common_bf;
    ushort* c2_bf = priv_bf;

    // ---- phase 7: ent_out (bf16, padded) ----
    k_entout<<<dim3((NPAD_ENT * HD + 255) / 256), 256, 0, stream>>>(ent_emb, c1_bf, c2_bf, entout_bf);

    // ---- phase 8: MLPs (arena -> g1/g2); memset clears K-pad columns ----
    hipMemsetAsync((void*)g1, 0, ARENA_BYTES, stream);
    k_mgemm<2,2,1><<<dim3(391, 2, 1), 256, 0, stream>>>(c1_bf, HD, p0t, HD, phi_b0, g1, KPAD200, N_ENTS, HIDD, HD, HD, 1);
    k_mgemm<2,2,1><<<dim3(391, 2, 1), 256, 0, stream>>>(g1, KPAD200, p1t, KPAD200, phi_b1, g2, KPAD200, N_ENTS, HIDD, KPAD200, KPAD200, 1);
    k_matvec<<<dim3((N_ENTS + 3) / 4), 256, 0, stream>>>(g2, KPAD200, phi_w2, phi_b2, x1, N_ENTS);
    k_mgemm<2,2,1><<<dim3(391, 2, 1), 256, 0, stream>>>(c2_bf, HD, q0t, HD, psi_b0, g1, KPAD200, N_ENTS, HIDD, HD, HD, 1);
    k_mgemm<2,2,1><<<dim3(391, 2, 1), 256, 0, stream>>>(g1, KPAD200, q1t, KPAD200, psi_b1, g2, KPAD200, N_ENTS, HIDD, KPAD200, KPAD200, 1);
    k_matvec<<<dim3((N_ENTS + 3) / 4), 256, 0, stream>>>(g2, KPAD200, psi_w2, psi_b2, x2, N_ENTS);

    // ---- phase 9: corr ----
    k_corr1<<<dim3(1), 1024, 0, stream>>>(x1, x2, red);
    k_corr2<<<dim3(1), 1024, 0, stream>>>(x1, x2, red, outf + OUT_SCORE);

    // ---- phase 10-11: ConvE ----
    k_conv<<<dim3(BSZ), 256, 0, stream>>>(h_id, r_id, entout_bf, prel_bf, conv_w, conv_b, convout);
    k_mgemm<2,2,0><<<dim3(8, 1, SPLITK), 256, 0, stream>>>(convout, FLATD, fct, FLATD, nullptr, fcpart, HD,
                                                           BSZ, HD, FLATD, FLATD / SPLITK, 0);
    k_fcreduce<<<dim3((BSZ * HD + 255) / 256), 256, 0, stream>>>(fcpart, fc_b, xfc_bf);

    // ---- phase 12: score GEMM (bf16 MFMA, sigmoid, f32 out) ----
    k_mgemm<1,4,0><<<dim3(16, 196, 1), 256, 0, stream>>>(xfc_bf, HD, entout_bf, HD, score_b, outf, N_ENTS,
                                                         BSZ, N_ENTS, HD, HD, 3);
}

// Round 3
// 1081.336 us; speedup vs baseline: 1.7330x; 1.1013x over previous
//
#include <hip/hip_runtime.h>
#include <math.h>

typedef unsigned short ushort;
typedef unsigned int   uint;
typedef short bf16x8 __attribute__((ext_vector_type(8)));
typedef float f32x4  __attribute__((ext_vector_type(4)));
typedef ushort u16x8 __attribute__((ext_vector_type(8)));
typedef ushort u16x4 __attribute__((ext_vector_type(4)));

// ---------------- problem constants ----------------
#define N_ENTS   50000
#define E_EDGES  800000
#define HD       128
#define BSZ      1024
#define C_CH     96
#define FLATD    9600
#define TOPK_K   15
#define HIDD     200
#define SPLITK   10
#define OUT_SCORE ((size_t)BSZ * N_ENTS)

#define MPAD     50048            // 391*128
#define NPAD_ENT 50176            // 196*256
#define KPAD200  224
#define NPAD200  256

// ---------------- workspace layout (byte offsets) ----------------
#define OFF_EP       ((size_t)0)            // ushort [50048][256] interleaved c/p (c1/c2 alias later)
#define OFF_ENTOUT   ((size_t)25624576)     // ushort [50176][128]
#define OFF_RELBF    ((size_t)38469632)     // ushort [1000][128]
#define OFF_PRELBF   ((size_t)38725632)
#define OFF_SWT      ((size_t)38981632)     // ushort [128][128]
#define OFF_LWT      ((size_t)39014400)
#define OFF_NWT      ((size_t)39047168)
#define OFF_P0T      ((size_t)39079936)     // ushort [256][128]
#define OFF_Q0T      ((size_t)39145472)
#define OFF_P1T      ((size_t)39211008)     // ushort [256][224]
#define OFF_Q1T      ((size_t)39325696)
#define OFF_FCT      ((size_t)39440384)     // ushort [128][9600]
#define OFF_SC       ((size_t)41897984)     // float2 [800000]
#define OFF_W        ((size_t)48297984)     // float2 [800000]
#define OFF_SIDX     ((size_t)54697984)     // int4 [800000]
#define OFF_EORD     ((size_t)67497984)     // int [800000]
#define OFF_DEG      ((size_t)70697984)     // int [50000]
#define OFF_START    ((size_t)70897984)
#define OFF_CUR      ((size_t)71097984)
#define OFF_BSUM     ((size_t)71297984)     // int [1024]
#define OFF_X1       ((size_t)71302080)     // float [50000]
#define OFF_X2       ((size_t)71502080)
#define OFF_RED      ((size_t)71702080)     // float [64]
#define OFF_XFC      ((size_t)71702336)     // ushort [1024][128]
#define OFF_ARENA    ((size_t)71964480)     // 44,843,008 bytes -> total 116,807,488
#define ARENA_BYTES  ((size_t)44843008)
// arena: neigh1=+0 (u16[50048][128]), neigh2=+12812288
//        g1=+0 (u16[50048][224]), g2=+22421504
//        convout=+0 (u16[1024][9600]), fcpart=+22421504 (f32[10][1024][128])
// c1 = EP+0 (u16[50048][128]), c2 = EP+12812288  (EP dead after k_agg)

// ---------------- bf16 helpers ----------------
__device__ inline ushort f2b(float f) {
    uint u = __float_as_uint(f);
    return (ushort)((u + 0x7fffu + ((u >> 16) & 1u)) >> 16);  // RNE
}
__device__ inline float b2f(ushort u) { return __uint_as_float((uint)u << 16); }

// ---------------- conversion kernels ----------------
__global__ void k_cvt(const float* __restrict__ in, ushort* __restrict__ out,
                      int M, int Mpad, int K) {
    int i = blockIdx.x * 256 + threadIdx.x;
    if (i >= Mpad * K) return;
    int r = i / K;
    out[i] = (r < M) ? f2b(in[i]) : (ushort)0;
}

// tiled transpose-convert: f32 in[K][N] -> bf16 out[Npad][Kpad], pads zero
__global__ __launch_bounds__(256) void k_tcvtT(const float* __restrict__ in, ushort* __restrict__ out,
                                               int K, int N, int Kpad, int Npad) {
    __shared__ float t[32][33];
    int k0 = blockIdx.x * 32, n0 = blockIdx.y * 32;
    int tx = threadIdx.x & 31, ty = threadIdx.x >> 5;   // ty 0..7
    for (int i = ty; i < 32; i += 8) {
        int k = k0 + i, n = n0 + tx;
        t[i][tx] = (k < K && n < N) ? in[(size_t)k * N + n] : 0.f;
    }
    __syncthreads();
    for (int i = ty; i < 32; i += 8) {
        int n = n0 + i, k = k0 + tx;
        if (n < Npad && k < Kpad) out[(size_t)n * Kpad + k] = f2b(t[tx][i]);
    }
}

// ================= MFMA bf16 GEMM =================
// C[M,N] = epi(A[M,*lda] @ Bt[N,*ldb]^T + bias); K mult of 32.
// iofs<0: normal store; iofs in {0,2}: interleaved bf16 store (ep table).
// gridDim.z>1: split-K f32 partials. epi: 0 none,1 relu,2 tanh,3 sigmoid.
template <int WM, int WN, int OUTBF>
__global__ __launch_bounds__(256) void k_mgemm(
    const ushort* __restrict__ A, int lda,
    const ushort* __restrict__ Bt, int ldb,
    const float* __restrict__ bias, void* __restrict__ Cout, int ldc,
    int M, int N, int K, int kChunk, int epi, int iofs) {
    const int w = threadIdx.x >> 6, lane = threadIdx.x & 63;
    const int wr = w / WN, wc = w % WN;
    const int row0 = blockIdx.x * (WM * 64) + wr * 64;
    const int col0 = blockIdx.y * (WN * 64) + wc * 64;
    const int lr = lane & 15;
    const int kg = (lane >> 4) * 8;
    const int kb = blockIdx.z * kChunk;
    const int ke = kb + kChunk;

    f32x4 acc[4][4];
#pragma unroll
    for (int i = 0; i < 4; i++)
#pragma unroll
        for (int j = 0; j < 4; j++) acc[i][j] = (f32x4){0.f, 0.f, 0.f, 0.f};

    for (int kk = kb; kk < ke; kk += 32) {
        bf16x8 af[4], bfr[4];
#pragma unroll
        for (int i = 0; i < 4; i++) {
            int r = row0 + i * 16 + lr;
            r = min(r, M - 1);
            af[i] = *(const bf16x8*)(A + (size_t)r * lda + kk + kg);
        }
#pragma unroll
        for (int j = 0; j < 4; j++) {
            int c = col0 + j * 16 + lr;
            bfr[j] = *(const bf16x8*)(Bt + (size_t)c * ldb + kk + kg);
        }
#pragma unroll
        for (int i = 0; i < 4; i++)
#pragma unroll
            for (int j = 0; j < 4; j++)
                acc[i][j] = __builtin_amdgcn_mfma_f32_16x16x32_bf16(af[i], bfr[j], acc[i][j], 0, 0, 0);
    }

    const int cr = (lane >> 4) * 4, cc = lane & 15;
    if (gridDim.z > 1) {
        float* P = (float*)Cout + (size_t)blockIdx.z * M * ldc;
#pragma unroll
        for (int i = 0; i < 4; i++)
#pragma unroll
            for (int j = 0; j < 4; j++) {
                int col = col0 + j * 16 + cc;
                if (col >= N) continue;
#pragma unroll
                for (int t = 0; t < 4; t++) {
                    int row = row0 + i * 16 + cr + t;
                    if (row < M) P[(size_t)row * ldc + col] = acc[i][j][t];
                }
            }
    } else {
#pragma unroll
        for (int i = 0; i < 4; i++)
#pragma unroll
            for (int j = 0; j < 4; j++) {
                int col = col0 + j * 16 + cc;
                if (col >= N) continue;
                float bi = bias ? bias[col] : 0.f;
#pragma unroll
                for (int t = 0; t < 4; t++) {
                    int row = row0 + i * 16 + cr + t;
                    if (row >= M) continue;
                    float v = acc[i][j][t] + bi;
                    if (epi == 1) v = fmaxf(v, 0.f);
                    else if (epi == 2) v = tanhf(v);
                    else if (epi == 3) v = 1.f / (1.f + expf(-v));
                    if (OUTBF) {
                        size_t idx = (iofs < 0) ? ((size_t)row * ldc + col)
                                   : ((size_t)row * ldc + ((size_t)(col >> 1) << 2) + (col & 1) + iofs);
                        ((ushort*)Cout)[idx] = f2b(v);
                    } else {
                        ((float*)Cout)[(size_t)row * ldc + col] = v;
                    }
                }
            }
    }
}

// ================= CSR build =================
__global__ void k_deg(const int* __restrict__ dst, int* __restrict__ deg) {
    int e = blockIdx.x * 256 + threadIdx.x;
    if (e < E_EDGES) atomicAdd(&deg[dst[e]], 1);
}

__global__ void k_scan1(const int* __restrict__ in, int* __restrict__ out,
                        int* __restrict__ bsum, int n) {
    __shared__ int sh[256];
    int i = blockIdx.x * 256 + threadIdx.x;
    int v = (i < n) ? in[i] : 0;
    sh[threadIdx.x] = v; __syncthreads();
    for (int off = 1; off < 256; off <<= 1) {
        int t = (threadIdx.x >= off) ? sh[threadIdx.x - off] : 0;
        __syncthreads();
        sh[threadIdx.x] += t;
        __syncthreads();
    }
    if (i < n) out[i] = sh[threadIdx.x] - v;
    if (threadIdx.x == 255) bsum[blockIdx.x] = sh[255];
}

__global__ void k_scan2(int* __restrict__ bsum, int nb) {
    __shared__ int sh[1024];
    int t = threadIdx.x;
    int v = (t < nb) ? bsum[t] : 0;
    sh[t] = v; __syncthreads();
    for (int off = 1; off < 1024; off <<= 1) {
        int u = (t >= off) ? sh[t - off] : 0;
        __syncthreads();
        sh[t] += u;
        __syncthreads();
    }
    if (t < nb) bsum[t] = sh[t] - v;
}

__global__ void k_scan3(int* __restrict__ out, const int* __restrict__ bsum, int n) {
    int i = blockIdx.x * 256 + threadIdx.x;
    if (i < n) out[i] += bsum[blockIdx.x];
}

__global__ void k_scatter(const int* __restrict__ dst, const int* __restrict__ start,
                          int* __restrict__ cursor, int* __restrict__ eorder) {
    int e = blockIdx.x * 256 + threadIdx.x;
    if (e < E_EDGES) {
        int n = dst[e];
        int p = start[n] + atomicAdd(&cursor[n], 1);
        eorder[p] = e;
    }
}

__global__ void k_sortseg(const int* __restrict__ start, const int* __restrict__ deg,
                          int* __restrict__ eorder) {
    int n = blockIdx.x * 256 + threadIdx.x;
    if (n >= N_ENTS) return;
    int b = start[n], d = deg[n];
    for (int i = 1; i < d; i++) {
        int key = eorder[b + i];
        int j = i - 1;
        while (j >= 0 && eorder[b + j] > key) { eorder[b + j + 1] = eorder[b + j]; j--; }
        eorder[b + j + 1] = key;
    }
}

__global__ void k_mkidx(const int* __restrict__ eorder, const int* __restrict__ src,
                        const int* __restrict__ dst, const int* __restrict__ rel_id,
                        int4* __restrict__ sidx) {
    int slot = blockIdx.x * 256 + threadIdx.x;
    if (slot < E_EDGES) {
        int e = eorder[slot];
        sidx[slot] = make_int4(src[e], dst[e], rel_id[e], e);
    }
}

// ================= edge scores: 16 lanes/edge, 4 edges/wave =================
__global__ __launch_bounds__(256) void k_scores(
    const int4* __restrict__ sidx, const ushort* __restrict__ ep,
    const ushort* __restrict__ rel, float2* __restrict__ sc) {
    int g = threadIdx.x >> 4, l = threadIdx.x & 15;
    int slot = blockIdx.x * 16 + g;
    int4 si = sidx[slot];
    const ushort* rs = ep + (size_t)si.x * 256 + l * 16;
    const ushort* rd = ep + (size_t)si.y * 256 + l * 16;
    const ushort* rr = rel + (size_t)si.z * 128 + l * 8;
    u16x8 s0 = *(const u16x8*)rs, s1v = *(const u16x8*)(rs + 8);
    u16x8 d0 = *(const u16x8*)rd, d1v = *(const u16x8*)(rd + 8);
    u16x8 rv = *(const u16x8*)rr;
    // group layout: {c[2G],c[2G+1],p[2G],p[2G+1]} per 4 elems
    float a = 0.f, b = 0.f;
#pragma unroll
    for (int G = 0; G < 2; G++) {
        float r0 = b2f(rv[2*G]), r1 = b2f(rv[2*G+1]);
        a += b2f(s0[4*G])   * r0 * b2f(d0[4*G])   + b2f(s0[4*G+1]) * r1 * b2f(d0[4*G+1]);
        b += b2f(s0[4*G+2]) * r0 * b2f(d0[4*G+2]) + b2f(s0[4*G+3]) * r1 * b2f(d0[4*G+3]);
    }
#pragma unroll
    for (int G = 0; G < 2; G++) {
        float r0 = b2f(rv[4+2*G]), r1 = b2f(rv[5+2*G]);
        a += b2f(s1v[4*G])   * r0 * b2f(d1v[4*G])   + b2f(s1v[4*G+1]) * r1 * b2f(d1v[4*G+1]);
        b += b2f(s1v[4*G+2]) * r0 * b2f(d1v[4*G+2]) + b2f(s1v[4*G+3]) * r1 * b2f(d1v[4*G+3]);
    }
#pragma unroll
    for (int m = 8; m; m >>= 1) { a += __shfl_xor(a, m, 64); b += __shfl_xor(b, m, 64); }
    if (l == 0) sc[slot] = make_float2(a, b);
}

// ================= softmax + top-15 (rank by raw score; exp monotone) =================
__global__ void k_softtop(const int* __restrict__ start, const int* __restrict__ deg,
                          const float2* __restrict__ sc, float2* __restrict__ w) {
    int n = blockIdx.x * 4 + (threadIdx.x >> 6);
    int lane = threadIdx.x & 63;
    if (n >= N_ENTS) return;
    int b = start[n], d = deg[n];
    if (d == 0) return;
    float m1 = -INFINITY, m2 = -INFINITY;
    for (int i = lane; i < d; i += 64) {
        float2 s = sc[b + i];
        m1 = fmaxf(m1, s.x); m2 = fmaxf(m2, s.y);
    }
    for (int o = 32; o; o >>= 1) { m1 = fmaxf(m1, __shfl_xor(m1, o, 64)); m2 = fmaxf(m2, __shfl_xor(m2, o, 64)); }
    float z1 = 0.f, z2 = 0.f;
    for (int i = lane; i < d; i += 64) {
        float2 s = sc[b + i];
        z1 += expf(s.x - m1); z2 += expf(s.y - m2);
    }
    for (int o = 32; o; o >>= 1) { z1 += __shfl_xor(z1, o, 64); z2 += __shfl_xor(z2, o, 64); }
    for (int i = lane; i < d; i += 64) {
        float2 sp = sc[b + i];
        int r1 = 0, r2 = 0;
        for (int j = 0; j < d; j++) {
            float2 sq = sc[b + j];
            r1 += (sq.x > sp.x) || (sq.x == sp.x && j < i);
            r2 += (sq.y > sp.y) || (sq.y == sp.y && j < i);
        }
        w[b + i] = make_float2(r1 < TOPK_K ? expf(sp.x - m1) / z1 : 0.f,
                               r2 < TOPK_K ? expf(sp.y - m2) / z2 : 0.f);
    }
}

// ================= weighted aggregation (pipelined, wave/node) =================
__global__ __launch_bounds__(256) void k_agg(
    const int4* __restrict__ sidx, const int* __restrict__ start, const int* __restrict__ deg,
    const float2* __restrict__ w, const ushort* __restrict__ ep, const ushort* __restrict__ rel,
    ushort* __restrict__ neigh1, ushort* __restrict__ neigh2) {
    int n = blockIdx.x * 4 + (threadIdx.x >> 6);
    int g = threadIdx.x & 63;
    if (n >= N_ENTS) return;
    int b = start[n], d = deg[n];
    float2 a1 = make_float2(0.f, 0.f), a2 = make_float2(0.f, 0.f);
    if (d > 0) {
        int end = b + d;
        int4 si0 = sidx[b];
        int4 si1 = (d > 1) ? sidx[b + 1] : si0;
        float2 w0 = w[b];
        u16x4 v0 = *(const u16x4*)(ep + (size_t)si0.x * 256 + g * 4);
        uint  r0 = *(const uint*)(rel + (size_t)si0.z * 128 + g * 2);
        for (int s = b; s < end; s++) {
            int4 si2 = (s + 2 < end) ? sidx[s + 2] : si1;
            float2 w1v = (s + 1 < end) ? w[s + 1] : make_float2(0.f, 0.f);
            u16x4 v1 = *(const u16x4*)(ep + (size_t)si1.x * 256 + g * 4);
            uint  r1 = *(const uint*)(rel + (size_t)si1.z * 128 + g * 2);
            float rx = b2f((ushort)(r0 & 0xffffu)), ry = b2f((ushort)(r0 >> 16));
            a1.x += w0.x * b2f(v0[0]) * rx;  a1.y += w0.x * b2f(v0[1]) * ry;
            a2.x += w0.y * b2f(v0[2]) * rx;  a2.y += w0.y * b2f(v0[3]) * ry;
            v0 = v1; r0 = r1; si1 = si2; w0 = w1v;
        }
    }
    uint o1 = (uint)f2b(a1.x) | ((uint)f2b(a1.y) << 16);
    uint o2 = (uint)f2b(a2.x) | ((uint)f2b(a2.y) << 16);
    ((uint*)(neigh1 + (size_t)n * HD))[g] = o1;
    ((uint*)(neigh2 + (size_t)n * HD))[g] = o2;
}

// ================= ent_out (bf16, padded rows zero) =================
__global__ void k_entout(const float* __restrict__ ent, const ushort* __restrict__ c1,
                         const ushort* __restrict__ c2, ushort* __restrict__ out) {
    int i = blockIdx.x * 256 + threadIdx.x;
    if (i >= NPAD_ENT * HD) return;
    int r = i >> 7;
    float v = 0.f;
    if (r < N_ENTS) v = ent[i] + b2f(c1[i]) + b2f(c2[i]);
    out[i] = (r < N_ENTS) ? f2b(v) : (ushort)0;
}

// ================= matvec over K=200 (bf16 A) =================
__global__ void k_matvec(const ushort* __restrict__ A, int lda, const float* __restrict__ w,
                         const float* __restrict__ b, float* __restrict__ out, int M) {
    int r = blockIdx.x * 4 + (threadIdx.x >> 6);
    int lane = threadIdx.x & 63;
    if (r >= M) return;
    float s = 0.f;
    for (int k = lane; k < HIDD; k += 64) s += b2f(A[(size_t)r * lda + k]) * w[k];
    for (int o = 32; o; o >>= 1) s += __shfl_xor(s, o, 64);
    if (lane == 0) out[r] = s + b[0];
}

// ================= corr =================
__global__ void k_corr1(const float* __restrict__ x1, const float* __restrict__ x2,
                        float* __restrict__ red) {
    __shared__ float sa[1024], sb[1024];
    int t = threadIdx.x;
    float s1 = 0.f, s2 = 0.f;
    for (int i = t; i < N_ENTS; i += 1024) { s1 += x1[i]; s2 += x2[i]; }
    sa[t] = s1; sb[t] = s2; __syncthreads();
    for (int o = 512; o > 0; o >>= 1) {
        if (t < o) { sa[t] += sa[t + o]; sb[t] += sb[t + o]; }
        __syncthreads();
    }
    if (t == 0) { red[0] = sa[0] / (float)N_ENTS; red[1] = sb[0] / (float)N_ENTS; }
}

__global__ void k_corr2(const float* __restrict__ x1, const float* __restrict__ x2,
                        const float* __restrict__ red, float* __restrict__ out) {
    __shared__ float s11[1024], s22[1024], s12[1024];
    int t = threadIdx.x;
    float m1 = red[0], m2 = red[1];
    float a11 = 0.f, a22 = 0.f, a12 = 0.f;
    for (int i = t; i < N_ENTS; i += 1024) {
        float a = x1[i] - m1, b = x2[i] - m2;
        a11 += a * a; a22 += b * b; a12 += a * b;
    }
    s11[t] = a11; s22[t] = a22; s12[t] = a12; __syncthreads();
    for (int o = 512; o > 0; o >>= 1) {
        if (t < o) { s11[t] += s11[t + o]; s22[t] += s22[t + o]; s12[t] += s12[t + o]; }
        __syncthreads();
    }
    if (t == 0) {
        float v11 = s11[0] / (float)N_ENTS, v22 = s22[0] / (float)N_ENTS, v12 = s12[0] / (float)N_ENTS;
        out[0] = fabsf(v12) / (sqrtf(v11) * sqrtf(v22));
    }
}

// ================= ConvE conv =================
__global__ void k_conv(const int* __restrict__ h_id, const int* __restrict__ r_id,
                       const ushort* __restrict__ entout, const ushort* __restrict__ prel,
                       const float* __restrict__ cw, const float* __restrict__ cb,
                       ushort* __restrict__ out) {
    __shared__ float img[256];
    __shared__ float filt[C_CH * 49];
    int b = blockIdx.x, tid = threadIdx.x;
    if (tid < 128) img[tid] = b2f(entout[(size_t)h_id[b] * HD + tid]);
    else           img[tid] = b2f(prel[(size_t)r_id[b] * HD + (tid - 128)]);
    for (int i = tid; i < C_CH * 49; i += 256) filt[i] = cw[i];
    __syncthreads();
    for (int idx = tid; idx < FLATD; idx += 256) {
        int o = idx / 100, rem = idx % 100, i = rem / 10, j = rem % 10;
        float acc = cb[o];
        const float* f = &filt[o * 49];
#pragma unroll
        for (int ki = 0; ki < 7; ki++)
#pragma unroll
            for (int kj = 0; kj < 7; kj++)
                acc += img[(i + ki) * 16 + (j + kj)] * f[ki * 7 + kj];
        out[(size_t)b * FLATD + idx] = f2b(fmaxf(acc, 0.f));
    }
}

// ================= split-K reduce for fc =================
__global__ void k_fcreduce(const float* __restrict__ part, const float* __restrict__ bias,
                           ushort* __restrict__ out) {
    int i = blockIdx.x * 256 + threadIdx.x;
    if (i >= BSZ * HD) return;
    float s = 0.f;
    for (int z = 0; z < SPLITK; z++) s += part[(size_t)z * BSZ * HD + i];
    s += bias[i & (HD - 1)];
    out[i] = f2b(fmaxf(s, 0.f));
}

// ================= host launcher =================
extern "C" void kernel_launch(void* const* d_in, const int* in_sizes, int n_in,
                              void* d_out, int out_size, void* d_ws, size_t ws_size,
                              hipStream_t stream) {
    const int* h_id    = (const int*)d_in[0];
    const int* r_id    = (const int*)d_in[1];
    const int* src     = (const int*)d_in[2];
    const int* dst     = (const int*)d_in[3];
    const int* rel_id  = (const int*)d_in[4];
    const float* ent_emb  = (const float*)d_in[5];
    const float* rel_emb0 = (const float*)d_in[6];
    const float* neigh_w  = (const float*)d_in[7];
    const float* S_w = (const float*)d_in[8];
    const float* S_b = (const float*)d_in[9];
    const float* L_w = (const float*)d_in[10];
    const float* L_b = (const float*)d_in[11];
    const float* pred_rel = (const float*)d_in[12];
    const float* phi_w0 = (const float*)d_in[13]; const float* phi_b0 = (const float*)d_in[14];
    const float* phi_w1 = (const float*)d_in[15]; const float* phi_b1 = (const float*)d_in[16];
    const float* phi_w2 = (const float*)d_in[17]; const float* phi_b2 = (const float*)d_in[18];
    const float* psi_w0 = (const float*)d_in[19]; const float* psi_b0 = (const float*)d_in[20];
    const float* psi_w1 = (const float*)d_in[21]; const float* psi_b1 = (const float*)d_in[22];
    const float* psi_w2 = (const float*)d_in[23]; const float* psi_b2 = (const float*)d_in[24];
    const float* conv_w = (const float*)d_in[25]; const float* conv_b = (const float*)d_in[26];
    const float* fc_w   = (const float*)d_in[27]; const float* fc_b   = (const float*)d_in[28];
    const float* score_b= (const float*)d_in[29];

    char* base = (char*)d_ws;
    ushort* ep       = (ushort*)(base + OFF_EP);
    ushort* entout_bf= (ushort*)(base + OFF_ENTOUT);
    ushort* rel_bf   = (ushort*)(base + OFF_RELBF);
    ushort* prel_bf  = (ushort*)(base + OFF_PRELBF);
    ushort* Swt      = (ushort*)(base + OFF_SWT);
    ushort* Lwt      = (ushort*)(base + OFF_LWT);
    ushort* nWt      = (ushort*)(base + OFF_NWT);
    ushort* p0t      = (ushort*)(base + OFF_P0T);
    ushort* q0t      = (ushort*)(base + OFF_Q0T);
    ushort* p1t      = (ushort*)(base + OFF_P1T);
    ushort* q1t      = (ushort*)(base + OFF_Q1T);
    ushort* fct      = (ushort*)(base + OFF_FCT);
    float2* sc       = (float2*)(base + OFF_SC);
    float2* wpair    = (float2*)(base + OFF_W);
    int4*   sidx     = (int4*)(base + OFF_SIDX);
    int*    eorder   = (int*)(base + OFF_EORD);
    int*    deg      = (int*)(base + OFF_DEG);
    int*    startp   = (int*)(base + OFF_START);
    int*    cursor   = (int*)(base + OFF_CUR);
    int*    bsum     = (int*)(base + OFF_BSUM);
    float*  x1       = (float*)(base + OFF_X1);
    float*  x2       = (float*)(base + OFF_X2);
    float*  red      = (float*)(base + OFF_RED);
    ushort* xfc_bf   = (ushort*)(base + OFF_XFC);
    ushort* c1_bf    = (ushort*)(base + OFF_EP);                 // alias (ep dead after agg)
    ushort* c2_bf    = (ushort*)(base + OFF_EP + 12812288);
    ushort* ent_bf   = (ushort*)(base + OFF_ARENA);              // temp: arena before neigh use
    ushort* neigh1_bf= (ushort*)(base + OFF_ARENA);
    ushort* neigh2_bf= (ushort*)(base + OFF_ARENA + 12812288);
    ushort* g1       = (ushort*)(base + OFF_ARENA);
    ushort* g2       = (ushort*)(base + OFF_ARENA + 22421504);
    ushort* convout  = (ushort*)(base + OFF_ARENA);
    float*  fcpart   = (float*)(base + OFF_ARENA + 22421504);
    float*  outf     = (float*)d_out;

    // NOTE: ent_bf shares arena with neigh1; projections (reading ent_bf) finish
    // before k_agg (writing neigh1)?  NO — k_agg writes neigh over ent_bf region,
    // and projections are long done by then.  Order: cvt->proj (reads ent_bf) ->
    // edge pipeline -> agg writes neigh (ent_bf dead).  Safe.

    // ---- phase 0: conversions & weight transposes ----
    k_cvt<<<dim3((MPAD * HD + 255) / 256), 256, 0, stream>>>(ent_emb, ent_bf, N_ENTS, MPAD, HD);
    k_cvt<<<dim3((1000 * HD + 255) / 256), 256, 0, stream>>>(rel_emb0, rel_bf, 1000, 1000, HD);
    k_cvt<<<dim3((1000 * HD + 255) / 256), 256, 0, stream>>>(pred_rel, prel_bf, 1000, 1000, HD);
    k_tcvtT<<<dim3(4, 4), 256, 0, stream>>>(S_w, Swt, 128, 128, 128, 128);
    k_tcvtT<<<dim3(4, 4), 256, 0, stream>>>(L_w, Lwt, 128, 128, 128, 128);
    k_tcvtT<<<dim3(4, 4), 256, 0, stream>>>(neigh_w, nWt, 128, 128, 128, 128);
    k_tcvtT<<<dim3(4, 8), 256, 0, stream>>>(phi_w0, p0t, 128, HIDD, 128, NPAD200);
    k_tcvtT<<<dim3(4, 8), 256, 0, stream>>>(psi_w0, q0t, 128, HIDD, 128, NPAD200);
    k_tcvtT<<<dim3(7, 8), 256, 0, stream>>>(phi_w1, p1t, HIDD, HIDD, KPAD200, NPAD200);
    k_tcvtT<<<dim3(7, 8), 256, 0, stream>>>(psi_w1, q1t, HIDD, HIDD, KPAD200, NPAD200);
    k_tcvtT<<<dim3(300, 4), 256, 0, stream>>>(fc_w, fct, FLATD, 128, FLATD, 128);

    // ---- phase 1: projections -> interleaved ep table ----
    k_mgemm<2,2,1><<<dim3(391, 1, 1), 256, 0, stream>>>(ent_bf, HD, Swt, HD, S_b, ep, 256, N_ENTS, HD, HD, HD, 0, 0);
    k_mgemm<2,2,1><<<dim3(391, 1, 1), 256, 0, stream>>>(ent_bf, HD, Lwt, HD, L_b, ep, 256, N_ENTS, HD, HD, HD, 0, 2);

    // ---- phase 2: CSR build ----
    hipMemsetAsync(deg, 0, N_ENTS * sizeof(int), stream);
    hipMemsetAsync(cursor, 0, N_ENTS * sizeof(int), stream);
    k_deg<<<dim3((E_EDGES + 255) / 256), 256, 0, stream>>>(dst, deg);
    int nscan = (N_ENTS + 255) / 256;
    k_scan1<<<dim3(nscan), 256, 0, stream>>>(deg, startp, bsum, N_ENTS);
    k_scan2<<<dim3(1), 1024, 0, stream>>>(bsum, nscan);
    k_scan3<<<dim3(nscan), 256, 0, stream>>>(startp, bsum, N_ENTS);
    k_scatter<<<dim3((E_EDGES + 255) / 256), 256, 0, stream>>>(dst, startp, cursor, eorder);
    k_sortseg<<<dim3(nscan), 256, 0, stream>>>(startp, deg, eorder);
    k_mkidx<<<dim3((E_EDGES + 255) / 256), 256, 0, stream>>>(eorder, src, dst, rel_id, sidx);

    // ---- phase 3-5: edge pipeline ----
    k_scores<<<dim3(E_EDGES / 16), 256, 0, stream>>>(sidx, ep, rel_bf, sc);
    k_softtop<<<dim3((N_ENTS + 3) / 4), 256, 0, stream>>>(startp, deg, sc, wpair);
    k_agg<<<dim3((N_ENTS + 3) / 4), 256, 0, stream>>>(sidx, startp, deg, wpair, ep, rel_bf,
                                                      neigh1_bf, neigh2_bf);

    // ---- phase 6: c1/c2 = tanh(neigh @ W)  (write over dead ep) ----
    k_mgemm<2,2,1><<<dim3(391, 1, 1), 256, 0, stream>>>(neigh1_bf, HD, nWt, HD, nullptr, c1_bf, HD, N_ENTS, HD, HD, HD, 2, -1);
    k_mgemm<2,2,1><<<dim3(391, 1, 1), 256, 0, stream>>>(neigh2_bf, HD, nWt, HD, nullptr, c2_bf, HD, N_ENTS, HD, HD, HD, 2, -1);

    // ---- phase 7: ent_out ----
    k_entout<<<dim3((NPAD_ENT * HD + 255) / 256), 256, 0, stream>>>(ent_emb, c1_bf, c2_bf, entout_bf);

    // ---- phase 8: MLPs ----
    hipMemsetAsync((void*)g1, 0, ARENA_BYTES, stream);
    k_mgemm<2,2,1><<<dim3(391, 2, 1), 256, 0, stream>>>(c1_bf, HD, p0t, HD, phi_b0, g1, KPAD200, N_ENTS, HIDD, HD, HD, 1, -1);
    k_mgemm<2,2,1><<<dim3(391, 2, 1), 256, 0, stream>>>(g1, KPAD200, p1t, KPAD200, phi_b1, g2, KPAD200, N_ENTS, HIDD, KPAD200, KPAD200, 1, -1);
    k_matvec<<<dim3((N_ENTS + 3) / 4), 256, 0, stream>>>(g2, KPAD200, phi_w2, phi_b2, x1, N_ENTS);
    k_mgemm<2,2,1><<<dim3(391, 2, 1), 256, 0, stream>>>(c2_bf, HD, q0t, HD, psi_b0, g1, KPAD200, N_ENTS, HIDD, HD, HD, 1, -1);
    k_mgemm<2,2,1><<<dim3(391, 2, 1), 256, 0, stream>>>(g1, KPAD200, q1t, KPAD200, psi_b1, g2, KPAD200, N_ENTS, HIDD, KPAD200, KPAD200, 1, -1);
    k_matvec<<<dim3((N_ENTS + 3) / 4), 256, 0, stream>>>(g2, KPAD200, psi_w2, psi_b2, x2, N_ENTS);

    // ---- phase 9: corr ----
    k_corr1<<<dim3(1), 1024, 0, stream>>>(x1, x2, red);
    k_corr2<<<dim3(1), 1024, 0, stream>>>(x1, x2, red, outf + OUT_SCORE);

    // ---- phase 10-11: ConvE ----
    k_conv<<<dim3(BSZ), 256, 0, stream>>>(h_id, r_id, entout_bf, prel_bf, conv_w, conv_b, convout);
    k_mgemm<2,2,0><<<dim3(8, 1, SPLITK), 256, 0, stream>>>(convout, FLATD, fct, FLATD, nullptr, fcpart, HD,
                                                           BSZ, HD, FLATD, FLATD / SPLITK, 0, -1);
    k_fcreduce<<<dim3((BSZ * HD + 255) / 256), 256, 0, stream>>>(fcpart, fc_b, xfc_bf);

    // ---- phase 12: score GEMM (B-panel re-read 4x instead of 16x) ----
    k_mgemm<4,1,0><<<dim3(4, 784, 1), 256, 0, stream>>>(xfc_bf, HD, entout_bf, HD, score_b, outf, N_ENTS,
                                                        BSZ, N_ENTS, HD, HD, 3, -1);
}

// Round 4
// 1018.821 us; speedup vs baseline: 1.8393x; 1.0614x over previous
//
#include <hip/hip_runtime.h>
#include <math.h>

typedef unsigned short ushort;
typedef unsigned int   uint;
typedef short bf16x8 __attribute__((ext_vector_type(8)));
typedef float f32x4  __attribute__((ext_vector_type(4)));
typedef ushort u16x8 __attribute__((ext_vector_type(8)));
typedef ushort u16x4 __attribute__((ext_vector_type(4)));

// ---------------- problem constants ----------------
#define N_ENTS   50000
#define E_EDGES  800000
#define HD       128
#define BSZ      1024
#define C_CH     96
#define FLATD    9600
#define TOPK_K   15
#define HIDD     200
#define SPLITK   10
#define OUT_SCORE ((size_t)BSZ * N_ENTS)

#define MPAD     50048            // 391*128
#define NPAD_ENT 50176            // 196*256
#define KPAD200  224
#define NPAD200  256

// ---------------- workspace layout (byte offsets) ----------------
#define OFF_EP       ((size_t)0)            // ushort [50048][256] interleaved c/p (c1/c2 alias later)
#define OFF_ENTOUT   ((size_t)25624576)     // ushort [50176][128]
#define OFF_RELBF    ((size_t)38469632)     // ushort [1000][128]
#define OFF_PRELBF   ((size_t)38725632)
#define OFF_SWT      ((size_t)38981632)     // ushort [128][128]
#define OFF_LWT      ((size_t)39014400)
#define OFF_NWT      ((size_t)39047168)
#define OFF_P0T      ((size_t)39079936)     // ushort [256][128]
#define OFF_Q0T      ((size_t)39145472)
#define OFF_P1T      ((size_t)39211008)     // ushort [256][224]
#define OFF_Q1T      ((size_t)39325696)
#define OFF_FCT      ((size_t)39440384)     // ushort [128][9600]
#define OFF_SC       ((size_t)41897984)     // float2 [800000]
#define OFF_W        ((size_t)48297984)     // float2 [800000]
#define OFF_SIDX     ((size_t)54697984)     // int4 [800000]
#define OFF_EORD     ((size_t)67497984)     // int [800000]
#define OFF_DEG      ((size_t)70697984)     // int [50000]
#define OFF_START    ((size_t)70897984)
#define OFF_CUR      ((size_t)71097984)
#define OFF_BSUM     ((size_t)71297984)     // int [1024]
#define OFF_X1       ((size_t)71302080)     // float [50000]
#define OFF_X2       ((size_t)71502080)
#define OFF_RED      ((size_t)71702080)     // float [64]
#define OFF_XFC      ((size_t)71702336)     // ushort [1024][128]
#define OFF_ARENA    ((size_t)71964480)     // 44,843,008 bytes -> total 116,807,488
#define ARENA_BYTES  ((size_t)44843008)
// arena: ent_bf=+0 (u16[50048][128]) [dead after proj]
//        neigh1=+0, neigh2=+12812288 [dead after tanh GEMMs]
//        g1=+0 (u16[50048][224]), g2=+22421504 [dead after matvecs]
//        convout=+0 (u16[1024][9600]), fcpart=+22421504 (f32[10][1024][128])
// c1 = EP+0 (u16[50048][128]), c2 = EP+12812288  (EP dead after k_agg)

// ---------------- bf16 helpers ----------------
__device__ inline ushort f2b(float f) {
    uint u = __float_as_uint(f);
    return (ushort)((u + 0x7fffu + ((u >> 16) & 1u)) >> 16);  // RNE
}
__device__ inline float b2f(ushort u) { return __uint_as_float((uint)u << 16); }

// ---------------- conversion kernels ----------------
__global__ void k_cvt(const float* __restrict__ in, ushort* __restrict__ out,
                      int M, int Mpad, int K) {
    int i = blockIdx.x * 256 + threadIdx.x;
    if (i >= Mpad * K) return;
    int r = i / K;
    out[i] = (r < M) ? f2b(in[i]) : (ushort)0;
}

// tiled transpose-convert: f32 in[K][N] -> bf16 out[Npad][Kpad], pads zero
__global__ __launch_bounds__(256) void k_tcvtT(const float* __restrict__ in, ushort* __restrict__ out,
                                               int K, int N, int Kpad, int Npad) {
    __shared__ float t[32][33];
    int k0 = blockIdx.x * 32, n0 = blockIdx.y * 32;
    int tx = threadIdx.x & 31, ty = threadIdx.x >> 5;   // ty 0..7
    for (int i = ty; i < 32; i += 8) {
        int k = k0 + i, n = n0 + tx;
        t[i][tx] = (k < K && n < N) ? in[(size_t)k * N + n] : 0.f;
    }
    __syncthreads();
    for (int i = ty; i < 32; i += 8) {
        int n = n0 + i, k = k0 + tx;
        if (n < Npad && k < Kpad) out[(size_t)n * Kpad + k] = f2b(t[tx][i]);
    }
}

// ================= MFMA bf16 GEMM =================
// C[M,N] = epi(A[M,*lda] @ Bt[N,*ldb]^T + bias); K mult of 32.
// iofs<0: normal store; iofs in {0,2}: interleaved bf16 store (ep table).
// npad: bf16 cols in [N, npad) are stored as literal 0 (K-pad zeroing).
// gridDim.z>1: split-K f32 partials. epi: 0 none,1 relu,2 tanh,3 sigmoid.
template <int WM, int WN, int OUTBF>
__global__ __launch_bounds__(256) void k_mgemm(
    const ushort* __restrict__ A, int lda,
    const ushort* __restrict__ Bt, int ldb,
    const float* __restrict__ bias, void* __restrict__ Cout, int ldc,
    int M, int N, int K, int kChunk, int epi, int iofs, int npad) {
    const int w = threadIdx.x >> 6, lane = threadIdx.x & 63;
    const int wr = w / WN, wc = w % WN;
    const int row0 = blockIdx.x * (WM * 64) + wr * 64;
    const int col0 = blockIdx.y * (WN * 64) + wc * 64;
    const int lr = lane & 15;
    const int kg = (lane >> 4) * 8;
    const int kb = blockIdx.z * kChunk;
    const int ke = kb + kChunk;

    f32x4 acc[4][4];
#pragma unroll
    for (int i = 0; i < 4; i++)
#pragma unroll
        for (int j = 0; j < 4; j++) acc[i][j] = (f32x4){0.f, 0.f, 0.f, 0.f};

    for (int kk = kb; kk < ke; kk += 32) {
        bf16x8 af[4], bfr[4];
#pragma unroll
        for (int i = 0; i < 4; i++) {
            int r = row0 + i * 16 + lr;
            r = min(r, M - 1);
            af[i] = *(const bf16x8*)(A + (size_t)r * lda + kk + kg);
        }
#pragma unroll
        for (int j = 0; j < 4; j++) {
            int c = col0 + j * 16 + lr;
            bfr[j] = *(const bf16x8*)(Bt + (size_t)c * ldb + kk + kg);
        }
#pragma unroll
        for (int i = 0; i < 4; i++)
#pragma unroll
            for (int j = 0; j < 4; j++)
                acc[i][j] = __builtin_amdgcn_mfma_f32_16x16x32_bf16(af[i], bfr[j], acc[i][j], 0, 0, 0);
    }

    const int cr = (lane >> 4) * 4, cc = lane & 15;
    if (gridDim.z > 1) {
        float* P = (float*)Cout + (size_t)blockIdx.z * M * ldc;
#pragma unroll
        for (int i = 0; i < 4; i++)
#pragma unroll
            for (int j = 0; j < 4; j++) {
                int col = col0 + j * 16 + cc;
                if (col >= N) continue;
#pragma unroll
                for (int t = 0; t < 4; t++) {
                    int row = row0 + i * 16 + cr + t;
                    if (row < M) P[(size_t)row * ldc + col] = acc[i][j][t];
                }
            }
    } else {
#pragma unroll
        for (int i = 0; i < 4; i++)
#pragma unroll
            for (int j = 0; j < 4; j++) {
                int col = col0 + j * 16 + cc;
                if (col >= (OUTBF ? npad : N)) continue;
                bool valid = col < N;
                float bi = (bias && valid) ? bias[col] : 0.f;
#pragma unroll
                for (int t = 0; t < 4; t++) {
                    int row = row0 + i * 16 + cr + t;
                    if (row >= M) continue;
                    float v = acc[i][j][t] + bi;
                    if (epi == 1) v = fmaxf(v, 0.f);
                    else if (epi == 2) v = tanhf(v);
                    else if (epi == 3) v = 1.f / (1.f + expf(-v));
                    if (!valid) v = 0.f;
                    if (OUTBF) {
                        size_t idx = (iofs < 0) ? ((size_t)row * ldc + col)
                                   : ((size_t)row * ldc + ((size_t)(col >> 1) << 2) + (col & 1) + iofs);
                        ((ushort*)Cout)[idx] = f2b(v);
                    } else {
                        ((float*)Cout)[(size_t)row * ldc + col] = v;
                    }
                }
            }
    }
}

// ================= CSR build =================
__global__ void k_deg(const int* __restrict__ dst, int* __restrict__ deg) {
    int e = blockIdx.x * 256 + threadIdx.x;
    if (e < E_EDGES) atomicAdd(&deg[dst[e]], 1);
}

__global__ void k_scan1(const int* __restrict__ in, int* __restrict__ out,
                        int* __restrict__ bsum, int n) {
    __shared__ int sh[256];
    int i = blockIdx.x * 256 + threadIdx.x;
    int v = (i < n) ? in[i] : 0;
    sh[threadIdx.x] = v; __syncthreads();
    for (int off = 1; off < 256; off <<= 1) {
        int t = (threadIdx.x >= off) ? sh[threadIdx.x - off] : 0;
        __syncthreads();
        sh[threadIdx.x] += t;
        __syncthreads();
    }
    if (i < n) out[i] = sh[threadIdx.x] - v;
    if (threadIdx.x == 255) bsum[blockIdx.x] = sh[255];
}

__global__ void k_scan2(int* __restrict__ bsum, int nb) {
    __shared__ int sh[1024];
    int t = threadIdx.x;
    int v = (t < nb) ? bsum[t] : 0;
    sh[t] = v; __syncthreads();
    for (int off = 1; off < 1024; off <<= 1) {
        int u = (t >= off) ? sh[t - off] : 0;
        __syncthreads();
        sh[t] += u;
        __syncthreads();
    }
    if (t < nb) bsum[t] = sh[t] - v;
}

__global__ void k_scan3(int* __restrict__ out, const int* __restrict__ bsum, int n) {
    int i = blockIdx.x * 256 + threadIdx.x;
    if (i < n) out[i] += bsum[blockIdx.x];
}

__global__ void k_scatter(const int* __restrict__ dst, const int* __restrict__ start,
                          int* __restrict__ cursor, int* __restrict__ eorder) {
    int e = blockIdx.x * 256 + threadIdx.x;
    if (e < E_EDGES) {
        int n = dst[e];
        int p = start[n] + atomicAdd(&cursor[n], 1);
        eorder[p] = e;
    }
}

__global__ void k_sortseg(const int* __restrict__ start, const int* __restrict__ deg,
                          int* __restrict__ eorder) {
    int n = blockIdx.x * 256 + threadIdx.x;
    if (n >= N_ENTS) return;
    int b = start[n], d = deg[n];
    for (int i = 1; i < d; i++) {
        int key = eorder[b + i];
        int j = i - 1;
        while (j >= 0 && eorder[b + j] > key) { eorder[b + j + 1] = eorder[b + j]; j--; }
        eorder[b + j + 1] = key;
    }
}

__global__ void k_mkidx(const int* __restrict__ eorder, const int* __restrict__ src,
                        const int* __restrict__ dst, const int* __restrict__ rel_id,
                        int4* __restrict__ sidx) {
    int slot = blockIdx.x * 256 + threadIdx.x;
    if (slot < E_EDGES) {
        int e = eorder[slot];
        sidx[slot] = make_int4(src[e], dst[e], rel_id[e], e);
    }
}

// ================= edge scores: 8 lanes/edge, 8 edges/wave =================
__global__ __launch_bounds__(256) void k_scores(
    const int4* __restrict__ sidx, const ushort* __restrict__ ep,
    const ushort* __restrict__ rel, float2* __restrict__ sc) {
    int gg = threadIdx.x >> 3, l = threadIdx.x & 7;
    int slot = blockIdx.x * 32 + gg;
    int4 si = sidx[slot];
    const ushort* rs = ep + (size_t)si.x * 256 + l * 32;
    const ushort* rd = ep + (size_t)si.y * 256 + l * 32;
    const ushort* rr = rel + (size_t)si.z * 128 + l * 16;
    u16x8 sv[4], dv[4], rv[2];
#pragma unroll
    for (int i = 0; i < 4; i++) sv[i] = *(const u16x8*)(rs + 8 * i);
#pragma unroll
    for (int i = 0; i < 4; i++) dv[i] = *(const u16x8*)(rd + 8 * i);
#pragma unroll
    for (int i = 0; i < 2; i++) rv[i] = *(const u16x8*)(rr + 8 * i);
    // ep quad q holds {c[2q],c[2q+1],p[2q],p[2q+1]}; lane covers quads l*8..l*8+7
    float a = 0.f, b = 0.f;
#pragma unroll
    for (int Q = 0; Q < 8; Q++) {
        int G = Q >> 1, k = (Q & 1) * 4;
        float r0 = b2f(rv[Q >> 2][(Q & 3) * 2]);
        float r1 = b2f(rv[Q >> 2][(Q & 3) * 2 + 1]);
        a += b2f(sv[G][k])     * r0 * b2f(dv[G][k])     + b2f(sv[G][k + 1]) * r1 * b2f(dv[G][k + 1]);
        b += b2f(sv[G][k + 2]) * r0 * b2f(dv[G][k + 2]) + b2f(sv[G][k + 3]) * r1 * b2f(dv[G][k + 3]);
    }
#pragma unroll
    for (int m = 4; m; m >>= 1) { a += __shfl_xor(a, m, 8); b += __shfl_xor(b, m, 8); }
    if (l == 0) sc[slot] = make_float2(a, b);
}

// ================= softmax + top-15: 16 lanes/node (rank by raw score) =========
__global__ __launch_bounds__(256) void k_softtop(
    const int* __restrict__ start, const int* __restrict__ deg,
    const float2* __restrict__ sc, float2* __restrict__ w) {
    int n = blockIdx.x * 16 + (threadIdx.x >> 4);
    int l = threadIdx.x & 15;
    if (n >= N_ENTS) return;
    int b = start[n], d = deg[n];
    if (d == 0) return;
    float m1 = -INFINITY, m2 = -INFINITY;
    for (int i = l; i < d; i += 16) {
        float2 s = sc[b + i];
        m1 = fmaxf(m1, s.x); m2 = fmaxf(m2, s.y);
    }
#pragma unroll
    for (int o = 8; o; o >>= 1) { m1 = fmaxf(m1, __shfl_xor(m1, o, 16)); m2 = fmaxf(m2, __shfl_xor(m2, o, 16)); }
    float z1 = 0.f, z2 = 0.f;
    for (int i = l; i < d; i += 16) {
        float2 s = sc[b + i];
        z1 += expf(s.x - m1); z2 += expf(s.y - m2);
    }
#pragma unroll
    for (int o = 8; o; o >>= 1) { z1 += __shfl_xor(z1, o, 16); z2 += __shfl_xor(z2, o, 16); }
    for (int i = l; i < d; i += 16) {
        float2 sp = sc[b + i];
        int r1 = 0, r2 = 0;
        for (int j = 0; j < d; j++) {
            float2 sq = sc[b + j];
            r1 += (sq.x > sp.x) || (sq.x == sp.x && j < i);
            r2 += (sq.y > sp.y) || (sq.y == sp.y && j < i);
        }
        w[b + i] = make_float2(r1 < TOPK_K ? expf(sp.x - m1) / z1 : 0.f,
                               r2 < TOPK_K ? expf(sp.y - m2) / z2 : 0.f);
    }
}

// ================= weighted aggregation: block-per-node, 4 waves =================
__global__ __launch_bounds__(256) void k_agg(
    const int4* __restrict__ sidx, const int* __restrict__ start, const int* __restrict__ deg,
    const float2* __restrict__ w, const ushort* __restrict__ ep, const ushort* __restrict__ rel,
    ushort* __restrict__ neigh1, ushort* __restrict__ neigh2) {
    __shared__ float4 part[3][64];
    int n = blockIdx.x;
    int wid = threadIdx.x >> 6, g = threadIdx.x & 63;
    int b = start[n], d = deg[n];
    int end = b + d;
    float2 a1 = make_float2(0.f, 0.f), a2 = make_float2(0.f, 0.f);
    int s = b + wid;
    if (s < end) {
        int4 si = sidx[s];
        float2 ww = w[s];
        for (;;) {
            int sn = s + 4;
            bool more = sn < end;
            int4 si_n; float2 ww_n;
            if (more) { si_n = sidx[sn]; ww_n = w[sn]; }
            if (ww.x != 0.f || ww.y != 0.f) {
                u16x4 v = *(const u16x4*)(ep + (size_t)si.x * 256 + g * 4);
                uint  r = *(const uint*)(rel + (size_t)si.z * 128 + g * 2);
                float rx = b2f((ushort)(r & 0xffffu)), ry = b2f((ushort)(r >> 16));
                a1.x += ww.x * b2f(v[0]) * rx;  a1.y += ww.x * b2f(v[1]) * ry;
                a2.x += ww.y * b2f(v[2]) * rx;  a2.y += ww.y * b2f(v[3]) * ry;
            }
            if (!more) break;
            si = si_n; ww = ww_n; s = sn;
        }
    }
    if (wid > 0) part[wid - 1][g] = make_float4(a1.x, a1.y, a2.x, a2.y);
    __syncthreads();
    if (wid == 0) {
#pragma unroll
        for (int k = 0; k < 3; k++) {
            float4 p = part[k][g];
            a1.x += p.x; a1.y += p.y; a2.x += p.z; a2.y += p.w;
        }
        uint o1 = (uint)f2b(a1.x) | ((uint)f2b(a1.y) << 16);
        uint o2 = (uint)f2b(a2.x) | ((uint)f2b(a2.y) << 16);
        ((uint*)(neigh1 + (size_t)n * HD))[g] = o1;
        ((uint*)(neigh2 + (size_t)n * HD))[g] = o2;
    }
}

// ================= ent_out (bf16, padded rows zero) =================
__global__ void k_entout(const float* __restrict__ ent, const ushort* __restrict__ c1,
                         const ushort* __restrict__ c2, ushort* __restrict__ out) {
    int i = blockIdx.x * 256 + threadIdx.x;
    if (i >= NPAD_ENT * HD) return;
    int r = i >> 7;
    float v = 0.f;
    if (r < N_ENTS) v = ent[i] + b2f(c1[i]) + b2f(c2[i]);
    out[i] = (r < N_ENTS) ? f2b(v) : (ushort)0;
}

// ================= matvec over K=200 (bf16 A) =================
__global__ void k_matvec(const ushort* __restrict__ A, int lda, const float* __restrict__ w,
                         const float* __restrict__ b, float* __restrict__ out, int M) {
    int r = blockIdx.x * 4 + (threadIdx.x >> 6);
    int lane = threadIdx.x & 63;
    if (r >= M) return;
    float s = 0.f;
    for (int k = lane; k < HIDD; k += 64) s += b2f(A[(size_t)r * lda + k]) * w[k];
    for (int o = 32; o; o >>= 1) s += __shfl_xor(s, o, 64);
    if (lane == 0) out[r] = s + b[0];
}

// ================= corr =================
__global__ void k_corr1(const float* __restrict__ x1, const float* __restrict__ x2,
                        float* __restrict__ red) {
    __shared__ float sa[1024], sb[1024];
    int t = threadIdx.x;
    float s1 = 0.f, s2 = 0.f;
    for (int i = t; i < N_ENTS; i += 1024) { s1 += x1[i]; s2 += x2[i]; }
    sa[t] = s1; sb[t] = s2; __syncthreads();
    for (int o = 512; o > 0; o >>= 1) {
        if (t < o) { sa[t] += sa[t + o]; sb[t] += sb[t + o]; }
        __syncthreads();
    }
    if (t == 0) { red[0] = sa[0] / (float)N_ENTS; red[1] = sb[0] / (float)N_ENTS; }
}

__global__ void k_corr2(const float* __restrict__ x1, const float* __restrict__ x2,
                        const float* __restrict__ red, float* __restrict__ out) {
    __shared__ float s11[1024], s22[1024], s12[1024];
    int t = threadIdx.x;
    float m1 = red[0], m2 = red[1];
    float a11 = 0.f, a22 = 0.f, a12 = 0.f;
    for (int i = t; i < N_ENTS; i += 1024) {
        float a = x1[i] - m1, b = x2[i] - m2;
        a11 += a * a; a22 += b * b; a12 += a * b;
    }
    s11[t] = a11; s22[t] = a22; s12[t] = a12; __syncthreads();
    for (int o = 512; o > 0; o >>= 1) {
        if (t < o) { s11[t] += s11[t + o]; s22[t] += s22[t + o]; s12[t] += s12[t + o]; }
        __syncthreads();
    }
    if (t == 0) {
        float v11 = s11[0] / (float)N_ENTS, v22 = s22[0] / (float)N_ENTS, v12 = s12[0] / (float)N_ENTS;
        out[0] = fabsf(v12) / (sqrtf(v11) * sqrtf(v22));
    }
}

// ================= ConvE conv =================
__global__ void k_conv(const int* __restrict__ h_id, const int* __restrict__ r_id,
                       const ushort* __restrict__ entout, const ushort* __restrict__ prel,
                       const float* __restrict__ cw, const float* __restrict__ cb,
                       ushort* __restrict__ out) {
    __shared__ float img[256];
    __shared__ float filt[C_CH * 49];
    int b = blockIdx.x, tid = threadIdx.x;
    if (tid < 128) img[tid] = b2f(entout[(size_t)h_id[b] * HD + tid]);
    else           img[tid] = b2f(prel[(size_t)r_id[b] * HD + (tid - 128)]);
    for (int i = tid; i < C_CH * 49; i += 256) filt[i] = cw[i];
    __syncthreads();
    for (int idx = tid; idx < FLATD; idx += 256) {
        int o = idx / 100, rem = idx % 100, i = rem / 10, j = rem % 10;
        float acc = cb[o];
        const float* f = &filt[o * 49];
#pragma unroll
        for (int ki = 0; ki < 7; ki++)
#pragma unroll
            for (int kj = 0; kj < 7; kj++)
                acc += img[(i + ki) * 16 + (j + kj)] * f[ki * 7 + kj];
        out[(size_t)b * FLATD + idx] = f2b(fmaxf(acc, 0.f));
    }
}

// ================= split-K reduce for fc =================
__global__ void k_fcreduce(const float* __restrict__ part, const float* __restrict__ bias,
                           ushort* __restrict__ out) {
    int i = blockIdx.x * 256 + threadIdx.x;
    if (i >= BSZ * HD) return;
    float s = 0.f;
    for (int z = 0; z < SPLITK; z++) s += part[(size_t)z * BSZ * HD + i];
    s += bias[i & (HD - 1)];
    out[i] = f2b(fmaxf(s, 0.f));
}

// ================= host launcher =================
extern "C" void kernel_launch(void* const* d_in, const int* in_sizes, int n_in,
                              void* d_out, int out_size, void* d_ws, size_t ws_size,
                              hipStream_t stream) {
    const int* h_id    = (const int*)d_in[0];
    const int* r_id    = (const int*)d_in[1];
    const int* src     = (const int*)d_in[2];
    const int* dst     = (const int*)d_in[3];
    const int* rel_id  = (const int*)d_in[4];
    const float* ent_emb  = (const float*)d_in[5];
    const float* rel_emb0 = (const float*)d_in[6];
    const float* neigh_w  = (const float*)d_in[7];
    const float* S_w = (const float*)d_in[8];
    const float* S_b = (const float*)d_in[9];
    const float* L_w = (const float*)d_in[10];
    const float* L_b = (const float*)d_in[11];
    const float* pred_rel = (const float*)d_in[12];
    const float* phi_w0 = (const float*)d_in[13]; const float* phi_b0 = (const float*)d_in[14];
    const float* phi_w1 = (const float*)d_in[15]; const float* phi_b1 = (const float*)d_in[16];
    const float* phi_w2 = (const float*)d_in[17]; const float* phi_b2 = (const float*)d_in[18];
    const float* psi_w0 = (const float*)d_in[19]; const float* psi_b0 = (const float*)d_in[20];
    const float* psi_w1 = (const float*)d_in[21]; const float* psi_b1 = (const float*)d_in[22];
    const float* psi_w2 = (const float*)d_in[23]; const float* psi_b2 = (const float*)d_in[24];
    const float* conv_w = (const float*)d_in[25]; const float* conv_b = (const float*)d_in[26];
    const float* fc_w   = (const float*)d_in[27]; const float* fc_b   = (const float*)d_in[28];
    const float* score_b= (const float*)d_in[29];

    char* base = (char*)d_ws;
    ushort* ep       = (ushort*)(base + OFF_EP);
    ushort* entout_bf= (ushort*)(base + OFF_ENTOUT);
    ushort* rel_bf   = (ushort*)(base + OFF_RELBF);
    ushort* prel_bf  = (ushort*)(base + OFF_PRELBF);
    ushort* Swt      = (ushort*)(base + OFF_SWT);
    ushort* Lwt      = (ushort*)(base + OFF_LWT);
    ushort* nWt      = (ushort*)(base + OFF_NWT);
    ushort* p0t      = (ushort*)(base + OFF_P0T);
    ushort* q0t      = (ushort*)(base + OFF_Q0T);
    ushort* p1t      = (ushort*)(base + OFF_P1T);
    ushort* q1t      = (ushort*)(base + OFF_Q1T);
    ushort* fct      = (ushort*)(base + OFF_FCT);
    float2* sc       = (float2*)(base + OFF_SC);
    float2* wpair    = (float2*)(base + OFF_W);
    int4*   sidx     = (int4*)(base + OFF_SIDX);
    int*    eorder   = (int*)(base + OFF_EORD);
    int*    deg      = (int*)(base + OFF_DEG);
    int*    startp   = (int*)(base + OFF_START);
    int*    cursor   = (int*)(base + OFF_CUR);
    int*    bsum     = (int*)(base + OFF_BSUM);
    float*  x1       = (float*)(base + OFF_X1);
    float*  x2       = (float*)(base + OFF_X2);
    float*  red      = (float*)(base + OFF_RED);
    ushort* xfc_bf   = (ushort*)(base + OFF_XFC);
    ushort* c1_bf    = (ushort*)(base + OFF_EP);                 // alias (ep dead after agg)
    ushort* c2_bf    = (ushort*)(base + OFF_EP + 12812288);
    ushort* ent_bf   = (ushort*)(base + OFF_ARENA);              // temp: arena before neigh use
    ushort* neigh1_bf= (ushort*)(base + OFF_ARENA);
    ushort* neigh2_bf= (ushort*)(base + OFF_ARENA + 12812288);
    ushort* g1       = (ushort*)(base + OFF_ARENA);
    ushort* g2       = (ushort*)(base + OFF_ARENA + 22421504);
    ushort* convout  = (ushort*)(base + OFF_ARENA);
    float*  fcpart   = (float*)(base + OFF_ARENA + 22421504);
    float*  outf     = (float*)d_out;

    // ---- phase 0: conversions & weight transposes ----
    k_cvt<<<dim3((MPAD * HD + 255) / 256), 256, 0, stream>>>(ent_emb, ent_bf, N_ENTS, MPAD, HD);
    k_cvt<<<dim3((1000 * HD + 255) / 256), 256, 0, stream>>>(rel_emb0, rel_bf, 1000, 1000, HD);
    k_cvt<<<dim3((1000 * HD + 255) / 256), 256, 0, stream>>>(pred_rel, prel_bf, 1000, 1000, HD);
    k_tcvtT<<<dim3(4, 4), 256, 0, stream>>>(S_w, Swt, 128, 128, 128, 128);
    k_tcvtT<<<dim3(4, 4), 256, 0, stream>>>(L_w, Lwt, 128, 128, 128, 128);
    k_tcvtT<<<dim3(4, 4), 256, 0, stream>>>(neigh_w, nWt, 128, 128, 128, 128);
    k_tcvtT<<<dim3(4, 8), 256, 0, stream>>>(phi_w0, p0t, 128, HIDD, 128, NPAD200);
    k_tcvtT<<<dim3(4, 8), 256, 0, stream>>>(psi_w0, q0t, 128, HIDD, 128, NPAD200);
    k_tcvtT<<<dim3(7, 8), 256, 0, stream>>>(phi_w1, p1t, HIDD, HIDD, KPAD200, NPAD200);
    k_tcvtT<<<dim3(7, 8), 256, 0, stream>>>(psi_w1, q1t, HIDD, HIDD, KPAD200, NPAD200);
    k_tcvtT<<<dim3(300, 4), 256, 0, stream>>>(fc_w, fct, FLATD, 128, FLATD, 128);

    // ---- phase 1: projections -> interleaved ep table ----
    k_mgemm<2,2,1><<<dim3(391, 1, 1), 256, 0, stream>>>(ent_bf, HD, Swt, HD, S_b, ep, 256, N_ENTS, HD, HD, HD, 0, 0, HD);
    k_mgemm<2,2,1><<<dim3(391, 1, 1), 256, 0, stream>>>(ent_bf, HD, Lwt, HD, L_b, ep, 256, N_ENTS, HD, HD, HD, 0, 2, HD);

    // ---- phase 2: CSR build ----
    hipMemsetAsync(deg, 0, N_ENTS * sizeof(int), stream);
    hipMemsetAsync(cursor, 0, N_ENTS * sizeof(int), stream);
    k_deg<<<dim3((E_EDGES + 255) / 256), 256, 0, stream>>>(dst, deg);
    int nscan = (N_ENTS + 255) / 256;
    k_scan1<<<dim3(nscan), 256, 0, stream>>>(deg, startp, bsum, N_ENTS);
    k_scan2<<<dim3(1), 1024, 0, stream>>>(bsum, nscan);
    k_scan3<<<dim3(nscan), 256, 0, stream>>>(startp, bsum, N_ENTS);
    k_scatter<<<dim3((E_EDGES + 255) / 256), 256, 0, stream>>>(dst, startp, cursor, eorder);
    k_sortseg<<<dim3(nscan), 256, 0, stream>>>(startp, deg, eorder);
    k_mkidx<<<dim3((E_EDGES + 255) / 256), 256, 0, stream>>>(eorder, src, dst, rel_id, sidx);

    // ---- phase 3-5: edge pipeline ----
    k_scores<<<dim3(E_EDGES / 32), 256, 0, stream>>>(sidx, ep, rel_bf, sc);
    k_softtop<<<dim3((N_ENTS + 15) / 16), 256, 0, stream>>>(startp, deg, sc, wpair);
    k_agg<<<dim3(N_ENTS), 256, 0, stream>>>(sidx, startp, deg, wpair, ep, rel_bf,
                                            neigh1_bf, neigh2_bf);

    // ---- phase 6: c1/c2 = tanh(neigh @ W)  (write over dead ep) ----
    k_mgemm<2,2,1><<<dim3(391, 1, 1), 256, 0, stream>>>(neigh1_bf, HD, nWt, HD, nullptr, c1_bf, HD, N_ENTS, HD, HD, HD, 2, -1, HD);
    k_mgemm<2,2,1><<<dim3(391, 1, 1), 256, 0, stream>>>(neigh2_bf, HD, nWt, HD, nullptr, c2_bf, HD, N_ENTS, HD, HD, HD, 2, -1, HD);

    // ---- phase 7: ent_out ----
    k_entout<<<dim3((NPAD_ENT * HD + 255) / 256), 256, 0, stream>>>(ent_emb, c1_bf, c2_bf, entout_bf);

    // ---- phase 8: MLPs (pad cols [200,224) zero-filled by npad mechanism) ----
    k_mgemm<2,2,1><<<dim3(391, 2, 1), 256, 0, stream>>>(c1_bf, HD, p0t, HD, phi_b0, g1, KPAD200, N_ENTS, HIDD, HD, HD, 1, -1, KPAD200);
    k_mgemm<2,2,1><<<dim3(391, 2, 1), 256, 0, stream>>>(g1, KPAD200, p1t, KPAD200, phi_b1, g2, KPAD200, N_ENTS, HIDD, KPAD200, KPAD200, 1, -1, KPAD200);
    k_matvec<<<dim3((N_ENTS + 3) / 4), 256, 0, stream>>>(g2, KPAD200, phi_w2, phi_b2, x1, N_ENTS);
    k_mgemm<2,2,1><<<dim3(391, 2, 1), 256, 0, stream>>>(c2_bf, HD, q0t, HD, psi_b0, g1, KPAD200, N_ENTS, HIDD, HD, HD, 1, -1, KPAD200);
    k_mgemm<2,2,1><<<dim3(391, 2, 1), 256, 0, stream>>>(g1, KPAD200, q1t, KPAD200, psi_b1, g2, KPAD200, N_ENTS, HIDD, KPAD200, KPAD200, 1, -1, KPAD200);
    k_matvec<<<dim3((N_ENTS + 3) / 4), 256, 0, stream>>>(g2, KPAD200, psi_w2, psi_b2, x2, N_ENTS);

    // ---- phase 9: corr ----
    k_corr1<<<dim3(1), 1024, 0, stream>>>(x1, x2, red);
    k_corr2<<<dim3(1), 1024, 0, stream>>>(x1, x2, red, outf + OUT_SCORE);

    // ---- phase 10-11: ConvE ----
    k_conv<<<dim3(BSZ), 256, 0, stream>>>(h_id, r_id, entout_bf, prel_bf, conv_w, conv_b, convout);
    k_mgemm<2,2,0><<<dim3(8, 1, SPLITK), 256, 0, stream>>>(convout, FLATD, fct, FLATD, nullptr, fcpart, HD,
                                                           BSZ, HD, FLATD, FLATD / SPLITK, 0, -1, HD);
    k_fcreduce<<<dim3((BSZ * HD + 255) / 256), 256, 0, stream>>>(fcpart, fc_b, xfc_bf);

    // ---- phase 12: score GEMM ----
    k_mgemm<4,1,0><<<dim3(4, 784, 1), 256, 0, stream>>>(xfc_bf, HD, entout_bf, HD, score_b, outf, N_ENTS,
                                                        BSZ, N_ENTS, HD, HD, 3, -1, N_ENTS);
}

// Round 5
// 804.922 us; speedup vs baseline: 2.3281x; 1.2657x over previous
//
#include <hip/hip_runtime.h>
#include <math.h>

typedef unsigned short ushort;
typedef unsigned int   uint;
typedef short bf16x8 __attribute__((ext_vector_type(8)));
typedef float f32x4  __attribute__((ext_vector_type(4)));
typedef ushort u16x8 __attribute__((ext_vector_type(8)));
typedef ushort u16x4 __attribute__((ext_vector_type(4)));

// ---------------- problem constants ----------------
#define N_ENTS   50000
#define E_EDGES  800000
#define HD       128
#define BSZ      1024
#define C_CH     96
#define FLATD    9600
#define TOPK_K   15
#define HIDD     200
#define SPLITK   10
#define OUT_SCORE ((size_t)BSZ * N_ENTS)

#define MPAD     50048            // 391*128
#define NPAD_ENT 50176            // 196*256
#define KPAD200  224
#define NPAD200  256
#define L2E      1.4426950408889634f

// ---------------- workspace layout (byte offsets) ----------------
#define OFF_EP       ((size_t)0)            // ushort [50048][256] interleaved c/p (c1/c2 alias later)
#define OFF_ENTOUT   ((size_t)25624576)     // ushort [50176][128]
#define OFF_RELBF    ((size_t)38469632)     // ushort [1000][128]
#define OFF_PRELBF   ((size_t)38725632)
#define OFF_SWT      ((size_t)38981632)     // ushort [128][128]
#define OFF_LWT      ((size_t)39014400)
#define OFF_NWT      ((size_t)39047168)
#define OFF_P0T      ((size_t)39079936)     // ushort [256][128]
#define OFF_Q0T      ((size_t)39145472)
#define OFF_P1T      ((size_t)39211008)     // ushort [256][224]
#define OFF_Q1T      ((size_t)39325696)
#define OFF_FCT      ((size_t)39440384)     // ushort [128][9600]
#define OFF_SC       ((size_t)41897984)     // float2 [800000]
#define OFF_W        ((size_t)48297984)     // float2 [800000]
#define OFF_SIDX     ((size_t)54697984)     // int4 [800000]
#define OFF_EORD     ((size_t)67497984)     // int [800000]
#define OFF_DEG      ((size_t)70697984)     // int [50000]
#define OFF_START    ((size_t)70897984)
#define OFF_CUR      ((size_t)71097984)
#define OFF_BSUM     ((size_t)71297984)     // int [1024]
#define OFF_X1       ((size_t)71302080)     // float [50000]
#define OFF_X2       ((size_t)71502080)
#define OFF_RED      ((size_t)71702080)     // float [64]
#define OFF_XFC      ((size_t)71702336)     // ushort [1024][128]
#define OFF_ARENA    ((size_t)71964480)     // 44,843,008 bytes -> total 116,807,488
// arena: ent_bf=+0 (u16[50048][128]) [dead after proj]
//        neigh1=+0, neigh2=+12812288 [dead after tanh GEMMs]
//        convout=+0 (u16[1024][9600]), fcpart=+22421504 (f32[10][1024][128])
// c1 = EP+0 (u16[50048][128]), c2 = EP+12812288  (EP dead after k_agg)

// ---------------- helpers ----------------
__device__ inline ushort f2b(float f) {
    uint u = __float_as_uint(f);
    return (ushort)((u + 0x7fffu + ((u >> 16) & 1u)) >> 16);  // RNE
}
__device__ inline float b2f(ushort u) { return __uint_as_float((uint)u << 16); }
__device__ inline float fexp2(float x) { return __builtin_amdgcn_exp2f(x); }
__device__ inline float frcp(float x)  { return __builtin_amdgcn_rcpf(x); }
__device__ inline float fsigmoid(float x) {           // 1/(1+e^-x), native exp2+rcp
    return frcp(1.f + fexp2(-x * L2E));
}
__device__ inline float ftanh(float x) {              // overflow-safe
    float ax = fabsf(x);
    float t = fexp2(ax * (-2.f * L2E));
    float r = (1.f - t) * frcp(1.f + t);
    return copysignf(r, x);
}

// ---------------- conversion kernels ----------------
__global__ void k_cvt(const float* __restrict__ in, ushort* __restrict__ out,
                      int M, int Mpad, int K) {
    int i = blockIdx.x * 256 + threadIdx.x;
    if (i >= Mpad * K) return;
    int r = i / K;
    out[i] = (r < M) ? f2b(in[i]) : (ushort)0;
}

// tiled transpose-convert: f32 in[K][N] -> bf16 out[Npad][Kpad], pads zero
__global__ __launch_bounds__(256) void k_tcvtT(const float* __restrict__ in, ushort* __restrict__ out,
                                               int K, int N, int Kpad, int Npad) {
    __shared__ float t[32][33];
    int k0 = blockIdx.x * 32, n0 = blockIdx.y * 32;
    int tx = threadIdx.x & 31, ty = threadIdx.x >> 5;
    for (int i = ty; i < 32; i += 8) {
        int k = k0 + i, n = n0 + tx;
        t[i][tx] = (k < K && n < N) ? in[(size_t)k * N + n] : 0.f;
    }
    __syncthreads();
    for (int i = ty; i < 32; i += 8) {
        int n = n0 + i, k = k0 + tx;
        if (n < Npad && k < Kpad) out[(size_t)n * Kpad + k] = f2b(t[tx][i]);
    }
}

// ================= MFMA bf16 GEMM (generic) =================
// C[M,N] = epi(A @ Bt^T + bias); K mult of 32. FUSE2: blockIdx.z==1 -> second set.
// iofs<0: normal store; 0/2: interleaved ep store. npad: bf16 cols [N,npad) -> 0.
// !FUSE2 && gridDim.z>1: split-K f32 partials. epi: 0 none,1 relu,2 tanh,3 sigmoid.
template <int WM, int WN, int OUTBF, int FUSE2>
__global__ __launch_bounds__(256) void k_mgemm(
    const ushort* __restrict__ A, int lda,
    const ushort* __restrict__ Bt, int ldb,
    const float* __restrict__ bias, void* __restrict__ Cout, int ldc,
    int M, int N, int K, int kChunk, int epi, int iofs, int npad,
    const ushort* __restrict__ A2, const ushort* __restrict__ Bt2,
    const float* __restrict__ bias2, void* __restrict__ Cout2, int iofs2) {
    if (FUSE2 && blockIdx.z == 1) { A = A2; Bt = Bt2; bias = bias2; Cout = Cout2; iofs = iofs2; }
    const int w = threadIdx.x >> 6, lane = threadIdx.x & 63;
    const int wr = w / WN, wc = w % WN;
    const int row0 = blockIdx.x * (WM * 64) + wr * 64;
    const int col0 = blockIdx.y * (WN * 64) + wc * 64;
    const int lr = lane & 15;
    const int kg = (lane >> 4) * 8;
    const int kb = FUSE2 ? 0 : blockIdx.z * kChunk;
    const int ke = kb + kChunk;

    f32x4 acc[4][4];
#pragma unroll
    for (int i = 0; i < 4; i++)
#pragma unroll
        for (int j = 0; j < 4; j++) acc[i][j] = (f32x4){0.f, 0.f, 0.f, 0.f};

    for (int kk = kb; kk < ke; kk += 32) {
        bf16x8 af[4], bfr[4];
#pragma unroll
        for (int i = 0; i < 4; i++) {
            int r = row0 + i * 16 + lr;
            r = min(r, M - 1);
            af[i] = *(const bf16x8*)(A + (size_t)r * lda + kk + kg);
        }
#pragma unroll
        for (int j = 0; j < 4; j++) {
            int c = col0 + j * 16 + lr;
            bfr[j] = *(const bf16x8*)(Bt + (size_t)c * ldb + kk + kg);
        }
#pragma unroll
        for (int i = 0; i < 4; i++)
#pragma unroll
            for (int j = 0; j < 4; j++)
                acc[i][j] = __builtin_amdgcn_mfma_f32_16x16x32_bf16(af[i], bfr[j], acc[i][j], 0, 0, 0);
    }

    const int cr = (lane >> 4) * 4, cc = lane & 15;
    if (!FUSE2 && gridDim.z > 1) {
        float* P = (float*)Cout + (size_t)blockIdx.z * M * ldc;
#pragma unroll
        for (int i = 0; i < 4; i++)
#pragma unroll
            for (int j = 0; j < 4; j++) {
                int col = col0 + j * 16 + cc;
                if (col >= N) continue;
#pragma unroll
                for (int t = 0; t < 4; t++) {
                    int row = row0 + i * 16 + cr + t;
                    if (row < M) P[(size_t)row * ldc + col] = acc[i][j][t];
                }
            }
    } else {
#pragma unroll
        for (int i = 0; i < 4; i++)
#pragma unroll
            for (int j = 0; j < 4; j++) {
                int col = col0 + j * 16 + cc;
                if (col >= (OUTBF ? npad : N)) continue;
                bool valid = col < N;
                float bi = (bias && valid) ? bias[col] : 0.f;
#pragma unroll
                for (int t = 0; t < 4; t++) {
                    int row = row0 + i * 16 + cr + t;
                    if (row >= M) continue;
                    float v = acc[i][j][t] + bi;
                    if (epi == 1) v = fmaxf(v, 0.f);
                    else if (epi == 2) v = ftanh(v);
                    else if (epi == 3) v = fsigmoid(v);
                    if (!valid) v = 0.f;
                    if (OUTBF) {
                        size_t idx = (iofs < 0) ? ((size_t)row * ldc + col)
                                   : ((size_t)row * ldc + ((size_t)(col >> 1) << 2) + (col & 1) + iofs);
                        ((ushort*)Cout)[idx] = f2b(v);
                    } else {
                        ((float*)Cout)[(size_t)row * ldc + col] = v;
                    }
                }
            }
    }
}

// ================= score GEMM: 64x256 tile, LDS-staged float4 stores =================
__global__ __launch_bounds__(256) void k_score(
    const ushort* __restrict__ A,      // [1024][128] xfc bf16
    const ushort* __restrict__ Bt,     // [50176][128] entout bf16
    const float* __restrict__ bias,    // [50000]
    float* __restrict__ C, int N) {    // [1024][N]
    __shared__ __align__(16) float st[4][16][68];
    const int w = threadIdx.x >> 6, lane = threadIdx.x & 63;
    const int lr = lane & 15, kg = (lane >> 4) * 8;
    const int cr = (lane >> 4) * 4, cc = lane & 15;
    const int row0 = blockIdx.x * 64;
    const int colw = blockIdx.y * 256 + w * 64;

    f32x4 acc[4][4];
#pragma unroll
    for (int i = 0; i < 4; i++)
#pragma unroll
        for (int j = 0; j < 4; j++) acc[i][j] = (f32x4){0.f, 0.f, 0.f, 0.f};

    for (int kk = 0; kk < HD; kk += 32) {
        bf16x8 af[4], bfr[4];
#pragma unroll
        for (int i = 0; i < 4; i++)
            af[i] = *(const bf16x8*)(A + (size_t)(row0 + i * 16 + lr) * HD + kk + kg);
#pragma unroll
        for (int j = 0; j < 4; j++)
            bfr[j] = *(const bf16x8*)(Bt + (size_t)(colw + j * 16 + lr) * HD + kk + kg);
#pragma unroll
        for (int i = 0; i < 4; i++)
#pragma unroll
            for (int j = 0; j < 4; j++)
                acc[i][j] = __builtin_amdgcn_mfma_f32_16x16x32_bf16(af[i], bfr[j], acc[i][j], 0, 0, 0);
    }

#pragma unroll
    for (int i = 0; i < 4; i++) {
        // stage sigmoid(acc+bias) into per-wave LDS tile (16 rows x 64 cols)
#pragma unroll
        for (int j = 0; j < 4; j++) {
            int col = colw + j * 16 + cc;
            float bi = (col < N) ? bias[col] : 0.f;
#pragma unroll
            for (int t = 0; t < 4; t++)
                st[w][cr + t][j * 16 + cc] = fsigmoid(acc[i][j][t] + bi);
        }
        // wave-local readback: float4 coalesced stores (1KB/instr per wave)
#pragma unroll
        for (int p = 0; p < 4; p++) {
            int r = p * 4 + (lane >> 4);
            int cq = (lane & 15) * 4;
            float4 v = *(const float4*)&st[w][r][cq];
            int gc = colw + cq;
            if (gc < N)
                *(float4*)&C[(size_t)(row0 + i * 16 + r) * N + gc] = v;
        }
    }
}

// ================= fused 3-layer MLP: x = mlp3(c) per 64-row block =================
__global__ __launch_bounds__(256) void k_mlp2(
    const ushort* __restrict__ A,       // [50048][128] c bf16
    const ushort* __restrict__ W0t,     // [256][128]
    const float* __restrict__ b0,       // [200]
    const ushort* __restrict__ W1t,     // [256][224]
    const float* __restrict__ b1,       // [200]
    const float* __restrict__ w2,       // [200]
    const float* __restrict__ b2,       // [1]
    float* __restrict__ x) {            // [50000]
    __shared__ __align__(16) char lbuf[64 * 232 * 2];   // g1 bf16 [64][232]; reused as pbuf f32[64][65]
    __shared__ float w2e[256], b1e[256], b0e[256];
    const int tid = threadIdx.x;
    const int w = tid >> 6, lane = tid & 63;
    const int lr = lane & 15, kg = (lane >> 4) * 8;
    const int cr = (lane >> 4) * 4, cc = lane & 15;
    const int row0 = blockIdx.x * 64;
    {
        int c = tid;
        w2e[c] = (c < HIDD) ? w2[c] : 0.f;
        b1e[c] = (c < HIDD) ? b1[c] : 0.f;
        b0e[c] = (c < HIDD) ? b0[c] : 0.f;
    }
    __syncthreads();
    ushort* g1 = (ushort*)lbuf;

    // ---- L1: [64x128] @ W0t^T -> relu -> g1 (bf16, cols<224) ----
    f32x4 acc[4][4];
#pragma unroll
    for (int i = 0; i < 4; i++)
#pragma unroll
        for (int j = 0; j < 4; j++) acc[i][j] = (f32x4){0.f, 0.f, 0.f, 0.f};
    for (int kk = 0; kk < 128; kk += 32) {
        bf16x8 af[4], bfr[4];
#pragma unroll
        for (int i = 0; i < 4; i++)
            af[i] = *(const bf16x8*)(A + (size_t)(row0 + i * 16 + lr) * HD + kk + kg);
#pragma unroll
        for (int j = 0; j < 4; j++)
            bfr[j] = *(const bf16x8*)(W0t + (size_t)(w * 64 + j * 16 + lr) * 128 + kk + kg);
#pragma unroll
        for (int i = 0; i < 4; i++)
#pragma unroll
            for (int j = 0; j < 4; j++)
                acc[i][j] = __builtin_amdgcn_mfma_f32_16x16x32_bf16(af[i], bfr[j], acc[i][j], 0, 0, 0);
    }
#pragma unroll
    for (int i = 0; i < 4; i++)
#pragma unroll
        for (int j = 0; j < 4; j++) {
            int col = w * 64 + j * 16 + cc;
            if (col < KPAD200) {
                float bi = b0e[col];
#pragma unroll
                for (int t = 0; t < 4; t++)
                    g1[(i * 16 + cr + t) * 232 + col] = f2b(fmaxf(acc[i][j][t] + bi, 0.f));
            }
        }
    __syncthreads();

    // ---- L2: g1[64x224] @ W1t^T ----
    f32x4 a2[4][4];
#pragma unroll
    for (int i = 0; i < 4; i++)
#pragma unroll
        for (int j = 0; j < 4; j++) a2[i][j] = (f32x4){0.f, 0.f, 0.f, 0.f};
    for (int ks = 0; ks < 7; ks++) {
        int kk = ks * 32;
        bf16x8 af[4], bfr[4];
#pragma unroll
        for (int i = 0; i < 4; i++)
            af[i] = *(const bf16x8*)(g1 + (i * 16 + lr) * 232 + kk + kg);
#pragma unroll
        for (int j = 0; j < 4; j++)
            bfr[j] = *(const bf16x8*)(W1t + (size_t)(w * 64 + j * 16 + lr) * KPAD200 + kk + kg);
#pragma unroll
        for (int i = 0; i < 4; i++)
#pragma unroll
            for (int j = 0; j < 4; j++)
                a2[i][j] = __builtin_amdgcn_mfma_f32_16x16x32_bf16(af[i], bfr[j], a2[i][j], 0, 0, 0);
    }
    __syncthreads();   // g1 dead; overlay pbuf

    // ---- L3: dot with w2 (relu(a2+b1) * w2), reduce 16cc x 4w per row ----
    float* pbuf = (float*)lbuf;   // [64][65]
#pragma unroll
    for (int i = 0; i < 4; i++)
#pragma unroll
        for (int t = 0; t < 4; t++) {
            float s = 0.f;
#pragma unroll
            for (int j = 0; j < 4; j++) {
                int col = w * 64 + j * 16 + cc;
                s += fmaxf(a2[i][j][t] + b1e[col], 0.f) * w2e[col];
            }
            pbuf[(i * 16 + cr + t) * 65 + w * 16 + cc] = s;
        }
    __syncthreads();
    if (tid < 64) {
        float s = b2[0];
        for (int q = 0; q < 64; q++) s += pbuf[tid * 65 + q];
        int gr = row0 + tid;
        if (gr < N_ENTS) x[gr] = s;
    }
}

// ================= CSR build =================
__global__ void k_deg(const int* __restrict__ dst, int* __restrict__ deg) {
    int e = blockIdx.x * 256 + threadIdx.x;
    if (e < E_EDGES) atomicAdd(&deg[dst[e]], 1);
}

__global__ void k_scan1(const int* __restrict__ in, int* __restrict__ out,
                        int* __restrict__ bsum, int n) {
    __shared__ int sh[256];
    int i = blockIdx.x * 256 + threadIdx.x;
    int v = (i < n) ? in[i] : 0;
    sh[threadIdx.x] = v; __syncthreads();
    for (int off = 1; off < 256; off <<= 1) {
        int t = (threadIdx.x >= off) ? sh[threadIdx.x - off] : 0;
        __syncthreads();
        sh[threadIdx.x] += t;
        __syncthreads();
    }
    if (i < n) out[i] = sh[threadIdx.x] - v;
    if (threadIdx.x == 255) bsum[blockIdx.x] = sh[255];
}

__global__ void k_scan2(int* __restrict__ bsum, int nb) {
    __shared__ int sh[1024];
    int t = threadIdx.x;
    int v = (t < nb) ? bsum[t] : 0;
    sh[t] = v; __syncthreads();
    for (int off = 1; off < 1024; off <<= 1) {
        int u = (t >= off) ? sh[t - off] : 0;
        __syncthreads();
        sh[t] += u;
        __syncthreads();
    }
    if (t < nb) bsum[t] = sh[t] - v;
}

__global__ void k_scan3(int* __restrict__ out, const int* __restrict__ bsum, int n) {
    int i = blockIdx.x * 256 + threadIdx.x;
    if (i < n) out[i] += bsum[blockIdx.x];
}

__global__ void k_scatter(const int* __restrict__ dst, const int* __restrict__ start,
                          int* __restrict__ cursor, int* __restrict__ eorder) {
    int e = blockIdx.x * 256 + threadIdx.x;
    if (e < E_EDGES) {
        int n = dst[e];
        int p = start[n] + atomicAdd(&cursor[n], 1);
        eorder[p] = e;
    }
}

__global__ void k_sortseg(const int* __restrict__ start, const int* __restrict__ deg,
                          int* __restrict__ eorder) {
    int n = blockIdx.x * 256 + threadIdx.x;
    if (n >= N_ENTS) return;
    int b = start[n], d = deg[n];
    for (int i = 1; i < d; i++) {
        int key = eorder[b + i];
        int j = i - 1;
        while (j >= 0 && eorder[b + j] > key) { eorder[b + j + 1] = eorder[b + j]; j--; }
        eorder[b + j + 1] = key;
    }
}

__global__ void k_mkidx(const int* __restrict__ eorder, const int* __restrict__ src,
                        const int* __restrict__ dst, const int* __restrict__ rel_id,
                        int4* __restrict__ sidx) {
    int slot = blockIdx.x * 256 + threadIdx.x;
    if (slot < E_EDGES) {
        int e = eorder[slot];
        sidx[slot] = make_int4(src[e], dst[e], rel_id[e], e);
    }
}

// ================= edge scores: 8 lanes/edge, 8 edges/wave =================
__global__ __launch_bounds__(256) void k_scores(
    const int4* __restrict__ sidx, const ushort* __restrict__ ep,
    const ushort* __restrict__ rel, float2* __restrict__ sc) {
    int gg = threadIdx.x >> 3, l = threadIdx.x & 7;
    int slot = blockIdx.x * 32 + gg;
    int4 si = sidx[slot];
    const ushort* rs = ep + (size_t)si.x * 256 + l * 32;
    const ushort* rd = ep + (size_t)si.y * 256 + l * 32;
    const ushort* rr = rel + (size_t)si.z * 128 + l * 16;
    u16x8 sv[4], dv[4], rv[2];
#pragma unroll
    for (int i = 0; i < 4; i++) sv[i] = *(const u16x8*)(rs + 8 * i);
#pragma unroll
    for (int i = 0; i < 4; i++) dv[i] = *(const u16x8*)(rd + 8 * i);
#pragma unroll
    for (int i = 0; i < 2; i++) rv[i] = *(const u16x8*)(rr + 8 * i);
    float a = 0.f, b = 0.f;
#pragma unroll
    for (int Q = 0; Q < 8; Q++) {
        int G = Q >> 1, k = (Q & 1) * 4;
        float r0 = b2f(rv[Q >> 2][(Q & 3) * 2]);
        float r1 = b2f(rv[Q >> 2][(Q & 3) * 2 + 1]);
        a += b2f(sv[G][k])     * r0 * b2f(dv[G][k])     + b2f(sv[G][k + 1]) * r1 * b2f(dv[G][k + 1]);
        b += b2f(sv[G][k + 2]) * r0 * b2f(dv[G][k + 2]) + b2f(sv[G][k + 3]) * r1 * b2f(dv[G][k + 3]);
    }
#pragma unroll
    for (int m = 4; m; m >>= 1) { a += __shfl_xor(a, m, 8); b += __shfl_xor(b, m, 8); }
    if (l == 0) sc[slot] = make_float2(a, b);
}

// ================= softmax + top-15: 16 lanes/node (rank by raw score) =========
__global__ __launch_bounds__(256) void k_softtop(
    const int* __restrict__ start, const int* __restrict__ deg,
    const float2* __restrict__ sc, float2* __restrict__ w) {
    int n = blockIdx.x * 16 + (threadIdx.x >> 4);
    int l = threadIdx.x & 15;
    if (n >= N_ENTS) return;
    int b = start[n], d = deg[n];
    if (d == 0) return;
    float m1 = -INFINITY, m2 = -INFINITY;
    for (int i = l; i < d; i += 16) {
        float2 s = sc[b + i];
        m1 = fmaxf(m1, s.x); m2 = fmaxf(m2, s.y);
    }
#pragma unroll
    for (int o = 8; o; o >>= 1) { m1 = fmaxf(m1, __shfl_xor(m1, o, 16)); m2 = fmaxf(m2, __shfl_xor(m2, o, 16)); }
    float z1 = 0.f, z2 = 0.f;
    for (int i = l; i < d; i += 16) {
        float2 s = sc[b + i];
        z1 += fexp2((s.x - m1) * L2E); z2 += fexp2((s.y - m2) * L2E);
    }
#pragma unroll
    for (int o = 8; o; o >>= 1) { z1 += __shfl_xor(z1, o, 16); z2 += __shfl_xor(z2, o, 16); }
    float iz1 = frcp(z1), iz2 = frcp(z2);
    for (int i = l; i < d; i += 16) {
        float2 sp = sc[b + i];
        int r1 = 0, r2 = 0;
        for (int j = 0; j < d; j++) {
            float2 sq = sc[b + j];
            r1 += (sq.x > sp.x) || (sq.x == sp.x && j < i);
            r2 += (sq.y > sp.y) || (sq.y == sp.y && j < i);
        }
        w[b + i] = make_float2(r1 < TOPK_K ? fexp2((sp.x - m1) * L2E) * iz1 : 0.f,
                               r2 < TOPK_K ? fexp2((sp.y - m2) * L2E) * iz2 : 0.f);
    }
}

// ================= weighted aggregation: block-per-node, 4 waves =================
__global__ __launch_bounds__(256) void k_agg(
    const int4* __restrict__ sidx, const int* __restrict__ start, const int* __restrict__ deg,
    const float2* __restrict__ w, const ushort* __restrict__ ep, const ushort* __restrict__ rel,
    ushort* __restrict__ neigh1, ushort* __restrict__ neigh2) {
    __shared__ float4 part[3][64];
    int n = blockIdx.x;
    int wid = threadIdx.x >> 6, g = threadIdx.x & 63;
    int b = start[n], d = deg[n];
    int end = b + d;
    float2 a1 = make_float2(0.f, 0.f), a2 = make_float2(0.f, 0.f);
    int s = b + wid;
    if (s < end) {
        int4 si = sidx[s];
        float2 ww = w[s];
        for (;;) {
            int sn = s + 4;
            bool more = sn < end;
            int4 si_n; float2 ww_n;
            if (more) { si_n = sidx[sn]; ww_n = w[sn]; }
            if (ww.x != 0.f || ww.y != 0.f) {
                u16x4 v = *(const u16x4*)(ep + (size_t)si.x * 256 + g * 4);
                uint  r = *(const uint*)(rel + (size_t)si.z * 128 + g * 2);
                float rx = b2f((ushort)(r & 0xffffu)), ry = b2f((ushort)(r >> 16));
                a1.x += ww.x * b2f(v[0]) * rx;  a1.y += ww.x * b2f(v[1]) * ry;
                a2.x += ww.y * b2f(v[2]) * rx;  a2.y += ww.y * b2f(v[3]) * ry;
            }
            if (!more) break;
            si = si_n; ww = ww_n; s = sn;
        }
    }
    if (wid > 0) part[wid - 1][g] = make_float4(a1.x, a1.y, a2.x, a2.y);
    __syncthreads();
    if (wid == 0) {
#pragma unroll
        for (int k = 0; k < 3; k++) {
            float4 p = part[k][g];
            a1.x += p.x; a1.y += p.y; a2.x += p.z; a2.y += p.w;
        }
        uint o1 = (uint)f2b(a1.x) | ((uint)f2b(a1.y) << 16);
        uint o2 = (uint)f2b(a2.x) | ((uint)f2b(a2.y) << 16);
        ((uint*)(neigh1 + (size_t)n * HD))[g] = o1;
        ((uint*)(neigh2 + (size_t)n * HD))[g] = o2;
    }
}

// ================= ent_out (bf16, padded rows zero) =================
__global__ void k_entout(const float* __restrict__ ent, const ushort* __restrict__ c1,
                         const ushort* __restrict__ c2, ushort* __restrict__ out) {
    int i = blockIdx.x * 256 + threadIdx.x;
    if (i >= NPAD_ENT * HD) return;
    int r = i >> 7;
    float v = 0.f;
    if (r < N_ENTS) v = ent[i] + b2f(c1[i]) + b2f(c2[i]);
    out[i] = (r < N_ENTS) ? f2b(v) : (ushort)0;
}

// ================= corr =================
__global__ void k_corr1(const float* __restrict__ x1, const float* __restrict__ x2,
                        float* __restrict__ red) {
    __shared__ float sa[1024], sb[1024];
    int t = threadIdx.x;
    float s1 = 0.f, s2 = 0.f;
    for (int i = t; i < N_ENTS; i += 1024) { s1 += x1[i]; s2 += x2[i]; }
    sa[t] = s1; sb[t] = s2; __syncthreads();
    for (int o = 512; o > 0; o >>= 1) {
        if (t < o) { sa[t] += sa[t + o]; sb[t] += sb[t + o]; }
        __syncthreads();
    }
    if (t == 0) { red[0] = sa[0] / (float)N_ENTS; red[1] = sb[0] / (float)N_ENTS; }
}

__global__ void k_corr2(const float* __restrict__ x1, const float* __restrict__ x2,
                        const float* __restrict__ red, float* __restrict__ out) {
    __shared__ float s11[1024], s22[1024], s12[1024];
    int t = threadIdx.x;
    float m1 = red[0], m2 = red[1];
    float a11 = 0.f, a22 = 0.f, a12 = 0.f;
    for (int i = t; i < N_ENTS; i += 1024) {
        float a = x1[i] - m1, b = x2[i] - m2;
        a11 += a * a; a22 += b * b; a12 += a * b;
    }
    s11[t] = a11; s22[t] = a22; s12[t] = a12; __syncthreads();
    for (int o = 512; o > 0; o >>= 1) {
        if (t < o) { s11[t] += s11[t + o]; s22[t] += s22[t + o]; s12[t] += s12[t + o]; }
        __syncthreads();
    }
    if (t == 0) {
        float v11 = s11[0] / (float)N_ENTS, v22 = s22[0] / (float)N_ENTS, v12 = s12[0] / (float)N_ENTS;
        out[0] = fabsf(v12) / (sqrtf(v11) * sqrtf(v22));
    }
}

// ================= ConvE conv =================
__global__ void k_conv(const int* __restrict__ h_id, const int* __restrict__ r_id,
                       const ushort* __restrict__ entout, const ushort* __restrict__ prel,
                       const float* __restrict__ cw, const float* __restrict__ cb,
                       ushort* __restrict__ out) {
    __shared__ float img[256];
    __shared__ float filt[C_CH * 49];
    int b = blockIdx.x, tid = threadIdx.x;
    if (tid < 128) img[tid] = b2f(entout[(size_t)h_id[b] * HD + tid]);
    else           img[tid] = b2f(prel[(size_t)r_id[b] * HD + (tid - 128)]);
    for (int i = tid; i < C_CH * 49; i += 256) filt[i] = cw[i];
    __syncthreads();
    for (int idx = tid; idx < FLATD; idx += 256) {
        int o = idx / 100, rem = idx % 100, i = rem / 10, j = rem % 10;
        float acc = cb[o];
        const float* f = &filt[o * 49];
#pragma unroll
        for (int ki = 0; ki < 7; ki++)
#pragma unroll
            for (int kj = 0; kj < 7; kj++)
                acc += img[(i + ki) * 16 + (j + kj)] * f[ki * 7 + kj];
        out[(size_t)b * FLATD + idx] = f2b(fmaxf(acc, 0.f));
    }
}

// ================= split-K reduce for fc =================
__global__ void k_fcreduce(const float* __restrict__ part, const float* __restrict__ bias,
                           ushort* __restrict__ out) {
    int i = blockIdx.x * 256 + threadIdx.x;
    if (i >= BSZ * HD) return;
    float s = 0.f;
    for (int z = 0; z < SPLITK; z++) s += part[(size_t)z * BSZ * HD + i];
    s += bias[i & (HD - 1)];
    out[i] = f2b(fmaxf(s, 0.f));
}

// ================= host launcher =================
extern "C" void kernel_launch(void* const* d_in, const int* in_sizes, int n_in,
                              void* d_out, int out_size, void* d_ws, size_t ws_size,
                              hipStream_t stream) {
    const int* h_id    = (const int*)d_in[0];
    const int* r_id    = (const int*)d_in[1];
    const int* src     = (const int*)d_in[2];
    const int* dst     = (const int*)d_in[3];
    const int* rel_id  = (const int*)d_in[4];
    const float* ent_emb  = (const float*)d_in[5];
    const float* rel_emb0 = (const float*)d_in[6];
    const float* neigh_w  = (const float*)d_in[7];
    const float* S_w = (const float*)d_in[8];
    const float* S_b = (const float*)d_in[9];
    const float* L_w = (const float*)d_in[10];
    const float* L_b = (const float*)d_in[11];
    const float* pred_rel = (const float*)d_in[12];
    const float* phi_w0 = (const float*)d_in[13]; const float* phi_b0 = (const float*)d_in[14];
    const float* phi_w1 = (const float*)d_in[15]; const float* phi_b1 = (const float*)d_in[16];
    const float* phi_w2 = (const float*)d_in[17]; const float* phi_b2 = (const float*)d_in[18];
    const float* psi_w0 = (const float*)d_in[19]; const float* psi_b0 = (const float*)d_in[20];
    const float* psi_w1 = (const float*)d_in[21]; const float* psi_b1 = (const float*)d_in[22];
    const float* psi_w2 = (const float*)d_in[23]; const float* psi_b2 = (const float*)d_in[24];
    const float* conv_w = (const float*)d_in[25]; const float* conv_b = (const float*)d_in[26];
    const float* fc_w   = (const float*)d_in[27]; const float* fc_b   = (const float*)d_in[28];
    const float* score_b= (const float*)d_in[29];

    char* base = (char*)d_ws;
    ushort* ep       = (ushort*)(base + OFF_EP);
    ushort* entout_bf= (ushort*)(base + OFF_ENTOUT);
    ushort* rel_bf   = (ushort*)(base + OFF_RELBF);
    ushort* prel_bf  = (ushort*)(base + OFF_PRELBF);
    ushort* Swt      = (ushort*)(base + OFF_SWT);
    ushort* Lwt      = (ushort*)(base + OFF_LWT);
    ushort* nWt      = (ushort*)(base + OFF_NWT);
    ushort* p0t      = (ushort*)(base + OFF_P0T);
    ushort* q0t      = (ushort*)(base + OFF_Q0T);
    ushort* p1t      = (ushort*)(base + OFF_P1T);
    ushort* q1t      = (ushort*)(base + OFF_Q1T);
    ushort* fct      = (ushort*)(base + OFF_FCT);
    float2* sc       = (float2*)(base + OFF_SC);
    float2* wpair    = (float2*)(base + OFF_W);
    int4*   sidx     = (int4*)(base + OFF_SIDX);
    int*    eorder   = (int*)(base + OFF_EORD);
    int*    deg      = (int*)(base + OFF_DEG);
    int*    startp   = (int*)(base + OFF_START);
    int*    cursor   = (int*)(base + OFF_CUR);
    int*    bsum     = (int*)(base + OFF_BSUM);
    float*  x1       = (float*)(base + OFF_X1);
    float*  x2       = (float*)(base + OFF_X2);
    float*  red      = (float*)(base + OFF_RED);
    ushort* xfc_bf   = (ushort*)(base + OFF_XFC);
    ushort* c1_bf    = (ushort*)(base + OFF_EP);                 // alias (ep dead after agg)
    ushort* c2_bf    = (ushort*)(base + OFF_EP + 12812288);
    ushort* ent_bf   = (ushort*)(base + OFF_ARENA);              // temp: arena before neigh use
    ushort* neigh1_bf= (ushort*)(base + OFF_ARENA);
    ushort* neigh2_bf= (ushort*)(base + OFF_ARENA + 12812288);
    ushort* convout  = (ushort*)(base + OFF_ARENA);
    float*  fcpart   = (float*)(base + OFF_ARENA + 22421504);
    float*  outf     = (float*)d_out;

    // ---- phase 0: conversions & weight transposes ----
    k_cvt<<<dim3((MPAD * HD + 255) / 256), 256, 0, stream>>>(ent_emb, ent_bf, N_ENTS, MPAD, HD);
    k_cvt<<<dim3((1000 * HD + 255) / 256), 256, 0, stream>>>(rel_emb0, rel_bf, 1000, 1000, HD);
    k_cvt<<<dim3((1000 * HD + 255) / 256), 256, 0, stream>>>(pred_rel, prel_bf, 1000, 1000, HD);
    k_tcvtT<<<dim3(4, 4), 256, 0, stream>>>(S_w, Swt, 128, 128, 128, 128);
    k_tcvtT<<<dim3(4, 4), 256, 0, stream>>>(L_w, Lwt, 128, 128, 128, 128);
    k_tcvtT<<<dim3(4, 4), 256, 0, stream>>>(neigh_w, nWt, 128, 128, 128, 128);
    k_tcvtT<<<dim3(4, 8), 256, 0, stream>>>(phi_w0, p0t, 128, HIDD, 128, NPAD200);
    k_tcvtT<<<dim3(4, 8), 256, 0, stream>>>(psi_w0, q0t, 128, HIDD, 128, NPAD200);
    k_tcvtT<<<dim3(7, 8), 256, 0, stream>>>(phi_w1, p1t, HIDD, HIDD, KPAD200, NPAD200);
    k_tcvtT<<<dim3(7, 8), 256, 0, stream>>>(psi_w1, q1t, HIDD, HIDD, KPAD200, NPAD200);
    k_tcvtT<<<dim3(300, 4), 256, 0, stream>>>(fc_w, fct, FLATD, 128, FLATD, 128);

    // ---- phase 1: projections (fused pair) -> interleaved ep table ----
    k_mgemm<2,2,1,1><<<dim3(391, 1, 2), 256, 0, stream>>>(
        ent_bf, HD, Swt, HD, S_b, ep, 256, N_ENTS, HD, HD, HD, 0, 0, HD,
        ent_bf, Lwt, L_b, ep, 2);

    // ---- phase 2: CSR build ----
    hipMemsetAsync(deg, 0, N_ENTS * sizeof(int), stream);
    hipMemsetAsync(cursor, 0, N_ENTS * sizeof(int), stream);
    k_deg<<<dim3((E_EDGES + 255) / 256), 256, 0, stream>>>(dst, deg);
    int nscan = (N_ENTS + 255) / 256;
    k_scan1<<<dim3(nscan), 256, 0, stream>>>(deg, startp, bsum, N_ENTS);
    k_scan2<<<dim3(1), 1024, 0, stream>>>(bsum, nscan);
    k_scan3<<<dim3(nscan), 256, 0, stream>>>(startp, bsum, N_ENTS);
    k_scatter<<<dim3((E_EDGES + 255) / 256), 256, 0, stream>>>(dst, startp, cursor, eorder);
    k_sortseg<<<dim3(nscan), 256, 0, stream>>>(startp, deg, eorder);
    k_mkidx<<<dim3((E_EDGES + 255) / 256), 256, 0, stream>>>(eorder, src, dst, rel_id, sidx);

    // ---- phase 3-5: edge pipeline ----
    k_scores<<<dim3(E_EDGES / 32), 256, 0, stream>>>(sidx, ep, rel_bf, sc);
    k_softtop<<<dim3((N_ENTS + 15) / 16), 256, 0, stream>>>(startp, deg, sc, wpair);
    k_agg<<<dim3(N_ENTS), 256, 0, stream>>>(sidx, startp, deg, wpair, ep, rel_bf,
                                            neigh1_bf, neigh2_bf);

    // ---- phase 6: c1/c2 = tanh(neigh @ W) (fused pair, write over dead ep) ----
    k_mgemm<2,2,1,1><<<dim3(391, 1, 2), 256, 0, stream>>>(
        neigh1_bf, HD, nWt, HD, nullptr, c1_bf, HD, N_ENTS, HD, HD, HD, 2, -1, HD,
        neigh2_bf, nWt, nullptr, c2_bf, -1);

    // ---- phase 7: ent_out ----
    k_entout<<<dim3((NPAD_ENT * HD + 255) / 256), 256, 0, stream>>>(ent_emb, c1_bf, c2_bf, entout_bf);

    // ---- phase 8: fused MLPs ----
    k_mlp2<<<dim3(MPAD / 64), 256, 0, stream>>>(c1_bf, p0t, phi_b0, p1t, phi_b1, phi_w2, phi_b2, x1);
    k_mlp2<<<dim3(MPAD / 64), 256, 0, stream>>>(c2_bf, q0t, psi_b0, q1t, psi_b1, psi_w2, psi_b2, x2);

    // ---- phase 9: corr ----
    k_corr1<<<dim3(1), 1024, 0, stream>>>(x1, x2, red);
    k_corr2<<<dim3(1), 1024, 0, stream>>>(x1, x2, red, outf + OUT_SCORE);

    // ---- phase 10-11: ConvE ----
    k_conv<<<dim3(BSZ), 256, 0, stream>>>(h_id, r_id, entout_bf, prel_bf, conv_w, conv_b, convout);
    k_mgemm<2,2,0,0><<<dim3(8, 1, SPLITK), 256, 0, stream>>>(
        convout, FLATD, fct, FLATD, nullptr, fcpart, HD, BSZ, HD, FLATD, FLATD / SPLITK, 0, -1, HD,
        nullptr, nullptr, nullptr, nullptr, 0);
    k_fcreduce<<<dim3((BSZ * HD + 255) / 256), 256, 0, stream>>>(fcpart, fc_b, xfc_bf);

    // ---- phase 12: score GEMM (LDS-staged float4 stores, exp2 sigmoid) ----
    k_score<<<dim3(16, 196), 256, 0, stream>>>(xfc_bf, entout_bf, score_b, outf, N_ENTS);
}

// Round 6
// 699.444 us; speedup vs baseline: 2.6792x; 1.1508x over previous
//
#include <hip/hip_runtime.h>
#include <math.h>

typedef unsigned short ushort;
typedef unsigned int   uint;
typedef short bf16x8 __attribute__((ext_vector_type(8)));
typedef float f32x4  __attribute__((ext_vector_type(4)));
typedef ushort u16x8 __attribute__((ext_vector_type(8)));
typedef ushort u16x4 __attribute__((ext_vector_type(4)));

// ---------------- problem constants ----------------
#define N_ENTS   50000
#define E_EDGES  800000
#define HD       128
#define BSZ      1024
#define C_CH     96
#define FLATD    9600
#define TOPK_K   15
#define HIDD     200
#define SPLITK   10
#define OUT_SCORE ((size_t)BSZ * N_ENTS)

#define MPAD     50048            // 391*128
#define NPAD_ENT 50176            // 196*256
#define KPAD200  224
#define NPAD200  256
#define L2E      1.4426950408889634f

// ---------------- workspace layout (byte offsets) ----------------
#define OFF_EP       ((size_t)0)            // ushort [50048][256] interleaved c/p (c1/c2 alias later)
#define OFF_ENTOUT   ((size_t)25624576)     // ushort [50176][128]
#define OFF_RELBF    ((size_t)38469632)     // ushort [1000][128]
#define OFF_PRELBF   ((size_t)38725632)
#define OFF_SWT      ((size_t)38981632)     // ushort [128][128]
#define OFF_LWT      ((size_t)39014400)
#define OFF_NWT      ((size_t)39047168)
#define OFF_P0T      ((size_t)39079936)     // ushort [256][128]
#define OFF_Q0T      ((size_t)39145472)
#define OFF_P1T      ((size_t)39211008)     // ushort [256][224]
#define OFF_Q1T      ((size_t)39325696)
#define OFF_FCT      ((size_t)39440384)     // ushort [128][9600]
#define OFF_SC       ((size_t)41897984)     // float2 [800000]
#define OFF_W        ((size_t)48297984)     // float2 [800000]
#define OFF_SIDX     ((size_t)54697984)     // int4 [800000]
#define OFF_EORD     ((size_t)67497984)     // int [800000]
#define OFF_DEG      ((size_t)70697984)     // int [50000]
#define OFF_START    ((size_t)70897984)
#define OFF_CUR      ((size_t)71097984)
#define OFF_BSUM     ((size_t)71297984)     // int [1024]
#define OFF_X1       ((size_t)71302080)     // float [50000]
#define OFF_X2       ((size_t)71502080)
#define OFF_RED      ((size_t)71702080)     // float [64]
#define OFF_XFC      ((size_t)71702336)     // ushort [1024][128]
#define OFF_ARENA    ((size_t)71964480)     // 44,843,008 bytes -> total 116,807,488
// arena: ent_bf=+0 (u16[50048][128]) [dead after proj]
//        neigh1=+0, neigh2=+12812288 [dead after tanh GEMMs]
//        convout=+0 (u16[1024][9600]), fcpart=+22421504 (f32[10][1024][128])
// c1 = EP+0 (u16[50048][128]), c2 = EP+12812288  (EP dead after k_agg)

// ---------------- helpers ----------------
__device__ inline ushort f2b(float f) {
    uint u = __float_as_uint(f);
    return (ushort)((u + 0x7fffu + ((u >> 16) & 1u)) >> 16);  // RNE
}
__device__ inline float b2f(ushort u) { return __uint_as_float((uint)u << 16); }
__device__ inline float fexp2(float x) { return __builtin_amdgcn_exp2f(x); }
__device__ inline float frcp(float x)  { return __builtin_amdgcn_rcpf(x); }
__device__ inline float fsigmoid(float x) { return frcp(1.f + fexp2(-x * L2E)); }
__device__ inline float ftanh(float x) {
    float ax = fabsf(x);
    float t = fexp2(ax * (-2.f * L2E));
    float r = (1.f - t) * frcp(1.f + t);
    return copysignf(r, x);
}

// ---------------- conversion kernels ----------------
__global__ void k_cvt(const float* __restrict__ in, ushort* __restrict__ out,
                      int M, int Mpad, int K) {
    int i = blockIdx.x * 256 + threadIdx.x;
    if (i >= Mpad * K) return;
    int r = i / K;
    out[i] = (r < M) ? f2b(in[i]) : (ushort)0;
}

// rel + prel in one launch (z switch)
__global__ void k_cvt2(const float* __restrict__ in0, ushort* __restrict__ out0,
                       const float* __restrict__ in1, ushort* __restrict__ out1, int n) {
    const float* in = blockIdx.z ? in1 : in0;
    ushort* out = blockIdx.z ? out1 : out0;
    int i = blockIdx.x * 256 + threadIdx.x;
    if (i < n) out[i] = f2b(in[i]);
}

// tiled transpose-convert: f32 in[K][N] -> bf16 out[Npad][Kpad], pads zero
__global__ __launch_bounds__(256) void k_tcvtT(const float* __restrict__ in, ushort* __restrict__ out,
                                               int K, int N, int Kpad, int Npad) {
    __shared__ float t[32][33];
    int k0 = blockIdx.x * 32, n0 = blockIdx.y * 32;
    int tx = threadIdx.x & 31, ty = threadIdx.x >> 5;
    for (int i = ty; i < 32; i += 8) {
        int k = k0 + i, n = n0 + tx;
        t[i][tx] = (k < K && n < N) ? in[(size_t)k * N + n] : 0.f;
    }
    __syncthreads();
    for (int i = ty; i < 32; i += 8) {
        int n = n0 + i, k = k0 + tx;
        if (n < Npad && k < Kpad) out[(size_t)n * Kpad + k] = f2b(t[tx][i]);
    }
}

// all 7 small weight transposes in one launch (z picks matrix)
__global__ __launch_bounds__(256) void k_tcvt7(
    const float* __restrict__ S_w, const float* __restrict__ L_w, const float* __restrict__ n_w,
    const float* __restrict__ p0, const float* __restrict__ q0,
    const float* __restrict__ p1, const float* __restrict__ q1,
    ushort* __restrict__ Swt, ushort* __restrict__ Lwt, ushort* __restrict__ nWt,
    ushort* __restrict__ p0t, ushort* __restrict__ q0t,
    ushort* __restrict__ p1t, ushort* __restrict__ q1t) {
    const float* in; ushort* out; int K, N, Kp, Np;
    switch (blockIdx.z) {
        case 0: in = S_w; out = Swt; K = 128; N = 128; Kp = 128; Np = 128; break;
        case 1: in = L_w; out = Lwt; K = 128; N = 128; Kp = 128; Np = 128; break;
        case 2: in = n_w; out = nWt; K = 128; N = 128; Kp = 128; Np = 128; break;
        case 3: in = p0;  out = p0t; K = 128; N = HIDD; Kp = 128; Np = NPAD200; break;
        case 4: in = q0;  out = q0t; K = 128; N = HIDD; Kp = 128; Np = NPAD200; break;
        case 5: in = p1;  out = p1t; K = HIDD; N = HIDD; Kp = KPAD200; Np = NPAD200; break;
        default: in = q1; out = q1t; K = HIDD; N = HIDD; Kp = KPAD200; Np = NPAD200; break;
    }
    __shared__ float t[32][33];
    int k0 = blockIdx.x * 32, n0 = blockIdx.y * 32;
    if (k0 >= Kp || n0 >= Np) return;
    int tx = threadIdx.x & 31, ty = threadIdx.x >> 5;
    for (int i = ty; i < 32; i += 8) {
        int k = k0 + i, n = n0 + tx;
        t[i][tx] = (k < K && n < N) ? in[(size_t)k * N + n] : 0.f;
    }
    __syncthreads();
    for (int i = ty; i < 32; i += 8) {
        int n = n0 + i, k = k0 + tx;
        if (n < Np && k < Kp) out[(size_t)n * Kp + k] = f2b(t[tx][i]);
    }
}

// ================= MFMA bf16 GEMM (generic) =================
template <int WM, int WN, int OUTBF, int FUSE2>
__global__ __launch_bounds__(256) void k_mgemm(
    const ushort* __restrict__ A, int lda,
    const ushort* __restrict__ Bt, int ldb,
    const float* __restrict__ bias, void* __restrict__ Cout, int ldc,
    int M, int N, int K, int kChunk, int epi, int iofs, int npad,
    const ushort* __restrict__ A2, const ushort* __restrict__ Bt2,
    const float* __restrict__ bias2, void* __restrict__ Cout2, int iofs2) {
    if (FUSE2 && blockIdx.z == 1) { A = A2; Bt = Bt2; bias = bias2; Cout = Cout2; iofs = iofs2; }
    const int w = threadIdx.x >> 6, lane = threadIdx.x & 63;
    const int wr = w / WN, wc = w % WN;
    const int row0 = blockIdx.x * (WM * 64) + wr * 64;
    const int col0 = blockIdx.y * (WN * 64) + wc * 64;
    const int lr = lane & 15;
    const int kg = (lane >> 4) * 8;
    const int kb = FUSE2 ? 0 : blockIdx.z * kChunk;
    const int ke = kb + kChunk;

    f32x4 acc[4][4];
#pragma unroll
    for (int i = 0; i < 4; i++)
#pragma unroll
        for (int j = 0; j < 4; j++) acc[i][j] = (f32x4){0.f, 0.f, 0.f, 0.f};

    for (int kk = kb; kk < ke; kk += 32) {
        bf16x8 af[4], bfr[4];
#pragma unroll
        for (int i = 0; i < 4; i++) {
            int r = row0 + i * 16 + lr;
            r = min(r, M - 1);
            af[i] = *(const bf16x8*)(A + (size_t)r * lda + kk + kg);
        }
#pragma unroll
        for (int j = 0; j < 4; j++) {
            int c = col0 + j * 16 + lr;
            bfr[j] = *(const bf16x8*)(Bt + (size_t)c * ldb + kk + kg);
        }
#pragma unroll
        for (int i = 0; i < 4; i++)
#pragma unroll
            for (int j = 0; j < 4; j++)
                acc[i][j] = __builtin_amdgcn_mfma_f32_16x16x32_bf16(af[i], bfr[j], acc[i][j], 0, 0, 0);
    }

    const int cr = (lane >> 4) * 4, cc = lane & 15;
    if (!FUSE2 && gridDim.z > 1) {
        float* P = (float*)Cout + (size_t)blockIdx.z * M * ldc;
#pragma unroll
        for (int i = 0; i < 4; i++)
#pragma unroll
            for (int j = 0; j < 4; j++) {
                int col = col0 + j * 16 + cc;
                if (col >= N) continue;
#pragma unroll
                for (int t = 0; t < 4; t++) {
                    int row = row0 + i * 16 + cr + t;
                    if (row < M) P[(size_t)row * ldc + col] = acc[i][j][t];
                }
            }
    } else {
#pragma unroll
        for (int i = 0; i < 4; i++)
#pragma unroll
            for (int j = 0; j < 4; j++) {
                int col = col0 + j * 16 + cc;
                if (col >= (OUTBF ? npad : N)) continue;
                bool valid = col < N;
                float bi = (bias && valid) ? bias[col] : 0.f;
#pragma unroll
                for (int t = 0; t < 4; t++) {
                    int row = row0 + i * 16 + cr + t;
                    if (row >= M) continue;
                    float v = acc[i][j][t] + bi;
                    if (epi == 1) v = fmaxf(v, 0.f);
                    else if (epi == 2) v = ftanh(v);
                    else if (epi == 3) v = fsigmoid(v);
                    if (!valid) v = 0.f;
                    if (OUTBF) {
                        size_t idx = (iofs < 0) ? ((size_t)row * ldc + col)
                                   : ((size_t)row * ldc + ((size_t)(col >> 1) << 2) + (col & 1) + iofs);
                        ((ushort*)Cout)[idx] = f2b(v);
                    } else {
                        ((float*)Cout)[(size_t)row * ldc + col] = v;
                    }
                }
            }
    }
}

// ================= score GEMM: XCD-swizzled, LDS-staged float4 stores ========
// grid (16,196) = 3136 blocks; bijective swizzle gives each XCD a contiguous
// y-panel range so the entout B-panel is fetched ~once per XCD, not ~8x.
__global__ __launch_bounds__(256) void k_score(
    const ushort* __restrict__ A,      // [1024][128] xfc bf16
    const ushort* __restrict__ Bt,     // [50176][128] entout bf16
    const float* __restrict__ bias,    // [50000]
    float* __restrict__ C, int N) {    // [1024][N]
    __shared__ __align__(16) float st[4][16][68];
    const int w = threadIdx.x >> 6, lane = threadIdx.x & 63;
    const int lr = lane & 15, kg = (lane >> 4) * 8;
    const int cr = (lane >> 4) * 4, cc = lane & 15;
    int flat = blockIdx.y * 16 + blockIdx.x;          // hw dispatch order
    int swz = (flat & 7) * 392 + (flat >> 3);         // 3136 = 8 * 392
    const int row0 = (swz & 15) * 64;
    const int colw = (swz >> 4) * 256 + w * 64;

    f32x4 acc[4][4];
#pragma unroll
    for (int i = 0; i < 4; i++)
#pragma unroll
        for (int j = 0; j < 4; j++) acc[i][j] = (f32x4){0.f, 0.f, 0.f, 0.f};

    for (int kk = 0; kk < HD; kk += 32) {
        bf16x8 af[4], bfr[4];
#pragma unroll
        for (int i = 0; i < 4; i++)
            af[i] = *(const bf16x8*)(A + (size_t)(row0 + i * 16 + lr) * HD + kk + kg);
#pragma unroll
        for (int j = 0; j < 4; j++)
            bfr[j] = *(const bf16x8*)(Bt + (size_t)(colw + j * 16 + lr) * HD + kk + kg);
#pragma unroll
        for (int i = 0; i < 4; i++)
#pragma unroll
            for (int j = 0; j < 4; j++)
                acc[i][j] = __builtin_amdgcn_mfma_f32_16x16x32_bf16(af[i], bfr[j], acc[i][j], 0, 0, 0);
    }

#pragma unroll
    for (int i = 0; i < 4; i++) {
#pragma unroll
        for (int j = 0; j < 4; j++) {
            int col = colw + j * 16 + cc;
            float bi = (col < N) ? bias[col] : 0.f;
#pragma unroll
            for (int t = 0; t < 4; t++)
                st[w][cr + t][j * 16 + cc] = fsigmoid(acc[i][j][t] + bi);
        }
#pragma unroll
        for (int p = 0; p < 4; p++) {
            int r = p * 4 + (lane >> 4);
            int cq = (lane & 15) * 4;
            float4 v = *(const float4*)&st[w][r][cq];
            int gc = colw + cq;
            if (gc < N)
                *(float4*)&C[(size_t)(row0 + i * 16 + r) * N + gc] = v;
        }
    }
}

// ================= fused 3-layer MLP (both MLPs via z switch) =================
__global__ __launch_bounds__(256) void k_mlp2(
    const ushort* __restrict__ A0, const ushort* __restrict__ W0t0,
    const float* __restrict__ b00, const ushort* __restrict__ W1t0,
    const float* __restrict__ b10, const float* __restrict__ w20,
    const float* __restrict__ b20, float* __restrict__ xo0,
    const ushort* __restrict__ A1, const ushort* __restrict__ W0t1,
    const float* __restrict__ b01, const ushort* __restrict__ W1t1,
    const float* __restrict__ b11, const float* __restrict__ w21,
    const float* __restrict__ b21, float* __restrict__ xo1) {
    const ushort* A   = blockIdx.z ? A1 : A0;
    const ushort* W0t = blockIdx.z ? W0t1 : W0t0;
    const float*  b0  = blockIdx.z ? b01 : b00;
    const ushort* W1t = blockIdx.z ? W1t1 : W1t0;
    const float*  b1  = blockIdx.z ? b11 : b10;
    const float*  w2  = blockIdx.z ? w21 : w20;
    const float*  b2  = blockIdx.z ? b21 : b20;
    float*        x   = blockIdx.z ? xo1 : xo0;

    __shared__ __align__(16) char lbuf[64 * 232 * 2];
    __shared__ float w2e[256], b1e[256], b0e[256];
    const int tid = threadIdx.x;
    const int w = tid >> 6, lane = tid & 63;
    const int lr = lane & 15, kg = (lane >> 4) * 8;
    const int cr = (lane >> 4) * 4, cc = lane & 15;
    const int row0 = blockIdx.x * 64;
    {
        int c = tid;
        w2e[c] = (c < HIDD) ? w2[c] : 0.f;
        b1e[c] = (c < HIDD) ? b1[c] : 0.f;
        b0e[c] = (c < HIDD) ? b0[c] : 0.f;
    }
    __syncthreads();
    ushort* g1 = (ushort*)lbuf;

    f32x4 acc[4][4];
#pragma unroll
    for (int i = 0; i < 4; i++)
#pragma unroll
        for (int j = 0; j < 4; j++) acc[i][j] = (f32x4){0.f, 0.f, 0.f, 0.f};
    for (int kk = 0; kk < 128; kk += 32) {
        bf16x8 af[4], bfr[4];
#pragma unroll
        for (int i = 0; i < 4; i++)
            af[i] = *(const bf16x8*)(A + (size_t)(row0 + i * 16 + lr) * HD + kk + kg);
#pragma unroll
        for (int j = 0; j < 4; j++)
            bfr[j] = *(const bf16x8*)(W0t + (size_t)(w * 64 + j * 16 + lr) * 128 + kk + kg);
#pragma unroll
        for (int i = 0; i < 4; i++)
#pragma unroll
            for (int j = 0; j < 4; j++)
                acc[i][j] = __builtin_amdgcn_mfma_f32_16x16x32_bf16(af[i], bfr[j], acc[i][j], 0, 0, 0);
    }
#pragma unroll
    for (int i = 0; i < 4; i++)
#pragma unroll
        for (int j = 0; j < 4; j++) {
            int col = w * 64 + j * 16 + cc;
            if (col < KPAD200) {
                float bi = b0e[col];
#pragma unroll
                for (int t = 0; t < 4; t++)
                    g1[(i * 16 + cr + t) * 232 + col] = f2b(fmaxf(acc[i][j][t] + bi, 0.f));
            }
        }
    __syncthreads();

    f32x4 a2[4][4];
#pragma unroll
    for (int i = 0; i < 4; i++)
#pragma unroll
        for (int j = 0; j < 4; j++) a2[i][j] = (f32x4){0.f, 0.f, 0.f, 0.f};
    for (int ks = 0; ks < 7; ks++) {
        int kk = ks * 32;
        bf16x8 af[4], bfr[4];
#pragma unroll
        for (int i = 0; i < 4; i++)
            af[i] = *(const bf16x8*)(g1 + (i * 16 + lr) * 232 + kk + kg);
#pragma unroll
        for (int j = 0; j < 4; j++)
            bfr[j] = *(const bf16x8*)(W1t + (size_t)(w * 64 + j * 16 + lr) * KPAD200 + kk + kg);
#pragma unroll
        for (int i = 0; i < 4; i++)
#pragma unroll
            for (int j = 0; j < 4; j++)
                a2[i][j] = __builtin_amdgcn_mfma_f32_16x16x32_bf16(af[i], bfr[j], a2[i][j], 0, 0, 0);
    }
    __syncthreads();

    float* pbuf = (float*)lbuf;   // [64][65]
#pragma unroll
    for (int i = 0; i < 4; i++)
#pragma unroll
        for (int t = 0; t < 4; t++) {
            float s = 0.f;
#pragma unroll
            for (int j = 0; j < 4; j++) {
                int col = w * 64 + j * 16 + cc;
                s += fmaxf(a2[i][j][t] + b1e[col], 0.f) * w2e[col];
            }
            pbuf[(i * 16 + cr + t) * 65 + w * 16 + cc] = s;
        }
    __syncthreads();
    if (tid < 64) {
        float s = b2[0];
        for (int q = 0; q < 64; q++) s += pbuf[tid * 65 + q];
        int gr = row0 + tid;
        if (gr < N_ENTS) x[gr] = s;
    }
}

// ================= CSR build =================
__global__ void k_deg(const int* __restrict__ dst, int* __restrict__ deg) {
    int e = blockIdx.x * 256 + threadIdx.x;
    if (e < E_EDGES) atomicAdd(&deg[dst[e]], 1);
}

__global__ void k_scan1(const int* __restrict__ in, int* __restrict__ out,
                        int* __restrict__ bsum, int n) {
    __shared__ int sh[256];
    int i = blockIdx.x * 256 + threadIdx.x;
    int v = (i < n) ? in[i] : 0;
    sh[threadIdx.x] = v; __syncthreads();
    for (int off = 1; off < 256; off <<= 1) {
        int t = (threadIdx.x >= off) ? sh[threadIdx.x - off] : 0;
        __syncthreads();
        sh[threadIdx.x] += t;
        __syncthreads();
    }
    if (i < n) out[i] = sh[threadIdx.x] - v;
    if (threadIdx.x == 255) bsum[blockIdx.x] = sh[255];
}

__global__ void k_scan2(int* __restrict__ bsum, int nb) {
    __shared__ int sh[1024];
    int t = threadIdx.x;
    int v = (t < nb) ? bsum[t] : 0;
    sh[t] = v; __syncthreads();
    for (int off = 1; off < 1024; off <<= 1) {
        int u = (t >= off) ? sh[t - off] : 0;
        __syncthreads();
        sh[t] += u;
        __syncthreads();
    }
    if (t < nb) bsum[t] = sh[t] - v;
}

__global__ void k_scan3(int* __restrict__ out, const int* __restrict__ bsum, int n) {
    int i = blockIdx.x * 256 + threadIdx.x;
    if (i < n) out[i] += bsum[blockIdx.x];
}

__global__ void k_scatter(const int* __restrict__ dst, const int* __restrict__ start,
                          int* __restrict__ cursor, int* __restrict__ eorder) {
    int e = blockIdx.x * 256 + threadIdx.x;
    if (e < E_EDGES) {
        int n = dst[e];
        int p = start[n] + atomicAdd(&cursor[n], 1);
        eorder[p] = e;
    }
}

__global__ void k_mkidx(const int* __restrict__ eorder, const int* __restrict__ src,
                        const int* __restrict__ dst, const int* __restrict__ rel_id,
                        int4* __restrict__ sidx) {
    int slot = blockIdx.x * 256 + threadIdx.x;
    if (slot < E_EDGES) {
        int e = eorder[slot];
        sidx[slot] = make_int4(src[e], dst[e], rel_id[e], e);
    }
}

// ================= edge scores: 8 lanes/edge, 8 edges/wave =================
__global__ __launch_bounds__(256) void k_scores(
    const int4* __restrict__ sidx, const ushort* __restrict__ ep,
    const ushort* __restrict__ rel, float2* __restrict__ sc) {
    int gg = threadIdx.x >> 3, l = threadIdx.x & 7;
    int slot = blockIdx.x * 32 + gg;
    int4 si = sidx[slot];
    const ushort* rs = ep + (size_t)si.x * 256 + l * 32;
    const ushort* rd = ep + (size_t)si.y * 256 + l * 32;
    const ushort* rr = rel + (size_t)si.z * 128 + l * 16;
    u16x8 sv[4], dv[4], rv[2];
#pragma unroll
    for (int i = 0; i < 4; i++) sv[i] = *(const u16x8*)(rs + 8 * i);
#pragma unroll
    for (int i = 0; i < 4; i++) dv[i] = *(const u16x8*)(rd + 8 * i);
#pragma unroll
    for (int i = 0; i < 2; i++) rv[i] = *(const u16x8*)(rr + 8 * i);
    float a = 0.f, b = 0.f;
#pragma unroll
    for (int Q = 0; Q < 8; Q++) {
        int G = Q >> 1, k = (Q & 1) * 4;
        float r0 = b2f(rv[Q >> 2][(Q & 3) * 2]);
        float r1 = b2f(rv[Q >> 2][(Q & 3) * 2 + 1]);
        a += b2f(sv[G][k])     * r0 * b2f(dv[G][k])     + b2f(sv[G][k + 1]) * r1 * b2f(dv[G][k + 1]);
        b += b2f(sv[G][k + 2]) * r0 * b2f(dv[G][k + 2]) + b2f(sv[G][k + 3]) * r1 * b2f(dv[G][k + 3]);
    }
#pragma unroll
    for (int m = 4; m; m >>= 1) { a += __shfl_xor(a, m, 8); b += __shfl_xor(b, m, 8); }
    if (l == 0) sc[slot] = make_float2(a, b);
}

// ===== softmax + top-15: 16 lanes/node, tie-break by TRUE edge id (no sortseg) =====
__global__ __launch_bounds__(256) void k_softtop(
    const int* __restrict__ start, const int* __restrict__ deg,
    const int4* __restrict__ sidx, const float2* __restrict__ sc, float2* __restrict__ w) {
    int n = blockIdx.x * 16 + (threadIdx.x >> 4);
    int l = threadIdx.x & 15;
    if (n >= N_ENTS) return;
    int b = start[n], d = deg[n];
    if (d == 0) return;
    float m1 = -INFINITY, m2 = -INFINITY;
    for (int i = l; i < d; i += 16) {
        float2 s = sc[b + i];
        m1 = fmaxf(m1, s.x); m2 = fmaxf(m2, s.y);
    }
#pragma unroll
    for (int o = 8; o; o >>= 1) { m1 = fmaxf(m1, __shfl_xor(m1, o, 16)); m2 = fmaxf(m2, __shfl_xor(m2, o, 16)); }
    float z1 = 0.f, z2 = 0.f;
    for (int i = l; i < d; i += 16) {
        float2 s = sc[b + i];
        z1 += fexp2((s.x - m1) * L2E); z2 += fexp2((s.y - m2) * L2E);
    }
#pragma unroll
    for (int o = 8; o; o >>= 1) { z1 += __shfl_xor(z1, o, 16); z2 += __shfl_xor(z2, o, 16); }
    float iz1 = frcp(z1), iz2 = frcp(z2);
    for (int i = l; i < d; i += 16) {
        float2 sp = sc[b + i];
        int ei = sidx[b + i].w;
        int r1 = 0, r2 = 0;
        for (int j = 0; j < d; j++) {
            float2 sq = sc[b + j];
            int ej = sidx[b + j].w;
            r1 += (sq.x > sp.x) || (sq.x == sp.x && ej < ei);
            r2 += (sq.y > sp.y) || (sq.y == sp.y && ej < ei);
        }
        w[b + i] = make_float2(r1 < TOPK_K ? fexp2((sp.x - m1) * L2E) * iz1 : 0.f,
                               r2 < TOPK_K ? fexp2((sp.y - m2) * L2E) * iz2 : 0.f);
    }
}

// ====== weighted aggregation: block-per-node, 4 waves, 2 gather chains/wave ======
__global__ __launch_bounds__(256) void k_agg(
    const int4* __restrict__ sidx, const int* __restrict__ start, const int* __restrict__ deg,
    const float2* __restrict__ w, const ushort* __restrict__ ep, const ushort* __restrict__ rel,
    ushort* __restrict__ neigh1, ushort* __restrict__ neigh2) {
    __shared__ float4 part[3][64];
    int n = blockIdx.x;
    int wid = threadIdx.x >> 6, g = threadIdx.x & 63;
    int b = start[n], end = b + deg[n];
    float2 a1 = make_float2(0.f, 0.f), a2 = make_float2(0.f, 0.f);
    float2 c1 = make_float2(0.f, 0.f), c2 = make_float2(0.f, 0.f);
    for (int s = b + wid; s < end; s += 8) {
        int sB = s + 4;
        bool hB = sB < end;
        int4 siA = sidx[s];
        float2 wA = w[s];
        int4 siB = hB ? sidx[sB] : siA;
        float2 wB = hB ? w[sB] : make_float2(0.f, 0.f);
        u16x4 vA = *(const u16x4*)(ep + (size_t)siA.x * 256 + g * 4);
        uint  rA = *(const uint*)(rel + (size_t)siA.z * 128 + g * 2);
        u16x4 vB = *(const u16x4*)(ep + (size_t)siB.x * 256 + g * 4);
        uint  rB = *(const uint*)(rel + (size_t)siB.z * 128 + g * 2);
        float rAx = b2f((ushort)(rA & 0xffffu)), rAy = b2f((ushort)(rA >> 16));
        a1.x += wA.x * b2f(vA[0]) * rAx;  a1.y += wA.x * b2f(vA[1]) * rAy;
        a2.x += wA.y * b2f(vA[2]) * rAx;  a2.y += wA.y * b2f(vA[3]) * rAy;
        float rBx = b2f((ushort)(rB & 0xffffu)), rBy = b2f((ushort)(rB >> 16));
        c1.x += wB.x * b2f(vB[0]) * rBx;  c1.y += wB.x * b2f(vB[1]) * rBy;
        c2.x += wB.y * b2f(vB[2]) * rBx;  c2.y += wB.y * b2f(vB[3]) * rBy;
    }
    a1.x += c1.x; a1.y += c1.y; a2.x += c2.x; a2.y += c2.y;
    if (wid > 0) part[wid - 1][g] = make_float4(a1.x, a1.y, a2.x, a2.y);
    __syncthreads();
    if (wid == 0) {
#pragma unroll
        for (int k = 0; k < 3; k++) {
            float4 p = part[k][g];
            a1.x += p.x; a1.y += p.y; a2.x += p.z; a2.y += p.w;
        }
        uint o1 = (uint)f2b(a1.x) | ((uint)f2b(a1.y) << 16);
        uint o2 = (uint)f2b(a2.x) | ((uint)f2b(a2.y) << 16);
        ((uint*)(neigh1 + (size_t)n * HD))[g] = o1;
        ((uint*)(neigh2 + (size_t)n * HD))[g] = o2;
    }
}

// ================= ent_out (bf16, padded rows zero) =================
__global__ void k_entout(const float* __restrict__ ent, const ushort* __restrict__ c1,
                         const ushort* __restrict__ c2, ushort* __restrict__ out) {
    int i = blockIdx.x * 256 + threadIdx.x;
    if (i >= NPAD_ENT * HD) return;
    int r = i >> 7;
    float v = 0.f;
    if (r < N_ENTS) v = ent[i] + b2f(c1[i]) + b2f(c2[i]);
    out[i] = (r < N_ENTS) ? f2b(v) : (ushort)0;
}

// ================= corr =================
__global__ void k_corr1(const float* __restrict__ x1, const float* __restrict__ x2,
                        float* __restrict__ red) {
    __shared__ float sa[1024], sb[1024];
    int t = threadIdx.x;
    float s1 = 0.f, s2 = 0.f;
    for (int i = t; i < N_ENTS; i += 1024) { s1 += x1[i]; s2 += x2[i]; }
    sa[t] = s1; sb[t] = s2; __syncthreads();
    for (int o = 512; o > 0; o >>= 1) {
        if (t < o) { sa[t] += sa[t + o]; sb[t] += sb[t + o]; }
        __syncthreads();
    }
    if (t == 0) { red[0] = sa[0] / (float)N_ENTS; red[1] = sb[0] / (float)N_ENTS; }
}

__global__ void k_corr2(const float* __restrict__ x1, const float* __restrict__ x2,
                        const float* __restrict__ red, float* __restrict__ out) {
    __shared__ float s11[1024], s22[1024], s12[1024];
    int t = threadIdx.x;
    float m1 = red[0], m2 = red[1];
    float a11 = 0.f, a22 = 0.f, a12 = 0.f;
    for (int i = t; i < N_ENTS; i += 1024) {
        float a = x1[i] - m1, b = x2[i] - m2;
        a11 += a * a; a22 += b * b; a12 += a * b;
    }
    s11[t] = a11; s22[t] = a22; s12[t] = a12; __syncthreads();
    for (int o = 512; o > 0; o >>= 1) {
        if (t < o) { s11[t] += s11[t + o]; s22[t] += s22[t + o]; s12[t] += s12[t + o]; }
        __syncthreads();
    }
    if (t == 0) {
        float v11 = s11[0] / (float)N_ENTS, v22 = s22[0] / (float)N_ENTS, v12 = s12[0] / (float)N_ENTS;
        out[0] = fabsf(v12) / (sqrtf(v11) * sqrtf(v22));
    }
}

// ================= ConvE conv =================
__global__ void k_conv(const int* __restrict__ h_id, const int* __restrict__ r_id,
                       const ushort* __restrict__ entout, const ushort* __restrict__ prel,
                       const float* __restrict__ cw, const float* __restrict__ cb,
                       ushort* __restrict__ out) {
    __shared__ float img[256];
    __shared__ float filt[C_CH * 49];
    int b = blockIdx.x, tid = threadIdx.x;
    if (tid < 128) img[tid] = b2f(entout[(size_t)h_id[b] * HD + tid]);
    else           img[tid] = b2f(prel[(size_t)r_id[b] * HD + (tid - 128)]);
    for (int i = tid; i < C_CH * 49; i += 256) filt[i] = cw[i];
    __syncthreads();
    for (int idx = tid; idx < FLATD; idx += 256) {
        int o = idx / 100, rem = idx % 100, i = rem / 10, j = rem % 10;
        float acc = cb[o];
        const float* f = &filt[o * 49];
#pragma unroll
        for (int ki = 0; ki < 7; ki++)
#pragma unroll
            for (int kj = 0; kj < 7; kj++)
                acc += img[(i + ki) * 16 + (j + kj)] * f[ki * 7 + kj];
        out[(size_t)b * FLATD + idx] = f2b(fmaxf(acc, 0.f));
    }
}

// ================= split-K reduce for fc =================
__global__ void k_fcreduce(const float* __restrict__ part, const float* __restrict__ bias,
                           ushort* __restrict__ out) {
    int i = blockIdx.x * 256 + threadIdx.x;
    if (i >= BSZ * HD) return;
    float s = 0.f;
    for (int z = 0; z < SPLITK; z++) s += part[(size_t)z * BSZ * HD + i];
    s += bias[i & (HD - 1)];
    out[i] = f2b(fmaxf(s, 0.f));
}

// ================= host launcher =================
extern "C" void kernel_launch(void* const* d_in, const int* in_sizes, int n_in,
                              void* d_out, int out_size, void* d_ws, size_t ws_size,
                              hipStream_t stream) {
    const int* h_id    = (const int*)d_in[0];
    const int* r_id    = (const int*)d_in[1];
    const int* src     = (const int*)d_in[2];
    const int* dst     = (const int*)d_in[3];
    const int* rel_id  = (const int*)d_in[4];
    const float* ent_emb  = (const float*)d_in[5];
    const float* rel_emb0 = (const float*)d_in[6];
    const float* neigh_w  = (const float*)d_in[7];
    const float* S_w = (const float*)d_in[8];
    const float* S_b = (const float*)d_in[9];
    const float* L_w = (const float*)d_in[10];
    const float* L_b = (const float*)d_in[11];
    const float* pred_rel = (const float*)d_in[12];
    const float* phi_w0 = (const float*)d_in[13]; const float* phi_b0 = (const float*)d_in[14];
    const float* phi_w1 = (const float*)d_in[15]; const float* phi_b1 = (const float*)d_in[16];
    const float* phi_w2 = (const float*)d_in[17]; const float* phi_b2 = (const float*)d_in[18];
    const float* psi_w0 = (const float*)d_in[19]; const float* psi_b0 = (const float*)d_in[20];
    const float* psi_w1 = (const float*)d_in[21]; const float* psi_b1 = (const float*)d_in[22];
    const float* psi_w2 = (const float*)d_in[23]; const float* psi_b2 = (const float*)d_in[24];
    const float* conv_w = (const float*)d_in[25]; const float* conv_b = (const float*)d_in[26];
    const float* fc_w   = (const float*)d_in[27]; const float* fc_b   = (const float*)d_in[28];
    const float* score_b= (const float*)d_in[29];

    char* base = (char*)d_ws;
    ushort* ep       = (ushort*)(base + OFF_EP);
    ushort* entout_bf= (ushort*)(base + OFF_ENTOUT);
    ushort* rel_bf   = (ushort*)(base + OFF_RELBF);
    ushort* prel_bf  = (ushort*)(base + OFF_PRELBF);
    ushort* Swt      = (ushort*)(base + OFF_SWT);
    ushort* Lwt      = (ushort*)(base + OFF_LWT);
    ushort* nWt      = (ushort*)(base + OFF_NWT);
    ushort* p0t      = (ushort*)(base + OFF_P0T);
    ushort* q0t      = (ushort*)(base + OFF_Q0T);
    ushort* p1t      = (ushort*)(base + OFF_P1T);
    ushort* q1t      = (ushort*)(base + OFF_Q1T);
    ushort* fct      = (ushort*)(base + OFF_FCT);
    float2* sc       = (float2*)(base + OFF_SC);
    float2* wpair    = (float2*)(base + OFF_W);
    int4*   sidx     = (int4*)(base + OFF_SIDX);
    int*    eorder   = (int*)(base + OFF_EORD);
    int*    deg      = (int*)(base + OFF_DEG);
    int*    startp   = (int*)(base + OFF_START);
    int*    cursor   = (int*)(base + OFF_CUR);
    int*    bsum     = (int*)(base + OFF_BSUM);
    float*  x1       = (float*)(base + OFF_X1);
    float*  x2       = (float*)(base + OFF_X2);
    float*  red      = (float*)(base + OFF_RED);
    ushort* xfc_bf   = (ushort*)(base + OFF_XFC);
    ushort* c1_bf    = (ushort*)(base + OFF_EP);                 // alias (ep dead after agg)
    ushort* c2_bf    = (ushort*)(base + OFF_EP + 12812288);
    ushort* ent_bf   = (ushort*)(base + OFF_ARENA);              // temp: arena before neigh use
    ushort* neigh1_bf= (ushort*)(base + OFF_ARENA);
    ushort* neigh2_bf= (ushort*)(base + OFF_ARENA + 12812288);
    ushort* convout  = (ushort*)(base + OFF_ARENA);
    float*  fcpart   = (float*)(base + OFF_ARENA + 22421504);
    float*  outf     = (float*)d_out;

    // ---- phase 0: conversions & weight transposes (fused) ----
    k_cvt<<<dim3((MPAD * HD + 255) / 256), 256, 0, stream>>>(ent_emb, ent_bf, N_ENTS, MPAD, HD);
    k_cvt2<<<dim3(500, 1, 2), 256, 0, stream>>>(rel_emb0, rel_bf, pred_rel, prel_bf, 1000 * HD);
    k_tcvt7<<<dim3(7, 8, 7), 256, 0, stream>>>(S_w, L_w, neigh_w, phi_w0, psi_w0, phi_w1, psi_w1,
                                               Swt, Lwt, nWt, p0t, q0t, p1t, q1t);
    k_tcvtT<<<dim3(300, 4), 256, 0, stream>>>(fc_w, fct, FLATD, 128, FLATD, 128);

    // ---- phase 1: projections (fused pair) -> interleaved ep table ----
    k_mgemm<2,2,1,1><<<dim3(391, 1, 2), 256, 0, stream>>>(
        ent_bf, HD, Swt, HD, S_b, ep, 256, N_ENTS, HD, HD, HD, 0, 0, HD,
        ent_bf, Lwt, L_b, ep, 2);

    // ---- phase 2: CSR build (no sortseg: tie-break is by true edge id) ----
    hipMemsetAsync(deg, 0, N_ENTS * sizeof(int), stream);
    hipMemsetAsync(cursor, 0, N_ENTS * sizeof(int), stream);
    k_deg<<<dim3((E_EDGES + 255) / 256), 256, 0, stream>>>(dst, deg);
    int nscan = (N_ENTS + 255) / 256;
    k_scan1<<<dim3(nscan), 256, 0, stream>>>(deg, startp, bsum, N_ENTS);
    k_scan2<<<dim3(1), 1024, 0, stream>>>(bsum, nscan);
    k_scan3<<<dim3(nscan), 256, 0, stream>>>(startp, bsum, N_ENTS);
    k_scatter<<<dim3((E_EDGES + 255) / 256), 256, 0, stream>>>(dst, startp, cursor, eorder);
    k_mkidx<<<dim3((E_EDGES + 255) / 256), 256, 0, stream>>>(eorder, src, dst, rel_id, sidx);

    // ---- phase 3-5: edge pipeline ----
    k_scores<<<dim3(E_EDGES / 32), 256, 0, stream>>>(sidx, ep, rel_bf, sc);
    k_softtop<<<dim3((N_ENTS + 15) / 16), 256, 0, stream>>>(startp, deg, sidx, sc, wpair);
    k_agg<<<dim3(N_ENTS), 256, 0, stream>>>(sidx, startp, deg, wpair, ep, rel_bf,
                                            neigh1_bf, neigh2_bf);

    // ---- phase 6: c1/c2 = tanh(neigh @ W) (fused pair, write over dead ep) ----
    k_mgemm<2,2,1,1><<<dim3(391, 1, 2), 256, 0, stream>>>(
        neigh1_bf, HD, nWt, HD, nullptr, c1_bf, HD, N_ENTS, HD, HD, HD, 2, -1, HD,
        neigh2_bf, nWt, nullptr, c2_bf, -1);

    // ---- phase 7: ent_out ----
    k_entout<<<dim3((NPAD_ENT * HD + 255) / 256), 256, 0, stream>>>(ent_emb, c1_bf, c2_bf, entout_bf);

    // ---- phase 8: fused MLPs (both via z) ----
    k_mlp2<<<dim3(MPAD / 64, 1, 2), 256, 0, stream>>>(
        c1_bf, p0t, phi_b0, p1t, phi_b1, phi_w2, phi_b2, x1,
        c2_bf, q0t, psi_b0, q1t, psi_b1, psi_w2, psi_b2, x2);

    // ---- phase 9: corr ----
    k_corr1<<<dim3(1), 1024, 0, stream>>>(x1, x2, red);
    k_corr2<<<dim3(1), 1024, 0, stream>>>(x1, x2, red, outf + OUT_SCORE);

    // ---- phase 10-11: ConvE ----
    k_conv<<<dim3(BSZ), 256, 0, stream>>>(h_id, r_id, entout_bf, prel_bf, conv_w, conv_b, convout);
    k_mgemm<2,2,0,0><<<dim3(8, 1, SPLITK), 256, 0, stream>>>(
        convout, FLATD, fct, FLATD, nullptr, fcpart, HD, BSZ, HD, FLATD, FLATD / SPLITK, 0, -1, HD,
        nullptr, nullptr, nullptr, nullptr, 0);
    k_fcreduce<<<dim3((BSZ * HD + 255) / 256), 256, 0, stream>>>(fcpart, fc_b, xfc_bf);

    // ---- phase 12: score GEMM (XCD-swizzled) ----
    k_score<<<dim3(16, 196), 256, 0, stream>>>(xfc_bf, entout_bf, score_b, outf, N_ENTS);
}

// Round 8
// 649.745 us; speedup vs baseline: 2.8841x; 1.0765x over previous
//
#include <hip/hip_runtime.h>
#include <math.h>

typedef unsigned short ushort;
typedef unsigned int   uint;
typedef short bf16x8 __attribute__((ext_vector_type(8)));
typedef float f32x4  __attribute__((ext_vector_type(4)));
typedef ushort u16x8 __attribute__((ext_vector_type(8)));
typedef ushort u16x4 __attribute__((ext_vector_type(4)));

// ---------------- problem constants ----------------
#define N_ENTS   50000
#define E_EDGES  800000
#define HD       128
#define BSZ      1024
#define C_CH     96
#define FLATD    9600
#define TOPK_K   15
#define HIDD     200
#define SPLITK   10
#define OUT_SCORE ((size_t)BSZ * N_ENTS)

#define MPAD     50048            // 391*128
#define NPAD_ENT 50176            // 196*256
#define KPAD200  224
#define NPAD200  256
#define L2E      1.4426950408889634f

// ---------------- workspace layout (byte offsets) ----------------
#define OFF_EP       ((size_t)0)            // ushort [50048][256] interleaved c/p (c1/c2 alias later)
#define OFF_ENTOUT   ((size_t)25624576)     // ushort [50176][128]
#define OFF_RELBF    ((size_t)38469632)     // ushort [1000][128]
#define OFF_PRELBF   ((size_t)38725632)
#define OFF_SWT      ((size_t)38981632)     // ushort [128][128]
#define OFF_LWT      ((size_t)39014400)
#define OFF_NWT      ((size_t)39047168)
#define OFF_P0T      ((size_t)39079936)     // ushort [256][128]
#define OFF_Q0T      ((size_t)39145472)
#define OFF_P1T      ((size_t)39211008)     // ushort [256][224]
#define OFF_Q1T      ((size_t)39325696)
#define OFF_FCT      ((size_t)39440384)     // ushort [128][9600]
#define OFF_SC       ((size_t)41897984)     // float2 [800000]
#define OFF_W        ((size_t)48297984)     // float2 [800000]
#define OFF_SIDX     ((size_t)54697984)     // int4 [800000]
#define OFF_DEG      ((size_t)70697984)     // int [50000]
#define OFF_START    ((size_t)70897984)
#define OFF_CUR      ((size_t)71097984)
#define OFF_BSUM     ((size_t)71297984)     // int [1024]
#define OFF_X1       ((size_t)71302080)     // float [50000]
#define OFF_X2       ((size_t)71502080)
#define OFF_RED      ((size_t)71702080)     // float [64]
#define OFF_XFC      ((size_t)71702336)     // ushort [1024][128]
#define OFF_ARENA    ((size_t)71964480)
// arena: ent_bf=+0 (u16[50048][128]) [dead after proj]
//        neigh1=+0, neigh2=+12812288 [dead after k_tanh2ent]
//        convout=+0 (u16[1024][9600]), fcpart=+22421504 (f32[10][1024][128])
// c1 = EP+0 (u16[50048][128]), c2 = EP+12812288  (EP dead after k_agg)

// ---------------- helpers ----------------
__device__ inline ushort f2b(float f) {
    uint u = __float_as_uint(f);
    return (ushort)((u + 0x7fffu + ((u >> 16) & 1u)) >> 16);  // RNE
}
__device__ inline float b2f(ushort u) { return __uint_as_float((uint)u << 16); }
__device__ inline float fexp2(float x) { return __builtin_amdgcn_exp2f(x); }
__device__ inline float frcp(float x)  { return __builtin_amdgcn_rcpf(x); }
__device__ inline float fsigmoid(float x) { return frcp(1.f + fexp2(-x * L2E)); }
__device__ inline float ftanh(float x) {
    float ax = fabsf(x);
    float t = fexp2(ax * (-2.f * L2E));
    float r = (1.f - t) * frcp(1.f + t);
    return copysignf(r, x);
}

// ---------------- conversion kernels ----------------
__global__ void k_cvt(const float* __restrict__ in, ushort* __restrict__ out,
                      int M, int Mpad, int K) {
    int i = blockIdx.x * 256 + threadIdx.x;
    if (i >= Mpad * K) return;
    int r = i / K;
    out[i] = (r < M) ? f2b(in[i]) : (ushort)0;
}

__global__ void k_cvt2(const float* __restrict__ in0, ushort* __restrict__ out0,
                       const float* __restrict__ in1, ushort* __restrict__ out1, int n) {
    const float* in = blockIdx.z ? in1 : in0;
    ushort* out = blockIdx.z ? out1 : out0;
    int i = blockIdx.x * 256 + threadIdx.x;
    if (i < n) out[i] = f2b(in[i]);
}

__global__ __launch_bounds__(256) void k_tcvtT(const float* __restrict__ in, ushort* __restrict__ out,
                                               int K, int N, int Kpad, int Npad) {
    __shared__ float t[32][33];
    int k0 = blockIdx.x * 32, n0 = blockIdx.y * 32;
    int tx = threadIdx.x & 31, ty = threadIdx.x >> 5;
    for (int i = ty; i < 32; i += 8) {
        int k = k0 + i, n = n0 + tx;
        t[i][tx] = (k < K && n < N) ? in[(size_t)k * N + n] : 0.f;
    }
    __syncthreads();
    for (int i = ty; i < 32; i += 8) {
        int n = n0 + i, k = k0 + tx;
        if (n < Npad && k < Kpad) out[(size_t)n * Kpad + k] = f2b(t[tx][i]);
    }
}

__global__ __launch_bounds__(256) void k_tcvt7(
    const float* __restrict__ S_w, const float* __restrict__ L_w, const float* __restrict__ n_w,
    const float* __restrict__ p0, const float* __restrict__ q0,
    const float* __restrict__ p1, const float* __restrict__ q1,
    ushort* __restrict__ Swt, ushort* __restrict__ Lwt, ushort* __restrict__ nWt,
    ushort* __restrict__ p0t, ushort* __restrict__ q0t,
    ushort* __restrict__ p1t, ushort* __restrict__ q1t) {
    const float* in; ushort* out; int K, N, Kp, Np;
    switch (blockIdx.z) {
        case 0: in = S_w; out = Swt; K = 128; N = 128; Kp = 128; Np = 128; break;
        case 1: in = L_w; out = Lwt; K = 128; N = 128; Kp = 128; Np = 128; break;
        case 2: in = n_w; out = nWt; K = 128; N = 128; Kp = 128; Np = 128; break;
        case 3: in = p0;  out = p0t; K = 128; N = HIDD; Kp = 128; Np = NPAD200; break;
        case 4: in = q0;  out = q0t; K = 128; N = HIDD; Kp = 128; Np = NPAD200; break;
        case 5: in = p1;  out = p1t; K = HIDD; N = HIDD; Kp = KPAD200; Np = NPAD200; break;
        default: in = q1; out = q1t; K = HIDD; N = HIDD; Kp = KPAD200; Np = NPAD200; break;
    }
    __shared__ float t[32][33];
    int k0 = blockIdx.x * 32, n0 = blockIdx.y * 32;
    if (k0 >= Kp || n0 >= Np) return;
    int tx = threadIdx.x & 31, ty = threadIdx.x >> 5;
    for (int i = ty; i < 32; i += 8) {
        int k = k0 + i, n = n0 + tx;
        t[i][tx] = (k < K && n < N) ? in[(size_t)k * N + n] : 0.f;
    }
    __syncthreads();
    for (int i = ty; i < 32; i += 8) {
        int n = n0 + i, k = k0 + tx;
        if (n < Np && k < Kp) out[(size_t)n * Kp + k] = f2b(t[tx][i]);
    }
}

// ================= MFMA bf16 GEMM (generic: projections & fc) =================
template <int WM, int WN, int OUTBF, int FUSE2>
__global__ __launch_bounds__(256) void k_mgemm(
    const ushort* __restrict__ A, int lda,
    const ushort* __restrict__ Bt, int ldb,
    const float* __restrict__ bias, void* __restrict__ Cout, int ldc,
    int M, int N, int K, int kChunk, int epi, int iofs, int npad,
    const ushort* __restrict__ A2, const ushort* __restrict__ Bt2,
    const float* __restrict__ bias2, void* __restrict__ Cout2, int iofs2) {
    if (FUSE2 && blockIdx.z == 1) { A = A2; Bt = Bt2; bias = bias2; Cout = Cout2; iofs = iofs2; }
    const int w = threadIdx.x >> 6, lane = threadIdx.x & 63;
    const int wr = w / WN, wc = w % WN;
    const int row0 = blockIdx.x * (WM * 64) + wr * 64;
    const int col0 = blockIdx.y * (WN * 64) + wc * 64;
    const int lr = lane & 15;
    const int kg = (lane >> 4) * 8;
    const int kb = FUSE2 ? 0 : blockIdx.z * kChunk;
    const int ke = kb + kChunk;

    f32x4 acc[4][4];
#pragma unroll
    for (int i = 0; i < 4; i++)
#pragma unroll
        for (int j = 0; j < 4; j++) acc[i][j] = (f32x4){0.f, 0.f, 0.f, 0.f};

    for (int kk = kb; kk < ke; kk += 32) {
        bf16x8 af[4], bfr[4];
#pragma unroll
        for (int i = 0; i < 4; i++) {
            int r = row0 + i * 16 + lr;
            r = min(r, M - 1);
            af[i] = *(const bf16x8*)(A + (size_t)r * lda + kk + kg);
        }
#pragma unroll
        for (int j = 0; j < 4; j++) {
            int c = col0 + j * 16 + lr;
            bfr[j] = *(const bf16x8*)(Bt + (size_t)c * ldb + kk + kg);
        }
#pragma unroll
        for (int i = 0; i < 4; i++)
#pragma unroll
            for (int j = 0; j < 4; j++)
                acc[i][j] = __builtin_amdgcn_mfma_f32_16x16x32_bf16(af[i], bfr[j], acc[i][j], 0, 0, 0);
    }

    const int cr = (lane >> 4) * 4, cc = lane & 15;
    if (!FUSE2 && gridDim.z > 1) {
        float* P = (float*)Cout + (size_t)blockIdx.z * M * ldc;
#pragma unroll
        for (int i = 0; i < 4; i++)
#pragma unroll
            for (int j = 0; j < 4; j++) {
                int col = col0 + j * 16 + cc;
                if (col >= N) continue;
#pragma unroll
                for (int t = 0; t < 4; t++) {
                    int row = row0 + i * 16 + cr + t;
                    if (row < M) P[(size_t)row * ldc + col] = acc[i][j][t];
                }
            }
    } else {
#pragma unroll
        for (int i = 0; i < 4; i++)
#pragma unroll
            for (int j = 0; j < 4; j++) {
                int col = col0 + j * 16 + cc;
                if (col >= (OUTBF ? npad : N)) continue;
                bool valid = col < N;
                float bi = (bias && valid) ? bias[col] : 0.f;
#pragma unroll
                for (int t = 0; t < 4; t++) {
                    int row = row0 + i * 16 + cr + t;
                    if (row >= M) continue;
                    float v = acc[i][j][t] + bi;
                    if (epi == 1) v = fmaxf(v, 0.f);
                    else if (epi == 2) v = ftanh(v);
                    else if (epi == 3) v = fsigmoid(v);
                    if (!valid) v = 0.f;
                    if (OUTBF) {
                        size_t idx = (iofs < 0) ? ((size_t)row * ldc + col)
                                   : ((size_t)row * ldc + ((size_t)(col >> 1) << 2) + (col & 1) + iofs);
                        ((ushort*)Cout)[idx] = f2b(v);
                    } else {
                        ((float*)Cout)[(size_t)row * ldc + col] = v;
                    }
                }
            }
    }
}

// ==== fused pair: c1=tanh(neigh1@W), c2=tanh(neigh2@W), entout=ent+c1+c2 ====
__global__ __launch_bounds__(256) void k_tanh2ent(
    const ushort* __restrict__ neigh1, const ushort* __restrict__ neigh2,
    const ushort* __restrict__ nWt, const float* __restrict__ ent,
    ushort* __restrict__ c1o, ushort* __restrict__ c2o, ushort* __restrict__ eo) {
    const int w = threadIdx.x >> 6, lane = threadIdx.x & 63;
    const int wr = w >> 1, wc = w & 1;
    const int row0 = blockIdx.x * 128 + wr * 64;
    const int col0 = wc * 64;
    const int lr = lane & 15, kg = (lane >> 4) * 8;

    f32x4 a1[4][4], a2[4][4];
#pragma unroll
    for (int i = 0; i < 4; i++)
#pragma unroll
        for (int j = 0; j < 4; j++) { a1[i][j] = (f32x4){0,0,0,0}; a2[i][j] = (f32x4){0,0,0,0}; }

    for (int kk = 0; kk < HD; kk += 32) {
        bf16x8 f1[4], f2v[4], bfr[4];
#pragma unroll
        for (int i = 0; i < 4; i++) {
            int r = min(row0 + i * 16 + lr, N_ENTS - 1);
            f1[i]  = *(const bf16x8*)(neigh1 + (size_t)r * HD + kk + kg);
            f2v[i] = *(const bf16x8*)(neigh2 + (size_t)r * HD + kk + kg);
        }
#pragma unroll
        for (int j = 0; j < 4; j++)
            bfr[j] = *(const bf16x8*)(nWt + (size_t)(col0 + j * 16 + lr) * HD + kk + kg);
#pragma unroll
        for (int i = 0; i < 4; i++)
#pragma unroll
            for (int j = 0; j < 4; j++) {
                a1[i][j] = __builtin_amdgcn_mfma_f32_16x16x32_bf16(f1[i],  bfr[j], a1[i][j], 0, 0, 0);
                a2[i][j] = __builtin_amdgcn_mfma_f32_16x16x32_bf16(f2v[i], bfr[j], a2[i][j], 0, 0, 0);
            }
    }

    const int cr = (lane >> 4) * 4, cc = lane & 15;
#pragma unroll
    for (int i = 0; i < 4; i++)
#pragma unroll
        for (int j = 0; j < 4; j++) {
            int col = col0 + j * 16 + cc;
#pragma unroll
            for (int t = 0; t < 4; t++) {
                int row = row0 + i * 16 + cr + t;
                if (row >= N_ENTS) continue;
                float t1 = ftanh(a1[i][j][t]);
                float t2 = ftanh(a2[i][j][t]);
                size_t idx = (size_t)row * HD + col;
                c1o[idx] = f2b(t1);
                c2o[idx] = f2b(t2);
                eo[idx] = f2b(ent[idx] + t1 + t2);
            }
        }
}

// ================= score GEMM: XCD-swizzled, LDS-staged NT f32x4 stores ======
__global__ __launch_bounds__(256) void k_score(
    const ushort* __restrict__ A, const ushort* __restrict__ Bt,
    const float* __restrict__ bias, float* __restrict__ C, int N) {
    __shared__ __align__(16) float st[4][16][68];
    const int w = threadIdx.x >> 6, lane = threadIdx.x & 63;
    const int lr = lane & 15, kg = (lane >> 4) * 8;
    const int cr = (lane >> 4) * 4, cc = lane & 15;
    int flat = blockIdx.y * 16 + blockIdx.x;
    int swz = (flat & 7) * 392 + (flat >> 3);         // 3136 = 8 * 392
    const int row0 = (swz & 15) * 64;
    const int colw = (swz >> 4) * 256 + w * 64;

    f32x4 acc[4][4];
#pragma unroll
    for (int i = 0; i < 4; i++)
#pragma unroll
        for (int j = 0; j < 4; j++) acc[i][j] = (f32x4){0.f, 0.f, 0.f, 0.f};

    for (int kk = 0; kk < HD; kk += 32) {
        bf16x8 af[4], bfr[4];
#pragma unroll
        for (int i = 0; i < 4; i++)
            af[i] = *(const bf16x8*)(A + (size_t)(row0 + i * 16 + lr) * HD + kk + kg);
#pragma unroll
        for (int j = 0; j < 4; j++)
            bfr[j] = *(const bf16x8*)(Bt + (size_t)(colw + j * 16 + lr) * HD + kk + kg);
#pragma unroll
        for (int i = 0; i < 4; i++)
#pragma unroll
            for (int j = 0; j < 4; j++)
                acc[i][j] = __builtin_amdgcn_mfma_f32_16x16x32_bf16(af[i], bfr[j], acc[i][j], 0, 0, 0);
    }

#pragma unroll
    for (int i = 0; i < 4; i++) {
#pragma unroll
        for (int j = 0; j < 4; j++) {
            int col = colw + j * 16 + cc;
            float bi = (col < N) ? bias[col] : 0.f;
#pragma unroll
            for (int t = 0; t < 4; t++)
                st[w][cr + t][j * 16 + cc] = fsigmoid(acc[i][j][t] + bi);
        }
#pragma unroll
        for (int p = 0; p < 4; p++) {
            int r = p * 4 + (lane >> 4);
            int cq = (lane & 15) * 4;
            f32x4 v = *(const f32x4*)&st[w][r][cq];
            int gc = colw + cq;
            if (gc < N)
                __builtin_nontemporal_store(v, (f32x4*)&C[(size_t)(row0 + i * 16 + r) * N + gc]);
        }
    }
}

// ================= fused 3-layer MLP (both MLPs via z switch) =================
__global__ __launch_bounds__(256) void k_mlp2(
    const ushort* __restrict__ A0, const ushort* __restrict__ W0t0,
    const float* __restrict__ b00, const ushort* __restrict__ W1t0,
    const float* __restrict__ b10, const float* __restrict__ w20,
    const float* __restrict__ b20, float* __restrict__ xo0,
    const ushort* __restrict__ A1, const ushort* __restrict__ W0t1,
    const float* __restrict__ b01, const ushort* __restrict__ W1t1,
    const float* __restrict__ b11, const float* __restrict__ w21,
    const float* __restrict__ b21, float* __restrict__ xo1) {
    const ushort* A   = blockIdx.z ? A1 : A0;
    const ushort* W0t = blockIdx.z ? W0t1 : W0t0;
    const float*  b0  = blockIdx.z ? b01 : b00;
    const ushort* W1t = blockIdx.z ? W1t1 : W1t0;
    const float*  b1  = blockIdx.z ? b11 : b10;
    const float*  w2  = blockIdx.z ? w21 : w20;
    const float*  b2  = blockIdx.z ? b21 : b20;
    float*        x   = blockIdx.z ? xo1 : xo0;

    __shared__ __align__(16) char lbuf[64 * 232 * 2];
    __shared__ float w2e[256], b1e[256], b0e[256];
    const int tid = threadIdx.x;
    const int w = tid >> 6, lane = tid & 63;
    const int lr = lane & 15, kg = (lane >> 4) * 8;
    const int cr = (lane >> 4) * 4, cc = lane & 15;
    const int row0 = blockIdx.x * 64;
    {
        int c = tid;
        w2e[c] = (c < HIDD) ? w2[c] : 0.f;
        b1e[c] = (c < HIDD) ? b1[c] : 0.f;
        b0e[c] = (c < HIDD) ? b0[c] : 0.f;
    }
    __syncthreads();
    ushort* g1 = (ushort*)lbuf;

    f32x4 acc[4][4];
#pragma unroll
    for (int i = 0; i < 4; i++)
#pragma unroll
        for (int j = 0; j < 4; j++) acc[i][j] = (f32x4){0.f, 0.f, 0.f, 0.f};
    for (int kk = 0; kk < 128; kk += 32) {
        bf16x8 af[4], bfr[4];
#pragma unroll
        for (int i = 0; i < 4; i++)
            af[i] = *(const bf16x8*)(A + (size_t)(row0 + i * 16 + lr) * HD + kk + kg);
#pragma unroll
        for (int j = 0; j < 4; j++)
            bfr[j] = *(const bf16x8*)(W0t + (size_t)(w * 64 + j * 16 + lr) * 128 + kk + kg);
#pragma unroll
        for (int i = 0; i < 4; i++)
#pragma unroll
            for (int j = 0; j < 4; j++)
                acc[i][j] = __builtin_amdgcn_mfma_f32_16x16x32_bf16(af[i], bfr[j], acc[i][j], 0, 0, 0);
    }
#pragma unroll
    for (int i = 0; i < 4; i++)
#pragma unroll
        for (int j = 0; j < 4; j++) {
            int col = w * 64 + j * 16 + cc;
            if (col < KPAD200) {
                float bi = b0e[col];
#pragma unroll
                for (int t = 0; t < 4; t++)
                    g1[(i * 16 + cr + t) * 232 + col] = f2b(fmaxf(acc[i][j][t] + bi, 0.f));
            }
        }
    __syncthreads();

    f32x4 a2[4][4];
#pragma unroll
    for (int i = 0; i < 4; i++)
#pragma unroll
        for (int j = 0; j < 4; j++) a2[i][j] = (f32x4){0.f, 0.f, 0.f, 0.f};
    for (int ks = 0; ks < 7; ks++) {
        int kk = ks * 32;
        bf16x8 af[4], bfr[4];
#pragma unroll
        for (int i = 0; i < 4; i++)
            af[i] = *(const bf16x8*)(g1 + (i * 16 + lr) * 232 + kk + kg);
#pragma unroll
        for (int j = 0; j < 4; j++)
            bfr[j] = *(const bf16x8*)(W1t + (size_t)(w * 64 + j * 16 + lr) * KPAD200 + kk + kg);
#pragma unroll
        for (int i = 0; i < 4; i++)
#pragma unroll
            for (int j = 0; j < 4; j++)
                a2[i][j] = __builtin_amdgcn_mfma_f32_16x16x32_bf16(af[i], bfr[j], a2[i][j], 0, 0, 0);
    }
    __syncthreads();

    float* pbuf = (float*)lbuf;   // [64][65]
#pragma unroll
    for (int i = 0; i < 4; i++)
#pragma unroll
        for (int t = 0; t < 4; t++) {
            float s = 0.f;
#pragma unroll
            for (int j = 0; j < 4; j++) {
                int col = w * 64 + j * 16 + cc;
                s += fmaxf(a2[i][j][t] + b1e[col], 0.f) * w2e[col];
            }
            pbuf[(i * 16 + cr + t) * 65 + w * 16 + cc] = s;
        }
    __syncthreads();
    if (tid < 64) {
        float s = b2[0];
        for (int q = 0; q < 64; q++) s += pbuf[tid * 65 + q];
        int gr = row0 + tid;
        if (gr < N_ENTS) x[gr] = s;
    }
}

// ================= CSR build =================
__global__ void k_deg(const int* __restrict__ dst, int* __restrict__ deg) {
    int e = blockIdx.x * 256 + threadIdx.x;
    if (e < E_EDGES) atomicAdd(&deg[dst[e]], 1);
}

__global__ void k_scan1(const int* __restrict__ in, int* __restrict__ out,
                        int* __restrict__ bsum, int n) {
    __shared__ int sh[256];
    int i = blockIdx.x * 256 + threadIdx.x;
    int v = (i < n) ? in[i] : 0;
    sh[threadIdx.x] = v; __syncthreads();
    for (int off = 1; off < 256; off <<= 1) {
        int t = (threadIdx.x >= off) ? sh[threadIdx.x - off] : 0;
        __syncthreads();
        sh[threadIdx.x] += t;
        __syncthreads();
    }
    if (i < n) out[i] = sh[threadIdx.x] - v;
    if (threadIdx.x == 255) bsum[blockIdx.x] = sh[255];
}

__global__ void k_scan2(int* __restrict__ bsum, int nb) {
    __shared__ int sh[1024];
    int t = threadIdx.x;
    int v = (t < nb) ? bsum[t] : 0;
    sh[t] = v; __syncthreads();
    for (int off = 1; off < 1024; off <<= 1) {
        int u = (t >= off) ? sh[t - off] : 0;
        __syncthreads();
        sh[t] += u;
        __syncthreads();
    }
    if (t < nb) bsum[t] = sh[t] - v;
}

__global__ void k_scan3(int* __restrict__ out, const int* __restrict__ bsum, int n) {
    int i = blockIdx.x * 256 + threadIdx.x;
    if (i < n) out[i] += bsum[blockIdx.x];
}

// fused scatter: writes sidx directly (no eorder / mkidx pass)
__global__ void k_scatter2(const int* __restrict__ src, const int* __restrict__ dst,
                           const int* __restrict__ rel_id, const int* __restrict__ start,
                           int* __restrict__ cursor, int4* __restrict__ sidx) {
    int e = blockIdx.x * 256 + threadIdx.x;
    if (e < E_EDGES) {
        int n = dst[e];
        int p = start[n] + atomicAdd(&cursor[n], 1);
        sidx[p] = make_int4(src[e], n, rel_id[e], e);
    }
}

// ====== edge scores: 8 lanes/edge, granule-major => 128B-contiguous loads ======
__global__ __launch_bounds__(256) void k_scores(
    const int4* __restrict__ sidx, const ushort* __restrict__ ep,
    const ushort* __restrict__ rel, float2* __restrict__ sc) {
    int gg = threadIdx.x >> 3, l = threadIdx.x & 7;
    int slot = blockIdx.x * 32 + gg;
    int4 si = sidx[slot];
    const ushort* rs = ep + (size_t)si.x * 256;
    const ushort* rd = ep + (size_t)si.y * 256;
    const ushort* rr = rel + (size_t)si.z * 128;
    u16x8 sv[4], dv[4];
    uint2 rv[4];
#pragma unroll
    for (int i = 0; i < 4; i++) {
        int t = i * 8 + l;                       // granule 0..31
        sv[i] = *(const u16x8*)(rs + t * 8);     // lanes contiguous: 128B/edge/instr
        dv[i] = *(const u16x8*)(rd + t * 8);
        rv[i] = *(const uint2*)(rr + t * 4);
    }
    float a = 0.f, b = 0.f;
#pragma unroll
    for (int i = 0; i < 4; i++) {
        float r0 = b2f((ushort)(rv[i].x & 0xffffu)), r1 = b2f((ushort)(rv[i].x >> 16));
        float r2 = b2f((ushort)(rv[i].y & 0xffffu)), r3 = b2f((ushort)(rv[i].y >> 16));
        a += b2f(sv[i][0]) * r0 * b2f(dv[i][0]) + b2f(sv[i][1]) * r1 * b2f(dv[i][1])
           + b2f(sv[i][4]) * r2 * b2f(dv[i][4]) + b2f(sv[i][5]) * r3 * b2f(dv[i][5]);
        b += b2f(sv[i][2]) * r0 * b2f(dv[i][2]) + b2f(sv[i][3]) * r1 * b2f(dv[i][3])
           + b2f(sv[i][6]) * r2 * b2f(dv[i][6]) + b2f(sv[i][7]) * r3 * b2f(dv[i][7]);
    }
#pragma unroll
    for (int m = 4; m; m >>= 1) { a += __shfl_xor(a, m, 8); b += __shfl_xor(b, m, 8); }
    if (l == 0) sc[slot] = make_float2(a, b);
}

// ===== softmax + top-15: 16 lanes/node; d<=15 fast path; tie-break by edge id =====
__global__ __launch_bounds__(256) void k_softtop(
    const int* __restrict__ start, const int* __restrict__ deg,
    const int4* __restrict__ sidx, const float2* __restrict__ sc, float2* __restrict__ w) {
    int n = blockIdx.x * 16 + (threadIdx.x >> 4);
    int l = threadIdx.x & 15;
    if (n >= N_ENTS) return;
    int b = start[n], d = deg[n];
    if (d == 0) return;
    float m1 = -INFINITY, m2 = -INFINITY;
    for (int i = l; i < d; i += 16) {
        float2 s = sc[b + i];
        m1 = fmaxf(m1, s.x); m2 = fmaxf(m2, s.y);
    }
#pragma unroll
    for (int o = 8; o; o >>= 1) { m1 = fmaxf(m1, __shfl_xor(m1, o, 16)); m2 = fmaxf(m2, __shfl_xor(m2, o, 16)); }
    float z1 = 0.f, z2 = 0.f;
    for (int i = l; i < d; i += 16) {
        float2 s = sc[b + i];
        z1 += fexp2((s.x - m1) * L2E); z2 += fexp2((s.y - m2) * L2E);
    }
#pragma unroll
    for (int o = 8; o; o >>= 1) { z1 += __shfl_xor(z1, o, 16); z2 += __shfl_xor(z2, o, 16); }
    float iz1 = frcp(z1), iz2 = frcp(z2);
    if (d <= TOPK_K) {                 // no pruning possible: all edges kept
        for (int i = l; i < d; i += 16) {
            float2 sp = sc[b + i];
            w[b + i] = make_float2(fexp2((sp.x - m1) * L2E) * iz1,
                                   fexp2((sp.y - m2) * L2E) * iz2);
        }
        return;
    }
    for (int i = l; i < d; i += 16) {
        float2 sp = sc[b + i];
        int ei = sidx[b + i].w;
        int r1 = 0, r2 = 0;
        for (int j = 0; j < d; j++) {
            float2 sq = sc[b + j];
            int ej = sidx[b + j].w;
            r1 += (sq.x > sp.x) || (sq.x == sp.x && ej < ei);
            r2 += (sq.y > sp.y) || (sq.y == sp.y && ej < ei);
        }
        w[b + i] = make_float2(r1 < TOPK_K ? fexp2((sp.x - m1) * L2E) * iz1 : 0.f,
                               r2 < TOPK_K ? fexp2((sp.y - m2) * L2E) * iz2 : 0.f);
    }
}

// ====== weighted aggregation: block-per-node, 4 waves, 4 gather chains/wave ======
__global__ __launch_bounds__(256) void k_agg(
    const int4* __restrict__ sidx, const int* __restrict__ start, const int* __restrict__ deg,
    const float2* __restrict__ w, const ushort* __restrict__ ep, const ushort* __restrict__ rel,
    ushort* __restrict__ neigh1, ushort* __restrict__ neigh2) {
    __shared__ float4 part[3][64];
    int n = blockIdx.x;
    int wid = threadIdx.x >> 6, g = threadIdx.x & 63;
    int b = start[n], end = b + deg[n];
    float2 p1a = {0.f, 0.f}, p2a = {0.f, 0.f}, p1b = {0.f, 0.f}, p2b = {0.f, 0.f};
    for (int s = b + wid; s < end; s += 16) {
        int sB = s + 4, sC = s + 8, sD = s + 12;
        bool hB = sB < end, hC = sC < end, hD = sD < end;
        int4 siA = sidx[s];
        int4 siB = hB ? sidx[sB] : siA;
        int4 siC = hC ? sidx[sC] : siA;
        int4 siD = hD ? sidx[sD] : siA;
        float2 wA = w[s];
        float2 wB = hB ? w[sB] : make_float2(0.f, 0.f);
        float2 wC = hC ? w[sC] : make_float2(0.f, 0.f);
        float2 wD = hD ? w[sD] : make_float2(0.f, 0.f);
        u16x4 vA = *(const u16x4*)(ep + (size_t)siA.x * 256 + g * 4);
        u16x4 vB = *(const u16x4*)(ep + (size_t)siB.x * 256 + g * 4);
        u16x4 vC = *(const u16x4*)(ep + (size_t)siC.x * 256 + g * 4);
        u16x4 vD = *(const u16x4*)(ep + (size_t)siD.x * 256 + g * 4);
        uint rA = *(const uint*)(rel + (size_t)siA.z * 128 + g * 2);
        uint rB = *(const uint*)(rel + (size_t)siB.z * 128 + g * 2);
        uint rC = *(const uint*)(rel + (size_t)siC.z * 128 + g * 2);
        uint rD = *(const uint*)(rel + (size_t)siD.z * 128 + g * 2);
        float rx, ry;
        rx = b2f((ushort)(rA & 0xffffu)); ry = b2f((ushort)(rA >> 16));
        p1a.x += wA.x * b2f(vA[0]) * rx;  p1a.y += wA.x * b2f(vA[1]) * ry;
        p2a.x += wA.y * b2f(vA[2]) * rx;  p2a.y += wA.y * b2f(vA[3]) * ry;
        rx = b2f((ushort)(rB & 0xffffu)); ry = b2f((ushort)(rB >> 16));
        p1b.x += wB.x * b2f(vB[0]) * rx;  p1b.y += wB.x * b2f(vB[1]) * ry;
        p2b.x += wB.y * b2f(vB[2]) * rx;  p2b.y += wB.y * b2f(vB[3]) * ry;
        rx = b2f((ushort)(rC & 0xffffu)); ry = b2f((ushort)(rC >> 16));
        p1a.x += wC.x * b2f(vC[0]) * rx;  p1a.y += wC.x * b2f(vC[1]) * ry;
        p2a.x += wC.y * b2f(vC[2]) * rx;  p2a.y += wC.y * b2f(vC[3]) * ry;
        rx = b2f((ushort)(rD & 0xffffu)); ry = b2f((ushort)(rD >> 16));
        p1b.x += wD.x * b2f(vD[0]) * rx;  p1b.y += wD.x * b2f(vD[1]) * ry;
        p2b.x += wD.y * b2f(vD[2]) * rx;  p2b.y += wD.y * b2f(vD[3]) * ry;
    }
    float2 a1 = make_float2(p1a.x + p1b.x, p1a.y + p1b.y);
    float2 a2 = make_float2(p2a.x + p2b.x, p2a.y + p2b.y);
    if (wid > 0) part[wid - 1][g] = make_float4(a1.x, a1.y, a2.x, a2.y);
    __syncthreads();
    if (wid == 0) {
#pragma unroll
        for (int k = 0; k < 3; k++) {
            float4 p = part[k][g];
            a1.x += p.x; a1.y += p.y; a2.x += p.z; a2.y += p.w;
        }
        uint o1 = (uint)f2b(a1.x) | ((uint)f2b(a1.y) << 16);
        uint o2 = (uint)f2b(a2.x) | ((uint)f2b(a2.y) << 16);
        ((uint*)(neigh1 + (size_t)n * HD))[g] = o1;
        ((uint*)(neigh2 + (size_t)n * HD))[g] = o2;
    }
}

// ================= corr (merged, one block) =================
__global__ void k_corr(const float* __restrict__ x1, const float* __restrict__ x2,
                       float* __restrict__ out) {
    __shared__ float sa[1024], sb[1024], sc_[1024];
    int t = threadIdx.x;
    float s1 = 0.f, s2 = 0.f;
    for (int i = t; i < N_ENTS; i += 1024) { s1 += x1[i]; s2 += x2[i]; }
    sa[t] = s1; sb[t] = s2; __syncthreads();
    for (int o = 512; o > 0; o >>= 1) {
        if (t < o) { sa[t] += sa[t + o]; sb[t] += sb[t + o]; }
        __syncthreads();
    }
    float m1 = sa[0] / (float)N_ENTS, m2 = sb[0] / (float)N_ENTS;
    __syncthreads();
    float a11 = 0.f, a22 = 0.f, a12 = 0.f;
    for (int i = t; i < N_ENTS; i += 1024) {
        float a = x1[i] - m1, b = x2[i] - m2;
        a11 += a * a; a22 += b * b; a12 += a * b;
    }
    sa[t] = a11; sb[t] = a22; sc_[t] = a12; __syncthreads();
    for (int o = 512; o > 0; o >>= 1) {
        if (t < o) { sa[t] += sa[t + o]; sb[t] += sb[t + o]; sc_[t] += sc_[t + o]; }
        __syncthreads();
    }
    if (t == 0) {
        float v11 = sa[0] / (float)N_ENTS, v22 = sb[0] / (float)N_ENTS, v12 = sc_[0] / (float)N_ENTS;
        out[0] = fabsf(v12) / (sqrtf(v11) * sqrtf(v22));
    }
}

// ================= ConvE conv =================
__global__ void k_conv(const int* __restrict__ h_id, const int* __restrict__ r_id,
                       const ushort* __restrict__ entout, const ushort* __restrict__ prel,
                       const float* __restrict__ cw, const float* __restrict__ cb,
                       ushort* __restrict__ out) {
    __shared__ float img[256];
    __shared__ float filt[C_CH * 49];
    int b = blockIdx.x, tid = threadIdx.x;
    if (tid < 128) img[tid] = b2f(entout[(size_t)h_id[b] * HD + tid]);
    else           img[tid] = b2f(prel[(size_t)r_id[b] * HD + (tid - 128)]);
    for (int i = tid; i < C_CH * 49; i += 256) filt[i] = cw[i];
    __syncthreads();
    for (int idx = tid; idx < FLATD; idx += 256) {
        int o = idx / 100, rem = idx % 100, i = rem / 10, j = rem % 10;
        float acc = cb[o];
        const float* f = &filt[o * 49];
#pragma unroll
        for (int ki = 0; ki < 7; ki++)
#pragma unroll
            for (int kj = 0; kj < 7; kj++)
                acc += img[(i + ki) * 16 + (j + kj)] * f[ki * 7 + kj];
        out[(size_t)b * FLATD + idx] = f2b(fmaxf(acc, 0.f));
    }
}

// ================= split-K reduce for fc =================
__global__ void k_fcreduce(const float* __restrict__ part, const float* __restrict__ bias,
                           ushort* __restrict__ out) {
    int i = blockIdx.x * 256 + threadIdx.x;
    if (i >= BSZ * HD) return;
    float s = 0.f;
    for (int z = 0; z < SPLITK; z++) s += part[(size_t)z * BSZ * HD + i];
    s += bias[i & (HD - 1)];
    out[i] = f2b(fmaxf(s, 0.f));
}

// ================= host launcher =================
extern "C" void kernel_launch(void* const* d_in, const int* in_sizes, int n_in,
                              void* d_out, int out_size, void* d_ws, size_t ws_size,
                              hipStream_t stream) {
    const int* h_id    = (const int*)d_in[0];
    const int* r_id    = (const int*)d_in[1];
    const int* src     = (const int*)d_in[2];
    const int* dst     = (const int*)d_in[3];
    const int* rel_id  = (const int*)d_in[4];
    const float* ent_emb  = (const float*)d_in[5];
    const float* rel_emb0 = (const float*)d_in[6];
    const float* neigh_w  = (const float*)d_in[7];
    const float* S_w = (const float*)d_in[8];
    const float* S_b = (const float*)d_in[9];
    const float* L_w = (const float*)d_in[10];
    const float* L_b = (const float*)d_in[11];
    const float* pred_rel = (const float*)d_in[12];
    const float* phi_w0 = (const float*)d_in[13]; const float* phi_b0 = (const float*)d_in[14];
    const float* phi_w1 = (const float*)d_in[15]; const float* phi_b1 = (const float*)d_in[16];
    const float* phi_w2 = (const float*)d_in[17]; const float* phi_b2 = (const float*)d_in[18];
    const float* psi_w0 = (const float*)d_in[19]; const float* psi_b0 = (const float*)d_in[20];
    const float* psi_w1 = (const float*)d_in[21]; const float* psi_b1 = (const float*)d_in[22];
    const float* psi_w2 = (const float*)d_in[23]; const float* psi_b2 = (const float*)d_in[24];
    const float* conv_w = (const float*)d_in[25]; const float* conv_b = (const float*)d_in[26];
    const float* fc_w   = (const float*)d_in[27]; const float* fc_b   = (const float*)d_in[28];
    const float* score_b= (const float*)d_in[29];

    char* base = (char*)d_ws;
    ushort* ep       = (ushort*)(base + OFF_EP);
    ushort* entout_bf= (ushort*)(base + OFF_ENTOUT);
    ushort* rel_bf   = (ushort*)(base + OFF_RELBF);
    ushort* prel_bf  = (ushort*)(base + OFF_PRELBF);
    ushort* Swt      = (ushort*)(base + OFF_SWT);
    ushort* Lwt      = (ushort*)(base + OFF_LWT);
    ushort* nWt      = (ushort*)(base + OFF_NWT);
    ushort* p0t      = (ushort*)(base + OFF_P0T);
    ushort* q0t      = (ushort*)(base + OFF_Q0T);
    ushort* p1t      = (ushort*)(base + OFF_P1T);
    ushort* q1t      = (ushort*)(base + OFF_Q1T);
    ushort* fct      = (ushort*)(base + OFF_FCT);
    float2* sc       = (float2*)(base + OFF_SC);
    float2* wpair    = (float2*)(base + OFF_W);
    int4*   sidx     = (int4*)(base + OFF_SIDX);
    int*    deg      = (int*)(base + OFF_DEG);
    int*    startp   = (int*)(base + OFF_START);
    int*    cursor   = (int*)(base + OFF_CUR);
    int*    bsum     = (int*)(base + OFF_BSUM);
    float*  x1       = (float*)(base + OFF_X1);
    float*  x2       = (float*)(base + OFF_X2);
    ushort* xfc_bf   = (ushort*)(base + OFF_XFC);
    ushort* c1_bf    = (ushort*)(base + OFF_EP);                 // alias (ep dead after agg)
    ushort* c2_bf    = (ushort*)(base + OFF_EP + 12812288);
    ushort* ent_bf   = (ushort*)(base + OFF_ARENA);              // temp: arena before neigh use
    ushort* neigh1_bf= (ushort*)(base + OFF_ARENA);
    ushort* neigh2_bf= (ushort*)(base + OFF_ARENA + 12812288);
    ushort* convout  = (ushort*)(base + OFF_ARENA);
    float*  fcpart   = (float*)(base + OFF_ARENA + 22421504);
    float*  outf     = (float*)d_out;

    // ---- phase 0: conversions & weight transposes (fused) ----
    k_cvt<<<dim3((MPAD * HD + 255) / 256), 256, 0, stream>>>(ent_emb, ent_bf, N_ENTS, MPAD, HD);
    k_cvt2<<<dim3(500, 1, 2), 256, 0, stream>>>(rel_emb0, rel_bf, pred_rel, prel_bf, 1000 * HD);
    k_tcvt7<<<dim3(7, 8, 7), 256, 0, stream>>>(S_w, L_w, neigh_w, phi_w0, psi_w0, phi_w1, psi_w1,
                                               Swt, Lwt, nWt, p0t, q0t, p1t, q1t);
    k_tcvtT<<<dim3(300, 4), 256, 0, stream>>>(fc_w, fct, FLATD, 128, FLATD, 128);

    // ---- phase 1: projections (fused pair) -> interleaved ep table ----
    k_mgemm<2,2,1,1><<<dim3(391, 1, 2), 256, 0, stream>>>(
        ent_bf, HD, Swt, HD, S_b, ep, 256, N_ENTS, HD, HD, HD, 0, 0, HD,
        ent_bf, Lwt, L_b, ep, 2);

    // ---- phase 2: CSR build (scatter writes sidx directly) ----
    hipMemsetAsync(deg, 0, N_ENTS * sizeof(int), stream);
    hipMemsetAsync(cursor, 0, N_ENTS * sizeof(int), stream);
    k_deg<<<dim3((E_EDGES + 255) / 256), 256, 0, stream>>>(dst, deg);
    int nscan = (N_ENTS + 255) / 256;
    k_scan1<<<dim3(nscan), 256, 0, stream>>>(deg, startp, bsum, N_ENTS);
    k_scan2<<<dim3(1), 1024, 0, stream>>>(bsum, nscan);
    k_scan3<<<dim3(nscan), 256, 0, stream>>>(startp, bsum, N_ENTS);
    k_scatter2<<<dim3((E_EDGES + 255) / 256), 256, 0, stream>>>(src, dst, rel_id, startp, cursor, sidx);

    // ---- phase 3-5: edge pipeline ----
    k_scores<<<dim3(E_EDGES / 32), 256, 0, stream>>>(sidx, ep, rel_bf, sc);
    k_softtop<<<dim3((N_ENTS + 15) / 16), 256, 0, stream>>>(startp, deg, sidx, sc, wpair);
    k_agg<<<dim3(N_ENTS), 256, 0, stream>>>(sidx, startp, deg, wpair, ep, rel_bf,
                                            neigh1_bf, neigh2_bf);

    // ---- phase 6+7: c1/c2 = tanh(neigh @ W) + ent_out, fused ----
    k_tanh2ent<<<dim3(391), 256, 0, stream>>>(neigh1_bf, neigh2_bf, nWt, ent_emb,
                                              c1_bf, c2_bf, entout_bf);

    // ---- phase 8: fused MLPs (both via z) ----
    k_mlp2<<<dim3(MPAD / 64, 1, 2), 256, 0, stream>>>(
        c1_bf, p0t, phi_b0, p1t, phi_b1, phi_w2, phi_b2, x1,
        c2_bf, q0t, psi_b0, q1t, psi_b1, psi_w2, psi_b2, x2);

    // ---- phase 9: corr (merged) ----
    k_corr<<<dim3(1), 1024, 0, stream>>>(x1, x2, outf + OUT_SCORE);

    // ---- phase 10-11: ConvE ----
    k_conv<<<dim3(BSZ), 256, 0, stream>>>(h_id, r_id, entout_bf, prel_bf, conv_w, conv_b, convout);
    k_mgemm<2,2,0,0><<<dim3(8, 1, SPLITK), 256, 0, stream>>>(
        convout, FLATD, fct, FLATD, nullptr, fcpart, HD, BSZ, HD, FLATD, FLATD / SPLITK, 0, -1, HD,
        nullptr, nullptr, nullptr, nullptr, 0);
    k_fcreduce<<<dim3((BSZ * HD + 255) / 256), 256, 0, stream>>>(fcpart, fc_b, xfc_bf);

    // ---- phase 12: score GEMM (XCD-swizzled, NT stores) ----
    k_score<<<dim3(16, 196), 256, 0, stream>>>(xfc_bf, entout_bf, score_b, outf, N_ENTS);
}